// Round 6
// baseline (509.115 us; speedup 1.0000x reference)
//
#include <hip/hip_runtime.h>
#include <math.h>

#define Bb 8
#define Nn 1024
#define Kk 32
#define Dd 256
#define Hh 8
#define DHh 32
#define TDIMt 16
#define NBnb 32
#define HIDh 128
#define NSns 128
#define SHDs 9
#define EINe 304   // NB + TDIM + 2*NS
#define NCOLS 1536 // vproj 256 | hsrc 128 | hdst 128 | qw 1024

typedef __bf16 bf16_t;
typedef bf16_t bf16x8 __attribute__((ext_vector_type(8)));
typedef float floatx4 __attribute__((ext_vector_type(4)));

// global->LDS direct copy, 16B per lane; LDS dest must be linear in lane id.
#define GLOAD_LDS16(gp, lp) __builtin_amdgcn_global_load_lds( \
    (const __attribute__((address_space(1))) void*)(gp),      \
    (__attribute__((address_space(3))) void*)(lp), 16, 0, 0)

__device__ __forceinline__ float gelu_fast(float x){
  float g = 1.5957691216057308f*(x + 0.044715f*x*x*x);
  return x*__builtin_amdgcn_rcpf(1.0f + __expf(-g));
}
__device__ __forceinline__ float tanh_fast(float x){
  return 1.0f - 2.0f*__builtin_amdgcn_rcpf(1.0f + __expf(2.0f*x));
}

// ---------------- setup: knn FIRST, then preps, then embed ----------------
__global__ __launch_bounds__(256) void setup_kernel(
    const float* __restrict__ x, const float* __restrict__ y, const float* __restrict__ t,
    const float* __restrict__ We, const float* __restrict__ Wk1, const float* __restrict__ bk1,
    const float* __restrict__ Wk2, const float* __restrict__ Wq, const float* __restrict__ Wv,
    const float* __restrict__ Wo,
    bf16_t* __restrict__ Wt, bf16_t* __restrict__ Wto, bf16_t* __restrict__ WrbfT,
    float* __restrict__ t_hd, int* __restrict__ src,
    float* __restrict__ node, bf16_t* __restrict__ node_bf){

  __shared__ float s_b[32];
  __shared__ unsigned long long s_knn[4][64];
  const int bid = blockIdx.x, tid = threadIdx.x;

  if (bid < 2048){                       // ---- knn: threshold-select + compact + bitonic sort
    int wave = tid >> 6, lane = tid & 63;
    int bn = bid*4 + wave;
    int b = bn >> 10, n = bn & (Nn-1);
    const float* xb = x + (size_t)b*Nn*3;
    float px = xb[n*3+0], py = xb[n*3+1], pz = xb[n*3+2];
    float d2v[16];
    #pragma unroll
    for (int i=0;i<16;i++){
      int j = i*64 + lane;
      float dx = px - xb[j*3+0];
      float dy = py - xb[j*3+1];
      float dz = pz - xb[j*3+2];
      d2v[i] = dx*dx + dy*dy + dz*dz;
    }

    // find wave-uniform T with |{d2 <= T}| in [32,64]; interp-bisection on count
    unsigned lob = 0u, hib = 0x7149F2CAu;   // bits(1e30)
    float T = 1.0f;
    int lc = 0;
    for (int it=0; it<24; ++it){
      lc = 0;
      #pragma unroll
      for (int i=0;i<16;i++) lc += (d2v[i] <= T) ? 1 : 0;
      int c = lc;
      #pragma unroll
      for (int off=32; off>=1; off>>=1) c += __shfl_xor(c, off);
      if (c >= 32 && c <= 64) break;
      if (c < 32) lob = __float_as_uint(T); else hib = __float_as_uint(T);
      // cnt ~ T^(3/2) for small radii -> T_next = T*(target/c)^(2/3)
      float ratio = 44.0f * __builtin_amdgcn_rcpf((float)(c < 1 ? 1 : c));
      float Tn = T * __powf(ratio, 0.6666667f);
      unsigned tb = __float_as_uint(Tn);
      if (tb <= lob || tb >= hib) tb = lob + ((hib - lob) >> 1);
      T = __uint_as_float(tb);
    }

    // exclusive prefix of per-lane candidate counts
    int pre = lc;
    #pragma unroll
    for (int d=1; d<64; d<<=1){
      int o = __shfl_up(pre, d);
      if (lane >= d) pre += o;
    }
    int wo = pre - lc;   // this lane's base slot

    unsigned long long* sl = s_knn[wave];
    sl[lane] = ~0ull;    // pad with +inf keys (program-order before compact writes)
    #pragma unroll
    for (int i=0;i<16;i++){
      if (d2v[i] <= T && wo < 64){
        sl[wo] = (((unsigned long long)__float_as_uint(d2v[i])) << 10)
                 | (unsigned)(i*64 + lane);
        wo++;
      }
    }
    __syncthreads();

    // 64-element cross-lane bitonic sort on exact (d2,idx) keys, ascending
    unsigned long long key = sl[lane];
    #pragma unroll
    for (int k2=2; k2<=64; k2<<=1){
      #pragma unroll
      for (int j2=k2>>1; j2>=1; j2>>=1){
        unsigned long long pv = __shfl_xor(key, j2);
        bool takeMin = (((lane & j2) == 0) == ((lane & k2) == 0));
        bool pLess = pv < key;
        key = (pLess == takeMin) ? pv : key;
      }
    }
    if (lane < 32) src[(size_t)bn*Kk + lane] = (int)(key & 1023u);
  } else if (bid < 6144){                // ---- wprepM (coalesced)
    int i = bid-2048; int l = i>>10, yy = i&1023;
    int h = yy>>7, c = yy&127;
    if (tid < 32) s_b[tid] = Wk2[(size_t)l*HIDh*Dd + (size_t)c*Dd + h*DHh + tid];
    __syncthreads();
    const int rloc = tid>>3, dg = tid&7;
    const float b0 = s_b[dg*4+0], b1 = s_b[dg*4+1], b2 = s_b[dg*4+2], b3 = s_b[dg*4+3];
    #pragma unroll
    for (int p=0;p<8;p++){
      int ii = p*32 + rloc;
      const float4 v = *(const float4*)(Wq + (size_t)l*Dd*Dd + (size_t)ii*Dd + h*DHh + dg*4);
      float part = v.x*b0 + v.y*b1 + v.z*b2 + v.w*b3;
      part += __shfl_xor(part, 1);
      part += __shfl_xor(part, 2);
      part += __shfl_xor(part, 4);
      if (dg == 0) Wt[((size_t)l*NCOLS + 512 + yy)*Dd + ii] = (bf16_t)part;
    }
  } else if (bid < 8192){                // ---- wprep: Wt[l][c][k], c<512
    int i = bid-6144; int l = i>>9, c = i&511, k = tid;
    const float* wk1l = Wk1 + (size_t)l*EINe*HIDh;
    float v;
    if (c < 256)       v = Wv[(size_t)l*265*Dd + (size_t)k*Dd + c];
    else if (c < 384){ int c2 = c-256; v = (k < 128) ? wk1l[(48+k)*HIDh + c2] : 0.0f; }
    else             { int c2 = c-384; v = (k < 128) ? wk1l[(176+k)*HIDh + c2] : 0.0f; }
    Wt[((size_t)l*NCOLS + c)*Dd + k] = (bf16_t)v;
  } else if (bid < 8960){                // ---- wprepO
    int i = bid-8192; int l = i>>8; int c = i&255; int k = tid;
    Wto[((size_t)l*Dd + c)*Dd + k] = (bf16_t)Wo[(size_t)l*Dd*Dd + (size_t)k*Dd + c];
  } else if (bid < 9024){                // ---- wprepR
    int i = bid-8960; int l = i>>4, cg = i&15;
    int c = cg*8 + (tid>>5), k = tid&31;
    WrbfT[((size_t)l*HIDh + c)*NBnb + k] = (bf16_t)Wk1[(size_t)l*EINe*HIDh + (size_t)k*HIDh + c];
  } else if (bid < 9040){                // ---- tprep
    int i = bid-9024; int pair = i*2 + (tid>>7);
    int l = pair>>3, b = pair&7, c = tid&127;
    const float* wk1l = Wk1 + (size_t)l*EINe*HIDh;
    float a = bk1[l*HIDh + c];
    #pragma unroll
    for (int ii=0;ii<TDIMt;ii++) a += t[b*TDIMt+ii]*wk1l[(32+ii)*HIDh + c];
    t_hd[(l*Bb + b)*HIDh + c] = a;
  } else {                               // ---- embed (4 nodes/block)
    int bn0 = (bid-9040)*4; int c = tid;
    float w0 = We[0*Dd+c], w1 = We[1*Dd+c], w2 = We[2*Dd+c];
    float wt[TDIMt];
    #pragma unroll
    for (int i=0;i<TDIMt;i++) wt[i] = We[(3+i)*Dd+c];
    #pragma unroll
    for (int u=0;u<4;u++){
      int bn = bn0 + u; int b = bn >> 10;
      float a = y[(size_t)bn*3+0]*w0 + y[(size_t)bn*3+1]*w1 + y[(size_t)bn*3+2]*w2;
      #pragma unroll
      for (int i=0;i<TDIMt;i++) a += t[b*TDIMt+i]*wt[i];
      node[(size_t)bn*Dd + c] = a;
      node_bf[(size_t)bn*Dd + c] = (bf16_t)a;
    }
  }
}

// ---------------- proj GEMM (all layers): LDS-staged 128x64 tile, BK=64 dbuf ----------------
// A [8192 x 256] bf16 row-major; B = Wt[layer][col][k]. Epilogue scatter unchanged.
// blockIdx.x swizzled so batch == bx&7 == XCD.
__global__ __launch_bounds__(256) void gemm_proj(const bf16_t* __restrict__ A,
    const bf16_t* __restrict__ Wt_all, float* __restrict__ vproj_f,
    bf16_t* __restrict__ hsrc_bf, float* __restrict__ hdst_f,
    bf16_t* __restrict__ qw_bf, const float* __restrict__ t_hd, int layer){

  __shared__ __align__(16) bf16_t s_A[2][8192];   // [buf][128 rows][64 k] xor-swizzled
  __shared__ __align__(16) bf16_t s_B[2][4096];   // [buf][ 64 cols][64 k] xor-swizzled

  const int tid = threadIdx.x;
  const int wave = tid>>6, lane = tid&63;
  const int row16 = lane&15, quad = lane>>4;
  const int bx = blockIdx.x;
  const int brow = ((bx & 7) << 3) + (bx >> 3);    // batch = bx&7
  const int m0 = brow*128;
  const int m_base = m0 + wave*32;
  const int n_base = blockIdx.y*64;
  const bf16_t* Ab = A + (size_t)m0*Dd;
  const bf16_t* Bw = Wt_all + ((size_t)layer*NCOLS + n_base)*Dd;

  // staging geometry: thread t -> row trow (8 thr/row, 16B each), pre-swizzled k source
  const int trow = tid>>3;                          // 0..31
  const int tk   = ((tid&7) ^ (trow&7)) << 3;       // element offset, xor-swizzled
  const int swz  = (row16&7) << 3;                  // read-side xor (elements)

  floatx4 acc[2][4];
  #pragma unroll
  for (int mi=0;mi<2;mi++)
    #pragma unroll
    for (int ni=0;ni<4;ni++){ floatx4 z = {0.f,0.f,0.f,0.f}; acc[mi][ni] = z; }

  // prologue: stage kt=0 into buf 0
  {
    const bf16_t* ga = Ab + (size_t)trow*Dd + tk;
    #pragma unroll
    for (int i=0;i<4;i++) GLOAD_LDS16(ga + (size_t)i*32*Dd, &s_A[0][i*2048 + tid*8]);
    const bf16_t* gb = Bw + (size_t)trow*Dd + tk;
    #pragma unroll
    for (int j=0;j<2;j++) GLOAD_LDS16(gb + (size_t)j*32*Dd, &s_B[0][j*2048 + tid*8]);
  }
  __syncthreads();

  #pragma unroll
  for (int kt=0; kt<4; kt++){
    const int cur = kt&1, nxt = cur^1;
    if (kt < 3){
      const bf16_t* ga = Ab + (size_t)trow*Dd + (kt+1)*64 + tk;
      #pragma unroll
      for (int i=0;i<4;i++) GLOAD_LDS16(ga + (size_t)i*32*Dd, &s_A[nxt][i*2048 + tid*8]);
      const bf16_t* gb = Bw + (size_t)trow*Dd + (kt+1)*64 + tk;
      #pragma unroll
      for (int j=0;j<2;j++) GLOAD_LDS16(gb + (size_t)j*32*Dd, &s_B[nxt][j*2048 + tid*8]);
    }
    #pragma unroll
    for (int ksub=0; ksub<2; ksub++){
      const int ko = (ksub*32 + quad*8) ^ swz;
      bf16x8 a0 = *(const bf16x8*)&s_A[cur][(wave*32      + row16)*64 + ko];
      bf16x8 a1 = *(const bf16x8*)&s_A[cur][(wave*32 + 16 + row16)*64 + ko];
      #pragma unroll
      for (int ni=0;ni<4;ni++){
        bf16x8 b = *(const bf16x8*)&s_B[cur][(ni*16 + row16)*64 + ko];
        acc[0][ni] = __builtin_amdgcn_mfma_f32_16x16x32_bf16(a0, b, acc[0][ni], 0,0,0);
        acc[1][ni] = __builtin_amdgcn_mfma_f32_16x16x32_bf16(a1, b, acc[1][ni], 0,0,0);
      }
    }
    __syncthreads();
  }

  const int by = blockIdx.y;
  const int bb = m_base >> 10;
  #pragma unroll
  for (int mi=0;mi<2;mi++)
    #pragma unroll
    for (int ni=0;ni<4;ni++){
      int col = n_base + ni*16 + row16;
      #pragma unroll
      for (int r=0;r<4;r++){
        int row = m_base + mi*16 + quad*4 + r;
        float v = acc[mi][ni][r];
        if (by < 4)       vproj_f[(size_t)row*256 + col]        = v;
        else if (by < 6)  hsrc_bf[(size_t)row*128 + (col-256)]  = (bf16_t)v;
        else if (by < 8)  hdst_f[(size_t)row*128 + (col-384)]   = v + t_hd[(size_t)(layer*Bb + bb)*HIDh + (col-384)];
        else              qw_bf[(size_t)row*1024 + (col-512)]   = (bf16_t)v;
      }
    }
}

// ---------------- upd GEMM: node_out = act(agg @ Wto[lu] + node_in); writes f32 + bf16 ----------------
// Same staged structure, N=256 (grid y=4).
__global__ __launch_bounds__(256) void gemm_upd(
    const bf16_t* __restrict__ agg_bf, const bf16_t* __restrict__ Wto,
    const float* __restrict__ node_in, float* __restrict__ node_out,
    bf16_t* __restrict__ node_bf, int lu, int write_node){

  __shared__ __align__(16) bf16_t s_A[2][8192];
  __shared__ __align__(16) bf16_t s_B[2][4096];

  const int tid = threadIdx.x;
  const int wave = tid>>6, lane = tid&63;
  const int row16 = lane&15, quad = lane>>4;
  const int bx = blockIdx.x;
  const int brow = ((bx & 7) << 3) + (bx >> 3);
  const int m0 = brow*128;
  const int m_base = m0 + wave*32;
  const int n_base = blockIdx.y*64;
  const bf16_t* Ab = agg_bf + (size_t)m0*Dd;
  const bf16_t* Bw = Wto + (size_t)lu*Dd*Dd + (size_t)n_base*Dd;

  const int trow = tid>>3;
  const int tk   = ((tid&7) ^ (trow&7)) << 3;
  const int swz  = (row16&7) << 3;

  floatx4 acc[2][4];
  #pragma unroll
  for (int mi=0;mi<2;mi++)
    #pragma unroll
    for (int ni=0;ni<4;ni++){ floatx4 z = {0.f,0.f,0.f,0.f}; acc[mi][ni] = z; }

  {
    const bf16_t* ga = Ab + (size_t)trow*Dd + tk;
    #pragma unroll
    for (int i=0;i<4;i++) GLOAD_LDS16(ga + (size_t)i*32*Dd, &s_A[0][i*2048 + tid*8]);
    const bf16_t* gb = Bw + (size_t)trow*Dd + tk;
    #pragma unroll
    for (int j=0;j<2;j++) GLOAD_LDS16(gb + (size_t)j*32*Dd, &s_B[0][j*2048 + tid*8]);
  }
  __syncthreads();

  #pragma unroll
  for (int kt=0; kt<4; kt++){
    const int cur = kt&1, nxt = cur^1;
    if (kt < 3){
      const bf16_t* ga = Ab + (size_t)trow*Dd + (kt+1)*64 + tk;
      #pragma unroll
      for (int i=0;i<4;i++) GLOAD_LDS16(ga + (size_t)i*32*Dd, &s_A[nxt][i*2048 + tid*8]);
      const bf16_t* gb = Bw + (size_t)trow*Dd + (kt+1)*64 + tk;
      #pragma unroll
      for (int j=0;j<2;j++) GLOAD_LDS16(gb + (size_t)j*32*Dd, &s_B[nxt][j*2048 + tid*8]);
    }
    #pragma unroll
    for (int ksub=0; ksub<2; ksub++){
      const int ko = (ksub*32 + quad*8) ^ swz;
      bf16x8 a0 = *(const bf16x8*)&s_A[cur][(wave*32      + row16)*64 + ko];
      bf16x8 a1 = *(const bf16x8*)&s_A[cur][(wave*32 + 16 + row16)*64 + ko];
      #pragma unroll
      for (int ni=0;ni<4;ni++){
        bf16x8 b = *(const bf16x8*)&s_B[cur][(ni*16 + row16)*64 + ko];
        acc[0][ni] = __builtin_amdgcn_mfma_f32_16x16x32_bf16(a0, b, acc[0][ni], 0,0,0);
        acc[1][ni] = __builtin_amdgcn_mfma_f32_16x16x32_bf16(a1, b, acc[1][ni], 0,0,0);
      }
    }
    __syncthreads();
  }

  #pragma unroll
  for (int mi=0;mi<2;mi++)
    #pragma unroll
    for (int ni=0;ni<4;ni++){
      int col = n_base + ni*16 + row16;
      #pragma unroll
      for (int r=0;r<4;r++){
        int row = m_base + mi*16 + quad*4 + r;
        float v = acc[mi][ni][r] + node_in[(size_t)row*Dd + col];
        if (col < 64)       v = gelu_fast(v);
        else if (col < 128) v = tanh_fast(v);
        if (write_node) node_out[(size_t)row*Dd + col] = v;
        node_bf[(size_t)row*Dd + col] = (bf16_t)v;
      }
    }
}

// ---------------- attn: 2 nodes per block; vproj rows prefetched at entry ----------------
__global__ __launch_bounds__(256) void attn_kernel(
    const float* __restrict__ x, const int* __restrict__ src,
    const float* __restrict__ vproj_f, const bf16_t* __restrict__ hsrc_bf,
    const float* __restrict__ hdst_f, const bf16_t* __restrict__ qw_bf,
    const bf16_t* __restrict__ WrbfT,
    const float* __restrict__ Wvg, const float* __restrict__ Woo,
    bf16_t* __restrict__ agg_bf, float* __restrict__ out, int layer){

  __shared__ __align__(16) char smem[23296];
  bf16_t* s_h     = (bf16_t*)(smem);             // [2][32][136] bf16
  float*  s_part  = (float*)(smem);              // [4][256] f32 overlay (s_h dead)
  float*  s_sh    = (float*)(smem + 17408);      // [2][32][10]
  float*  s_cut   = (float*)(smem + 19968);      // [2][32]
  float*  s_logit = (float*)(smem + 20480);      // [2][32][8]
  float*  s_pool  = (float*)(smem + 22528);      // [2][8][10]
  float*  s_red   = (float*)(smem + 23168);      // [2][4][3]

  const int tid  = threadIdx.x;
  const int bidx = blockIdx.x;
  const int b    = bidx & 7;                       // batch -> XCD affinity
  const int bn0  = (b << 10) | ((bidx >> 3) << 1); // node pair base
  const int wave = tid>>6, lane = tid&63;
  const int side = wave>>1, wv = wave&1;           // side: which node; wv: wave within side
  const int row16 = lane&15, quad = lane>>4;
  const int bns = bn0 + side;

  // ---- prefetch EVERYTHING latency-critical at entry ----
  // (a) vproj rows for this wave's 16 neighbors (uniform row ids -> scalar base)
  float4 vv[16];
  {
    const int* sp = src + (size_t)bns*Kk + wv*16;
    #pragma unroll
    for (int i=0;i<16;i++){
      int row = __builtin_amdgcn_readfirstlane(sp[i]);
      vv[i] = *(const float4*)(vproj_f + ((size_t)b*Nn + row)*256 + (lane<<2));
    }
  }
  // (b) q-weights + hdst
  bf16x8 qf[4];
  { const bf16_t* qp = qw_bf + (size_t)bns*1024 + row16*HIDh + quad*8;
    #pragma unroll
    for (int ks=0; ks<4; ks++) qf[ks] = *(const bf16x8*)(qp + ks*32); }
  float hdv[4];
  #pragma unroll
  for (int ni=0; ni<4; ni++) hdv[ni] = hdst_f[(size_t)bns*128 + wv*64 + ni*16 + row16];

  const float ax = x[(size_t)bns*3+0], ay = x[(size_t)bns*3+1], az = x[(size_t)bns*3+2];

  const int sE0 = src[(size_t)bns*Kk + row16];
  const int sE1 = src[(size_t)bns*Kk + row16 + 16];

  // hsrc gather: 128 threads/side cover 32 edges x 128 cols (4 x bf16x8 each)
  const int t2 = tid & 127;
  const int e0 = t2>>3, cg = t2&7;
  const int sG0 = src[(size_t)bns*Kk + e0];
  const int sG1 = src[(size_t)bns*Kk + e0 + 16];
  bf16x8 hsv00 = *(const bf16x8*)(hsrc_bf + ((size_t)b*Nn + sG0)*128 + cg*8);
  bf16x8 hsv01 = *(const bf16x8*)(hsrc_bf + ((size_t)b*Nn + sG0)*128 + cg*8 + 64);
  bf16x8 hsv10 = *(const bf16x8*)(hsrc_bf + ((size_t)b*Nn + sG1)*128 + cg*8);
  bf16x8 hsv11 = *(const bf16x8*)(hsrc_bf + ((size_t)b*Nn + sG1)*128 + cg*8 + 64);

  // rbf A-fragments via Gaussian recurrence (node bns)
  bf16x8 a0f, a1f;
  {
    const float* xj0 = x + ((size_t)b*Nn + sE0)*3;
    const float* xj1 = x + ((size_t)b*Nn + sE1)*3;
    float d0x = ax - xj0[0], d0y = ay - xj0[1], d0z = az - xj0[2];
    float d1x = ax - xj1[0], d1y = ay - xj1[1], d1z = az - xj1[2];
    float rr0 = sqrtf(d0x*d0x + d0y*d0y + d0z*d0z);
    float rr1 = sqrtf(d1x*d1x + d1y*d1y + d1z*d1z);
    float xx0 = 10.0f*(1.0f - rr0*0.5f);
    float xx1 = 10.0f*(1.0f - rr1*0.5f);
    float cu0 = (xx0 > 0.0f) ? 1.4f*__expf(-__builtin_amdgcn_rcpf(xx0)) : 0.0f;
    float cu1 = (xx1 > 0.0f) ? 1.4f*__expf(-__builtin_amdgcn_rcpf(xx1)) : 0.0f;
    float sc0 = 4.798224586623f*cu0;
    float sc1 = 4.798224586623f*cu1;
    float rs0 = fminf(rr0*15.5f, 33.0f);
    float rs1 = fminf(rr1*15.5f, 33.0f);
    float cbase = (float)(quad*8);
    float dd0 = rs0 - cbase, dd1 = rs1 - cbase;
    float e0v = __expf(-dd0*dd0)*sc0;
    float e1v = __expf(-dd1*dd1)*sc1;
    float g0 = __expf(2.0f*dd0 - 1.0f);
    float g1 = __expf(2.0f*dd1 - 1.0f);
    a0f[0] = (bf16_t)e0v; a1f[0] = (bf16_t)e1v;
    #pragma unroll
    for (int j=1;j<8;j++){
      e0v *= g0; e1v *= g1;
      a0f[j] = (bf16_t)e0v; a1f[j] = (bf16_t)e1v;
      g0 *= 0.13533528323661270f; g1 *= 0.13533528323661270f;
    }
  }

  // helper: cut + sh for BOTH nodes on waves 0-1
  if (tid < 128){
    const int hs = (tid>>6)&1;
    const int k = tid & 31;
    const int hn = bn0 + hs;
    const int j = src[(size_t)hn*Kk + k];
    const float hx = x[(size_t)hn*3+0], hy = x[(size_t)hn*3+1], hz = x[(size_t)hn*3+2];
    const float* xj = x + ((size_t)b*Nn + j)*3;
    float dx = hx - xj[0], dy = hy - xj[1], dz = hz - xj[2];
    float rr = sqrtf(dx*dx + dy*dy + dz*dz);
    if ((tid & 32) == 0){
      float xx = 10.0f*(1.0f - rr*0.5f);
      s_cut[hs*32 + k] = (xx > 0.0f) ? 1.4f*__expf(-__builtin_amdgcn_rcpf(xx)) : 0.0f;
    } else {
      float inv = __builtin_amdgcn_rcpf(fmaxf(rr, 1e-9f));
      float ux = dx*inv, uy = dy*inv, uz = dz*inv;
      float* sh = s_sh + hs*320 + k*10;
      sh[0] = 1.0f;
      sh[1] = 1.7320508075688772f*ux;
      sh[2] = 1.7320508075688772f*uy;
      sh[3] = 1.7320508075688772f*uz;
      sh[4] = 3.872983346207417f*ux*uy;
      sh[5] = 3.872983346207417f*uy*uz;
      sh[6] = 1.118033988749895f*(3.0f*uz*uz - 1.0f);
      sh[7] = 3.872983346207417f*ux*uz;
      sh[8] = 1.9364916731037085f*(ux*ux - uy*uy);
    }
  }

  // edge-MLP rbf MFMA: this wave covers cols wv*64 .. wv*64+63 of its node
  floatx4 acc[2][4];
  {
    #pragma unroll
    for (int mi=0;mi<2;mi++)
      #pragma unroll
      for (int ni=0;ni<4;ni++){ floatx4 z = {0.f,0.f,0.f,0.f}; acc[mi][ni] = z; }
    const bf16_t* bp = WrbfT + ((size_t)layer*HIDh + wv*64 + row16)*NBnb + quad*8;
    #pragma unroll
    for (int j=0;j<4;j++){
      bf16x8 bbf = *(const bf16x8*)(bp + (size_t)j*16*NBnb);
      acc[0][j] = __builtin_amdgcn_mfma_f32_16x16x32_bf16(a0f, bbf, acc[0][j], 0,0,0);
      acc[1][j] = __builtin_amdgcn_mfma_f32_16x16x32_bf16(a1f, bbf, acc[1][j], 0,0,0);
    }
  }

  bf16_t* shs = s_h + side*4352;
  *(bf16x8*)(shs + e0*136 + cg*8)            = hsv00;
  *(bf16x8*)(shs + e0*136 + cg*8 + 64)       = hsv01;
  *(bf16x8*)(shs + (e0+16)*136 + cg*8)       = hsv10;
  *(bf16x8*)(shs + (e0+16)*136 + cg*8 + 64)  = hsv11;
  __syncthreads();

  // gelu combine: 32 elems/thread
  #pragma unroll
  for (int ni=0;ni<4;ni++){
    int c = wv*64 + ni*16 + row16;
    #pragma unroll
    for (int mi=0;mi<2;mi++){
      #pragma unroll
      for (int r=0;r<4;r++){
        int e = mi*16 + quad*4 + r;
        float hs = (float)shs[e*136 + c];
        shs[e*136 + c] = (bf16_t)gelu_fast(acc[mi][ni][r] + hdv[ni] + hs);
      }
    }
  }
  __syncthreads();

  // logits: all 4 waves (wv covers 16 edges of its node)
  {
    floatx4 la = {0.f,0.f,0.f,0.f};
    #pragma unroll
    for (int ks=0; ks<4; ks++){
      bf16x8 a = *(const bf16x8*)(shs + (wv*16 + row16)*136 + ks*32 + quad*8);
      la = __builtin_amdgcn_mfma_f32_16x16x32_bf16(a, qf[ks], la, 0,0,0);
    }
    if (row16 < Hh){
      #pragma unroll
      for (int r=0;r<4;r++)
        s_logit[side*256 + (wv*16 + quad*4 + r)*8 + row16] = la[r]*0.17677669529663687f;
    }
  }
  __syncthreads();

  // softmax for both nodes: each thread owns (k,h), loops nodes
  {
    const int k = tid & 31;
    const int h = tid >> 5;          // 0..7
    #pragma unroll
    for (int sn=0; sn<2; sn++){
      float lv = s_logit[sn*256 + k*8 + h];
      float m = lv;
      #pragma unroll
      for (int off=16; off>=1; off>>=1) m = fmaxf(m, __shfl_xor(m, off));
      float w = s_cut[sn*32 + k]*__expf(lv - m);
      float ss = w;
      #pragma unroll
      for (int off=16; off>=1; off>>=1) ss += __shfl_xor(ss, off);
      s_logit[sn*256 + k*8 + h] = w*__builtin_amdgcn_rcpf(ss + 1e-9f);
    }
  }
  __syncthreads();

  // sh-pool: 2 nodes x 8 h x 9 sg on 256 threads (short pass)
  {
    const int pn = tid>>7, t3 = tid&127, h2 = t3>>4, sg = t3&15;
    if (sg < SHDs){
      float a = 0.0f;
      #pragma unroll
      for (int k2=0;k2<Kk;k2++)
        a += s_logit[pn*256 + k2*8 + h2] * s_sh[pn*320 + k2*10 + sg];
      s_pool[pn*80 + h2*10 + sg] = a;
    }
  }

  // main agg: prefetched rows x alpha (FMA only; loads issued at entry)
  {
    const int albase = side*256 + wv*128 + (lane>>3);
    float4 accv = {0.f,0.f,0.f,0.f};
    #pragma unroll
    for (int i=0;i<16;i++){
      float al = s_logit[albase + i*8];
      accv.x += al*vv[i].x; accv.y += al*vv[i].y; accv.z += al*vv[i].z; accv.w += al*vv[i].w;
    }
    *(float4*)(s_part + (side*2 + wv)*256 + (lane<<2)) = accv;
  }
  __syncthreads();

  // final: both nodes, wvsh shared
  {
    const int h = tid >> 5;
    const float* wvsh = Wvg + (size_t)layer*265*Dd + 256*Dd;
    float wv9[SHDs];
    #pragma unroll
    for (int sg=0; sg<SHDs; sg++) wv9[sg] = wvsh[sg*Dd + tid];

    float w0=0.f, w1=0.f, w2=0.f;
    if (layer >= 3){ w0 = Woo[tid*3+0]; w1 = Woo[tid*3+1]; w2 = Woo[tid*3+2]; }

    #pragma unroll
    for (int sn=0; sn<2; sn++){
      float a_main = s_part[sn*512 + tid] + s_part[sn*512 + 256 + tid];
      #pragma unroll
      for (int sg=0; sg<SHDs; sg++) a_main += s_pool[sn*80 + h*10 + sg]*wv9[sg];

      if (layer < 3){
        agg_bf[(size_t)(bn0+sn)*Dd + tid] = (bf16_t)a_main;
      } else {
        float p0 = a_main*w0;
        float p1 = a_main*w1;
        float p2 = a_main*w2;
        #pragma unroll
        for (int off=32; off>=1; off>>=1){
          p0 += __shfl_xor(p0, off);
          p1 += __shfl_xor(p1, off);
          p2 += __shfl_xor(p2, off);
        }
        if (lane == 0){
          s_red[sn*12 + wave*3+0] = p0;
          s_red[sn*12 + wave*3+1] = p1;
          s_red[sn*12 + wave*3+2] = p2;
        }
      }
    }
    if (layer >= 3){
      __syncthreads();
      if (tid < 8){
        int sn = tid>>2, j = tid&3;
        if (j < 3)
          out[(size_t)(bn0+sn)*3 + j] = s_red[sn*12 + j] + s_red[sn*12 + 3 + j]
                                      + s_red[sn*12 + 6 + j] + s_red[sn*12 + 9 + j];
      }
    }
  }
}

extern "C" void kernel_launch(void* const* d_in, const int* in_sizes, int n_in,
                              void* d_out, int out_size, void* d_ws, size_t ws_size,
                              hipStream_t stream){
  const float* x   = (const float*)d_in[0];
  const float* y   = (const float*)d_in[1];
  const float* t   = (const float*)d_in[2];
  const float* We  = (const float*)d_in[3];
  const float* Wk1 = (const float*)d_in[4];
  const float* bk1 = (const float*)d_in[5];
  const float* Wk2 = (const float*)d_in[6];
  const float* Wq  = (const float*)d_in[7];
  const float* Wv  = (const float*)d_in[8];
  const float* Wo  = (const float*)d_in[9];
  const float* Woo = (const float*)d_in[10];
  float* out = (float*)d_out;

  char* ws = (char*)d_ws;
  size_t off = 0;
  auto take = [&](size_t bytes)->char*{ char* p = ws + off; off = (off + bytes + 255) & ~(size_t)255; return p; };

  int*    src      = (int*)   take((size_t)Bb*Nn*Kk*4);
  float*  nodeA    = (float*) take((size_t)Bb*Nn*Dd*4);
  float*  nodeB    = (float*) take((size_t)Bb*Nn*Dd*4);
  bf16_t* node_bf  = (bf16_t*)take((size_t)Bb*Nn*Dd*2);
  bf16_t* agg_bf   = (bf16_t*)take((size_t)Bb*Nn*Dd*2);
  float*  vproj_f  = (float*) take((size_t)Bb*Nn*256*4);
  bf16_t* hsrc_bf  = (bf16_t*)take((size_t)Bb*Nn*128*2);
  float*  hdst_f   = (float*) take((size_t)Bb*Nn*128*4);
  bf16_t* qw_bf    = (bf16_t*)take(((size_t)Bb*Nn*1024 + 2048)*2);  // +pad for B-frag overread
  bf16_t* Wt       = (bf16_t*)take((size_t)4*NCOLS*Dd*2);
  bf16_t* Wto      = (bf16_t*)take((size_t)3*Dd*Dd*2);
  bf16_t* WrbfT    = (bf16_t*)take((size_t)4*HIDh*NBnb*2);
  float*  t_hd     = (float*) take((size_t)4*Bb*HIDh*4);

  setup_kernel<<<dim3(11088), 256, 0, stream>>>(x, y, t, We, Wk1, bk1, Wk2, Wq, Wv, Wo,
                                                Wt, Wto, WrbfT, t_hd, src, nodeA, node_bf);

  gemm_proj<<<dim3(64,24), 256, 0, stream>>>(node_bf, Wt, vproj_f, hsrc_bf, hdst_f, qw_bf, t_hd, 0);
  attn_kernel<<<dim3(Bb*Nn/2), 256, 0, stream>>>(x, src, vproj_f, hsrc_bf, hdst_f, qw_bf,
                                                 WrbfT, Wv, Woo, agg_bf, out, 0);
  // node f32 double-buffer: lu=0 reads A writes B; lu=1 reads B writes A; lu=2 reads A (bf16 only)
  const float* nin[3]  = {nodeA, nodeB, nodeA};
  float*       nout[3] = {nodeB, nodeA, nodeB};
  for (int l=1; l<4; l++){
    gemm_upd<<<dim3(64,4), 256, 0, stream>>>(agg_bf, Wto, nin[l-1], nout[l-1], node_bf,
                                             l-1, (l < 3) ? 1 : 0);
    gemm_proj<<<dim3(64,24), 256, 0, stream>>>(node_bf, Wt, vproj_f, hsrc_bf, hdst_f, qw_bf, t_hd, l);
    attn_kernel<<<dim3(Bb*Nn/2), 256, 0, stream>>>(x, src, vproj_f, hsrc_bf, hdst_f, qw_bf,
                                                   WrbfT, Wv, Woo, agg_bf, out, l);
  }
}

// Round 7
// 398.963 us; speedup vs baseline: 1.2761x; 1.2761x over previous
//
#include <hip/hip_runtime.h>
#include <math.h>

#define Bb 8
#define Nn 1024
#define Kk 32
#define Dd 256
#define Hh 8
#define DHh 32
#define TDIMt 16
#define NBnb 32
#define HIDh 128
#define NSns 128
#define SHDs 9
#define EINe 304   // NB + TDIM + 2*NS
#define NCOLS 1536 // vproj 256 | hsrc 128 | hdst 128 | qw 1024

typedef __bf16 bf16_t;
typedef bf16_t bf16x8 __attribute__((ext_vector_type(8)));
typedef float floatx4 __attribute__((ext_vector_type(4)));

// global->LDS direct copy, 16B per lane; LDS dest must be linear in lane id.
#define GLOAD_LDS16(gp, lp) __builtin_amdgcn_global_load_lds( \
    (const __attribute__((address_space(1))) void*)(gp),      \
    (__attribute__((address_space(3))) void*)(lp), 16, 0, 0)

__device__ __forceinline__ float gelu_fast(float x){
  float g = 1.5957691216057308f*(x + 0.044715f*x*x*x);
  return x*__builtin_amdgcn_rcpf(1.0f + __expf(-g));
}
__device__ __forceinline__ float tanh_fast(float x){
  return 1.0f - 2.0f*__builtin_amdgcn_rcpf(1.0f + __expf(2.0f*x));
}

// ---------------- setup: knn FIRST, then preps, then embed ----------------
__global__ __launch_bounds__(256) void setup_kernel(
    const float* __restrict__ x, const float* __restrict__ y, const float* __restrict__ t,
    const float* __restrict__ We, const float* __restrict__ Wk1, const float* __restrict__ bk1,
    const float* __restrict__ Wk2, const float* __restrict__ Wq, const float* __restrict__ Wv,
    const float* __restrict__ Wo,
    bf16_t* __restrict__ Wt, bf16_t* __restrict__ Wto, bf16_t* __restrict__ WrbfT,
    float* __restrict__ t_hd, int* __restrict__ src,
    float* __restrict__ node, bf16_t* __restrict__ node_bf){

  __shared__ float s_b[32];
  __shared__ unsigned long long s_knn[4][64];
  const int bid = blockIdx.x, tid = threadIdx.x;

  if (bid < 2048){                       // ---- knn: threshold-select + compact + bitonic sort
    int wave = tid >> 6, lane = tid & 63;
    int bn = bid*4 + wave;
    int b = bn >> 10, n = bn & (Nn-1);
    const float* xb = x + (size_t)b*Nn*3;
    float px = xb[n*3+0], py = xb[n*3+1], pz = xb[n*3+2];
    float d2v[16];
    #pragma unroll
    for (int i=0;i<16;i++){
      int j = i*64 + lane;
      float dx = px - xb[j*3+0];
      float dy = py - xb[j*3+1];
      float dz = pz - xb[j*3+2];
      d2v[i] = dx*dx + dy*dy + dz*dz;
    }

    // find wave-uniform T with |{d2 <= T}| in [32,64]; interp-bisection on count
    unsigned lob = 0u, hib = 0x7149F2CAu;   // bits(1e30)
    float T = 1.0f;
    int lc = 0;
    for (int it=0; it<24; ++it){
      lc = 0;
      #pragma unroll
      for (int i=0;i<16;i++) lc += (d2v[i] <= T) ? 1 : 0;
      int c = lc;
      #pragma unroll
      for (int off=32; off>=1; off>>=1) c += __shfl_xor(c, off);
      if (c >= 32 && c <= 64) break;
      if (c < 32) lob = __float_as_uint(T); else hib = __float_as_uint(T);
      // cnt ~ T^(3/2) for small radii -> T_next = T*(target/c)^(2/3)
      float ratio = 44.0f * __builtin_amdgcn_rcpf((float)(c < 1 ? 1 : c));
      float Tn = T * __powf(ratio, 0.6666667f);
      unsigned tb = __float_as_uint(Tn);
      if (tb <= lob || tb >= hib) tb = lob + ((hib - lob) >> 1);
      T = __uint_as_float(tb);
    }

    // exclusive prefix of per-lane candidate counts
    int pre = lc;
    #pragma unroll
    for (int d=1; d<64; d<<=1){
      int o = __shfl_up(pre, d);
      if (lane >= d) pre += o;
    }
    int wo = pre - lc;   // this lane's base slot

    unsigned long long* sl = s_knn[wave];
    sl[lane] = ~0ull;    // pad with +inf keys (program-order before compact writes)
    #pragma unroll
    for (int i=0;i<16;i++){
      if (d2v[i] <= T && wo < 64){
        sl[wo] = (((unsigned long long)__float_as_uint(d2v[i])) << 10)
                 | (unsigned)(i*64 + lane);
        wo++;
      }
    }
    __syncthreads();

    // 64-element cross-lane bitonic sort on exact (d2,idx) keys, ascending
    unsigned long long key = sl[lane];
    #pragma unroll
    for (int k2=2; k2<=64; k2<<=1){
      #pragma unroll
      for (int j2=k2>>1; j2>=1; j2>>=1){
        unsigned long long pv = __shfl_xor(key, j2);
        bool takeMin = (((lane & j2) == 0) == ((lane & k2) == 0));
        bool pLess = pv < key;
        key = (pLess == takeMin) ? pv : key;
      }
    }
    if (lane < 32) src[(size_t)bn*Kk + lane] = (int)(key & 1023u);
  } else if (bid < 6144){                // ---- wprepM (coalesced)
    int i = bid-2048; int l = i>>10, yy = i&1023;
    int h = yy>>7, c = yy&127;
    if (tid < 32) s_b[tid] = Wk2[(size_t)l*HIDh*Dd + (size_t)c*Dd + h*DHh + tid];
    __syncthreads();
    const int rloc = tid>>3, dg = tid&7;
    const float b0 = s_b[dg*4+0], b1 = s_b[dg*4+1], b2 = s_b[dg*4+2], b3 = s_b[dg*4+3];
    #pragma unroll
    for (int p=0;p<8;p++){
      int ii = p*32 + rloc;
      const float4 v = *(const float4*)(Wq + (size_t)l*Dd*Dd + (size_t)ii*Dd + h*DHh + dg*4);
      float part = v.x*b0 + v.y*b1 + v.z*b2 + v.w*b3;
      part += __shfl_xor(part, 1);
      part += __shfl_xor(part, 2);
      part += __shfl_xor(part, 4);
      if (dg == 0) Wt[((size_t)l*NCOLS + 512 + yy)*Dd + ii] = (bf16_t)part;
    }
  } else if (bid < 8192){                // ---- wprep: Wt[l][c][k], c<512
    int i = bid-6144; int l = i>>9, c = i&511, k = tid;
    const float* wk1l = Wk1 + (size_t)l*EINe*HIDh;
    float v;
    if (c < 256)       v = Wv[(size_t)l*265*Dd + (size_t)k*Dd + c];
    else if (c < 384){ int c2 = c-256; v = (k < 128) ? wk1l[(48+k)*HIDh + c2] : 0.0f; }
    else             { int c2 = c-384; v = (k < 128) ? wk1l[(176+k)*HIDh + c2] : 0.0f; }
    Wt[((size_t)l*NCOLS + c)*Dd + k] = (bf16_t)v;
  } else if (bid < 8960){                // ---- wprepO
    int i = bid-8192; int l = i>>8; int c = i&255; int k = tid;
    Wto[((size_t)l*Dd + c)*Dd + k] = (bf16_t)Wo[(size_t)l*Dd*Dd + (size_t)k*Dd + c];
  } else if (bid < 9024){                // ---- wprepR
    int i = bid-8960; int l = i>>4, cg = i&15;
    int c = cg*8 + (tid>>5), k = tid&31;
    WrbfT[((size_t)l*HIDh + c)*NBnb + k] = (bf16_t)Wk1[(size_t)l*EINe*HIDh + (size_t)k*HIDh + c];
  } else if (bid < 9040){                // ---- tprep
    int i = bid-9024; int pair = i*2 + (tid>>7);
    int l = pair>>3, b = pair&7, c = tid&127;
    const float* wk1l = Wk1 + (size_t)l*EINe*HIDh;
    float a = bk1[l*HIDh + c];
    #pragma unroll
    for (int ii=0;ii<TDIMt;ii++) a += t[b*TDIMt+ii]*wk1l[(32+ii)*HIDh + c];
    t_hd[(l*Bb + b)*HIDh + c] = a;
  } else {                               // ---- embed (4 nodes/block)
    int bn0 = (bid-9040)*4; int c = tid;
    float w0 = We[0*Dd+c], w1 = We[1*Dd+c], w2 = We[2*Dd+c];
    float wt[TDIMt];
    #pragma unroll
    for (int i=0;i<TDIMt;i++) wt[i] = We[(3+i)*Dd+c];
    #pragma unroll
    for (int u=0;u<4;u++){
      int bn = bn0 + u; int b = bn >> 10;
      float a = y[(size_t)bn*3+0]*w0 + y[(size_t)bn*3+1]*w1 + y[(size_t)bn*3+2]*w2;
      #pragma unroll
      for (int i=0;i<TDIMt;i++) a += t[b*TDIMt+i]*wt[i];
      node[(size_t)bn*Dd + c] = a;
      node_bf[(size_t)bn*Dd + c] = (bf16_t)a;
    }
  }
}

// ---------------- proj GEMM (all layers): LDS-staged 128x64 tile, BK=64 dbuf ----------------
// A [8192 x 256] bf16 row-major; B = Wt[layer][col][k]. Epilogue scatter unchanged.
// blockIdx.x swizzled so batch == bx&7 == XCD.
__global__ __launch_bounds__(256) void gemm_proj(const bf16_t* __restrict__ A,
    const bf16_t* __restrict__ Wt_all, float* __restrict__ vproj_f,
    bf16_t* __restrict__ hsrc_bf, float* __restrict__ hdst_f,
    bf16_t* __restrict__ qw_bf, const float* __restrict__ t_hd, int layer){

  __shared__ __align__(16) bf16_t s_A[2][8192];   // [buf][128 rows][64 k] xor-swizzled
  __shared__ __align__(16) bf16_t s_B[2][4096];   // [buf][ 64 cols][64 k] xor-swizzled

  const int tid = threadIdx.x;
  const int wave = tid>>6, lane = tid&63;
  const int row16 = lane&15, quad = lane>>4;
  const int bx = blockIdx.x;
  const int brow = ((bx & 7) << 3) + (bx >> 3);    // batch = bx&7
  const int m0 = brow*128;
  const int m_base = m0 + wave*32;
  const int n_base = blockIdx.y*64;
  const bf16_t* Ab = A + (size_t)m0*Dd;
  const bf16_t* Bw = Wt_all + ((size_t)layer*NCOLS + n_base)*Dd;

  // staging geometry: thread t -> row trow (8 thr/row, 16B each), pre-swizzled k source
  const int trow = tid>>3;                          // 0..31
  const int tk   = ((tid&7) ^ (trow&7)) << 3;       // element offset, xor-swizzled
  const int swz  = (row16&7) << 3;                  // read-side xor (elements)

  floatx4 acc[2][4];
  #pragma unroll
  for (int mi=0;mi<2;mi++)
    #pragma unroll
    for (int ni=0;ni<4;ni++){ floatx4 z = {0.f,0.f,0.f,0.f}; acc[mi][ni] = z; }

  // prologue: stage kt=0 into buf 0
  {
    const bf16_t* ga = Ab + (size_t)trow*Dd + tk;
    #pragma unroll
    for (int i=0;i<4;i++) GLOAD_LDS16(ga + (size_t)i*32*Dd, &s_A[0][i*2048 + tid*8]);
    const bf16_t* gb = Bw + (size_t)trow*Dd + tk;
    #pragma unroll
    for (int j=0;j<2;j++) GLOAD_LDS16(gb + (size_t)j*32*Dd, &s_B[0][j*2048 + tid*8]);
  }
  __syncthreads();

  #pragma unroll
  for (int kt=0; kt<4; kt++){
    const int cur = kt&1, nxt = cur^1;
    if (kt < 3){
      const bf16_t* ga = Ab + (size_t)trow*Dd + (kt+1)*64 + tk;
      #pragma unroll
      for (int i=0;i<4;i++) GLOAD_LDS16(ga + (size_t)i*32*Dd, &s_A[nxt][i*2048 + tid*8]);
      const bf16_t* gb = Bw + (size_t)trow*Dd + (kt+1)*64 + tk;
      #pragma unroll
      for (int j=0;j<2;j++) GLOAD_LDS16(gb + (size_t)j*32*Dd, &s_B[nxt][j*2048 + tid*8]);
    }
    #pragma unroll
    for (int ksub=0; ksub<2; ksub++){
      const int ko = (ksub*32 + quad*8) ^ swz;
      bf16x8 a0 = *(const bf16x8*)&s_A[cur][(wave*32      + row16)*64 + ko];
      bf16x8 a1 = *(const bf16x8*)&s_A[cur][(wave*32 + 16 + row16)*64 + ko];
      #pragma unroll
      for (int ni=0;ni<4;ni++){
        bf16x8 b = *(const bf16x8*)&s_B[cur][(ni*16 + row16)*64 + ko];
        acc[0][ni] = __builtin_amdgcn_mfma_f32_16x16x32_bf16(a0, b, acc[0][ni], 0,0,0);
        acc[1][ni] = __builtin_amdgcn_mfma_f32_16x16x32_bf16(a1, b, acc[1][ni], 0,0,0);
      }
    }
    __syncthreads();
  }

  const int by = blockIdx.y;
  const int bb = m_base >> 10;
  #pragma unroll
  for (int mi=0;mi<2;mi++)
    #pragma unroll
    for (int ni=0;ni<4;ni++){
      int col = n_base + ni*16 + row16;
      #pragma unroll
      for (int r=0;r<4;r++){
        int row = m_base + mi*16 + quad*4 + r;
        float v = acc[mi][ni][r];
        if (by < 4)       vproj_f[(size_t)row*256 + col]        = v;
        else if (by < 6)  hsrc_bf[(size_t)row*128 + (col-256)]  = (bf16_t)v;
        else if (by < 8)  hdst_f[(size_t)row*128 + (col-384)]   = v + t_hd[(size_t)(layer*Bb + bb)*HIDh + (col-384)];
        else              qw_bf[(size_t)row*1024 + (col-512)]   = (bf16_t)v;
      }
    }
}

// ---------------- upd GEMM: node_out = act(agg @ Wto[lu] + node_in); writes f32 + bf16 ----------------
// Same staged structure, N=256 (grid y=4).
__global__ __launch_bounds__(256) void gemm_upd(
    const bf16_t* __restrict__ agg_bf, const bf16_t* __restrict__ Wto,
    const float* __restrict__ node_in, float* __restrict__ node_out,
    bf16_t* __restrict__ node_bf, int lu, int write_node){

  __shared__ __align__(16) bf16_t s_A[2][8192];
  __shared__ __align__(16) bf16_t s_B[2][4096];

  const int tid = threadIdx.x;
  const int wave = tid>>6, lane = tid&63;
  const int row16 = lane&15, quad = lane>>4;
  const int bx = blockIdx.x;
  const int brow = ((bx & 7) << 3) + (bx >> 3);
  const int m0 = brow*128;
  const int m_base = m0 + wave*32;
  const int n_base = blockIdx.y*64;
  const bf16_t* Ab = agg_bf + (size_t)m0*Dd;
  const bf16_t* Bw = Wto + (size_t)lu*Dd*Dd + (size_t)n_base*Dd;

  const int trow = tid>>3;
  const int tk   = ((tid&7) ^ (trow&7)) << 3;
  const int swz  = (row16&7) << 3;

  floatx4 acc[2][4];
  #pragma unroll
  for (int mi=0;mi<2;mi++)
    #pragma unroll
    for (int ni=0;ni<4;ni++){ floatx4 z = {0.f,0.f,0.f,0.f}; acc[mi][ni] = z; }

  {
    const bf16_t* ga = Ab + (size_t)trow*Dd + tk;
    #pragma unroll
    for (int i=0;i<4;i++) GLOAD_LDS16(ga + (size_t)i*32*Dd, &s_A[0][i*2048 + tid*8]);
    const bf16_t* gb = Bw + (size_t)trow*Dd + tk;
    #pragma unroll
    for (int j=0;j<2;j++) GLOAD_LDS16(gb + (size_t)j*32*Dd, &s_B[0][j*2048 + tid*8]);
  }
  __syncthreads();

  #pragma unroll
  for (int kt=0; kt<4; kt++){
    const int cur = kt&1, nxt = cur^1;
    if (kt < 3){
      const bf16_t* ga = Ab + (size_t)trow*Dd + (kt+1)*64 + tk;
      #pragma unroll
      for (int i=0;i<4;i++) GLOAD_LDS16(ga + (size_t)i*32*Dd, &s_A[nxt][i*2048 + tid*8]);
      const bf16_t* gb = Bw + (size_t)trow*Dd + (kt+1)*64 + tk;
      #pragma unroll
      for (int j=0;j<2;j++) GLOAD_LDS16(gb + (size_t)j*32*Dd, &s_B[nxt][j*2048 + tid*8]);
    }
    #pragma unroll
    for (int ksub=0; ksub<2; ksub++){
      const int ko = (ksub*32 + quad*8) ^ swz;
      bf16x8 a0 = *(const bf16x8*)&s_A[cur][(wave*32      + row16)*64 + ko];
      bf16x8 a1 = *(const bf16x8*)&s_A[cur][(wave*32 + 16 + row16)*64 + ko];
      #pragma unroll
      for (int ni=0;ni<4;ni++){
        bf16x8 b = *(const bf16x8*)&s_B[cur][(ni*16 + row16)*64 + ko];
        acc[0][ni] = __builtin_amdgcn_mfma_f32_16x16x32_bf16(a0, b, acc[0][ni], 0,0,0);
        acc[1][ni] = __builtin_amdgcn_mfma_f32_16x16x32_bf16(a1, b, acc[1][ni], 0,0,0);
      }
    }
    __syncthreads();
  }

  #pragma unroll
  for (int mi=0;mi<2;mi++)
    #pragma unroll
    for (int ni=0;ni<4;ni++){
      int col = n_base + ni*16 + row16;
      #pragma unroll
      for (int r=0;r<4;r++){
        int row = m_base + mi*16 + quad*4 + r;
        float v = acc[mi][ni][r] + node_in[(size_t)row*Dd + col];
        if (col < 64)       v = gelu_fast(v);
        else if (col < 128) v = tanh_fast(v);
        if (write_node) node_out[(size_t)row*Dd + col] = v;
        node_bf[(size_t)row*Dd + col] = (bf16_t)v;
      }
    }
}

// ---------------- attn: 1 node per 128-thread block (2 waves); batch->XCD swizzle ----------------
__global__ __launch_bounds__(128) void attn_kernel(
    const float* __restrict__ x, const int* __restrict__ src,
    const float* __restrict__ vproj_f, const bf16_t* __restrict__ hsrc_bf,
    const float* __restrict__ hdst_f, const bf16_t* __restrict__ qw_bf,
    const bf16_t* __restrict__ WrbfT,
    const float* __restrict__ Wvg, const float* __restrict__ Woo,
    bf16_t* __restrict__ agg_bf, float* __restrict__ out, int layer){

  __shared__ __align__(16) char smem[11488];
  bf16_t* s_h     = (bf16_t*)(smem);             // [32][136] bf16
  float*  s_part  = (float*)(smem);              // [2][256] f32 overlay (s_h dead)
  float*  s_sh    = (float*)(smem + 8704);       // [32][10]
  float*  s_cut   = (float*)(smem + 9984);       // [32]
  float*  s_logit = (float*)(smem + 10112);      // [32][8]
  float*  s_pool  = (float*)(smem + 11136);      // [8][10]
  float*  s_red   = (float*)(smem + 11456);      // [2][3]

  const int tid  = threadIdx.x;
  const int bidx = blockIdx.x;
  const int b    = bidx & 7;                     // batch -> XCD affinity
  const int bn   = (b << 10) | (bidx >> 3);      // node
  const int wv   = tid>>6, lane = tid&63;
  const int row16 = lane&15, quad = lane>>4;

  // per-node prefetches (hide latency under rbf + helper)
  bf16x8 qf[4];
  { const bf16_t* qp = qw_bf + (size_t)bn*1024 + row16*HIDh + quad*8;
    #pragma unroll
    for (int ks=0; ks<4; ks++) qf[ks] = *(const bf16x8*)(qp + ks*32); }
  float hdv[4];
  #pragma unroll
  for (int ni=0; ni<4; ni++) hdv[ni] = hdst_f[(size_t)bn*128 + wv*64 + ni*16 + row16];

  const float ax = x[(size_t)bn*3+0], ay = x[(size_t)bn*3+1], az = x[(size_t)bn*3+2];

  const int sE0 = src[(size_t)bn*Kk + row16];
  const int sE1 = src[(size_t)bn*Kk + row16 + 16];

  // hsrc gather: 128 threads cover 32 edges x 128 cols (4 x bf16x8 each)
  const int e0 = tid>>3, cg = tid&7;
  const int sG0 = src[(size_t)bn*Kk + e0];
  const int sG1 = src[(size_t)bn*Kk + e0 + 16];
  bf16x8 hsv00 = *(const bf16x8*)(hsrc_bf + ((size_t)b*Nn + sG0)*128 + cg*8);
  bf16x8 hsv01 = *(const bf16x8*)(hsrc_bf + ((size_t)b*Nn + sG0)*128 + cg*8 + 64);
  bf16x8 hsv10 = *(const bf16x8*)(hsrc_bf + ((size_t)b*Nn + sG1)*128 + cg*8);
  bf16x8 hsv11 = *(const bf16x8*)(hsrc_bf + ((size_t)b*Nn + sG1)*128 + cg*8 + 64);

  // rbf A-fragments via Gaussian recurrence
  bf16x8 a0f, a1f;
  {
    const float* xj0 = x + ((size_t)b*Nn + sE0)*3;
    const float* xj1 = x + ((size_t)b*Nn + sE1)*3;
    float d0x = ax - xj0[0], d0y = ay - xj0[1], d0z = az - xj0[2];
    float d1x = ax - xj1[0], d1y = ay - xj1[1], d1z = az - xj1[2];
    float rr0 = sqrtf(d0x*d0x + d0y*d0y + d0z*d0z);
    float rr1 = sqrtf(d1x*d1x + d1y*d1y + d1z*d1z);
    float xx0 = 10.0f*(1.0f - rr0*0.5f);
    float xx1 = 10.0f*(1.0f - rr1*0.5f);
    float cu0 = (xx0 > 0.0f) ? 1.4f*__expf(-__builtin_amdgcn_rcpf(xx0)) : 0.0f;
    float cu1 = (xx1 > 0.0f) ? 1.4f*__expf(-__builtin_amdgcn_rcpf(xx1)) : 0.0f;
    float sc0 = 4.798224586623f*cu0;
    float sc1 = 4.798224586623f*cu1;
    float rs0 = fminf(rr0*15.5f, 33.0f);
    float rs1 = fminf(rr1*15.5f, 33.0f);
    float cbase = (float)(quad*8);
    float dd0 = rs0 - cbase, dd1 = rs1 - cbase;
    float e0v = __expf(-dd0*dd0)*sc0;
    float e1v = __expf(-dd1*dd1)*sc1;
    float g0 = __expf(2.0f*dd0 - 1.0f);
    float g1 = __expf(2.0f*dd1 - 1.0f);
    a0f[0] = (bf16_t)e0v; a1f[0] = (bf16_t)e1v;
    #pragma unroll
    for (int j=1;j<8;j++){
      e0v *= g0; e1v *= g1;
      a0f[j] = (bf16_t)e0v; a1f[j] = (bf16_t)e1v;
      g0 *= 0.13533528323661270f; g1 *= 0.13533528323661270f;
    }
  }

  // helper: cut (tid<32) + sh (32<=tid<64)
  if (tid < 64){
    const int k = tid & 31;
    const int j = src[(size_t)bn*Kk + k];
    const float* xj = x + ((size_t)b*Nn + j)*3;
    float dx = ax - xj[0], dy = ay - xj[1], dz = az - xj[2];
    float rr = sqrtf(dx*dx + dy*dy + dz*dz);
    if (tid < 32){
      float xx = 10.0f*(1.0f - rr*0.5f);
      s_cut[k] = (xx > 0.0f) ? 1.4f*__expf(-__builtin_amdgcn_rcpf(xx)) : 0.0f;
    } else {
      float inv = __builtin_amdgcn_rcpf(fmaxf(rr, 1e-9f));
      float ux = dx*inv, uy = dy*inv, uz = dz*inv;
      float* sh = s_sh + k*10;
      sh[0] = 1.0f;
      sh[1] = 1.7320508075688772f*ux;
      sh[2] = 1.7320508075688772f*uy;
      sh[3] = 1.7320508075688772f*uz;
      sh[4] = 3.872983346207417f*ux*uy;
      sh[5] = 3.872983346207417f*uy*uz;
      sh[6] = 1.118033988749895f*(3.0f*uz*uz - 1.0f);
      sh[7] = 3.872983346207417f*ux*uz;
      sh[8] = 1.9364916731037085f*(ux*ux - uy*uy);
    }
  }

  // edge-MLP rbf MFMA: wave wv covers cols wv*64 .. wv*64+63
  floatx4 acc[2][4];
  {
    #pragma unroll
    for (int mi=0;mi<2;mi++)
      #pragma unroll
      for (int ni=0;ni<4;ni++){ floatx4 z = {0.f,0.f,0.f,0.f}; acc[mi][ni] = z; }
    const bf16_t* bp = WrbfT + ((size_t)layer*HIDh + wv*64 + row16)*NBnb + quad*8;
    #pragma unroll
    for (int j=0;j<4;j++){
      bf16x8 bbf = *(const bf16x8*)(bp + (size_t)j*16*NBnb);
      acc[0][j] = __builtin_amdgcn_mfma_f32_16x16x32_bf16(a0f, bbf, acc[0][j], 0,0,0);
      acc[1][j] = __builtin_amdgcn_mfma_f32_16x16x32_bf16(a1f, bbf, acc[1][j], 0,0,0);
    }
  }

  *(bf16x8*)(s_h + e0*136 + cg*8)            = hsv00;
  *(bf16x8*)(s_h + e0*136 + cg*8 + 64)       = hsv01;
  *(bf16x8*)(s_h + (e0+16)*136 + cg*8)       = hsv10;
  *(bf16x8*)(s_h + (e0+16)*136 + cg*8 + 64)  = hsv11;
  __syncthreads();

  // gelu combine: 32 elems/thread
  #pragma unroll
  for (int ni=0;ni<4;ni++){
    int c = wv*64 + ni*16 + row16;
    #pragma unroll
    for (int mi=0;mi<2;mi++){
      #pragma unroll
      for (int r=0;r<4;r++){
        int e = mi*16 + quad*4 + r;
        float hs = (float)s_h[e*136 + c];
        s_h[e*136 + c] = (bf16_t)gelu_fast(acc[mi][ni][r] + hdv[ni] + hs);
      }
    }
  }
  __syncthreads();

  // logits: wave wv covers edges wv*16..wv*16+15
  {
    floatx4 la = {0.f,0.f,0.f,0.f};
    #pragma unroll
    for (int ks=0; ks<4; ks++){
      bf16x8 a = *(const bf16x8*)(s_h + (wv*16 + row16)*136 + ks*32 + quad*8);
      la = __builtin_amdgcn_mfma_f32_16x16x32_bf16(a, qf[ks], la, 0,0,0);
    }
    if (row16 < Hh){
      #pragma unroll
      for (int r=0;r<4;r++)
        s_logit[(wv*16 + quad*4 + r)*8 + row16] = la[r]*0.17677669529663687f;
    }
  }
  __syncthreads();

  // softmax: each thread owns (k, h) and (k, h+4)
  {
    const int k = tid & 31;
    const int h0 = tid >> 5;             // 0..3
    #pragma unroll
    for (int hh=0; hh<2; hh++){
      const int h = h0 + hh*4;
      float lv = s_logit[k*8 + h];
      float m = lv;
      #pragma unroll
      for (int off=16; off>=1; off>>=1) m = fmaxf(m, __shfl_xor(m, off));
      float w = s_cut[k]*__expf(lv - m);
      float ss = w;
      #pragma unroll
      for (int off=16; off>=1; off>>=1) ss += __shfl_xor(ss, off);
      s_logit[k*8 + h] = w*__builtin_amdgcn_rcpf(ss + 1e-9f);
    }
  }
  __syncthreads();

  // sh-pool: 8 h x 16 slots on 128 threads (short pass)
  {
    const int h2 = tid>>4, sg = tid&15;
    if (sg < SHDs){
      float a = 0.0f;
      #pragma unroll
      for (int k2=0;k2<Kk;k2++)
        a += s_logit[k2*8 + h2] * s_sh[k2*10 + sg];
      s_pool[h2*10 + sg] = a;
    }
  }

  // main agg: wave handles 16 neighbor rows; lane covers 4 cols
  {
    const float* rowp[16];
    #pragma unroll
    for (int i=0;i<16;i++){
      int row = __builtin_amdgcn_readfirstlane(src[(size_t)bn*Kk + wv*16 + i]);
      rowp[i] = vproj_f + ((size_t)b*Nn + row)*256;
    }
    const int albase = wv*128 + (lane>>3);
    float4 accv = {0.f,0.f,0.f,0.f};
    #pragma unroll
    for (int i=0;i<16;i++){
      const float4 v = *(const float4*)(rowp[i] + (lane<<2));
      float al = s_logit[albase + i*8];
      accv.x += al*v.x; accv.y += al*v.y; accv.z += al*v.z; accv.w += al*v.w;
    }
    *(float4*)(s_part + wv*256 + (lane<<2)) = accv;
  }
  __syncthreads();

  // final: 128 threads cover 256 cols in 2 passes
  {
    const float* wvsh = Wvg + (size_t)layer*265*Dd + 256*Dd;
    float p0 = 0.f, p1 = 0.f, p2 = 0.f;
    #pragma unroll
    for (int cc=0; cc<2; cc++){
      const int c = tid + cc*128;
      const int h = c >> 5;
      float a_main = s_part[c] + s_part[256 + c];
      #pragma unroll
      for (int sg=0; sg<SHDs; sg++) a_main += s_pool[h*10 + sg]*wvsh[sg*Dd + c];

      if (layer < 3){
        agg_bf[(size_t)bn*Dd + c] = (bf16_t)a_main;
      } else {
        p0 += a_main*Woo[c*3+0];
        p1 += a_main*Woo[c*3+1];
        p2 += a_main*Woo[c*3+2];
      }
    }
    if (layer >= 3){
      #pragma unroll
      for (int off=32; off>=1; off>>=1){
        p0 += __shfl_xor(p0, off);
        p1 += __shfl_xor(p1, off);
        p2 += __shfl_xor(p2, off);
      }
      if (lane == 0){ s_red[wv*3+0]=p0; s_red[wv*3+1]=p1; s_red[wv*3+2]=p2; }
      __syncthreads();
      if (tid < 3)
        out[(size_t)bn*3 + tid] = s_red[tid] + s_red[3+tid];
    }
  }
}

extern "C" void kernel_launch(void* const* d_in, const int* in_sizes, int n_in,
                              void* d_out, int out_size, void* d_ws, size_t ws_size,
                              hipStream_t stream){
  const float* x   = (const float*)d_in[0];
  const float* y   = (const float*)d_in[1];
  const float* t   = (const float*)d_in[2];
  const float* We  = (const float*)d_in[3];
  const float* Wk1 = (const float*)d_in[4];
  const float* bk1 = (const float*)d_in[5];
  const float* Wk2 = (const float*)d_in[6];
  const float* Wq  = (const float*)d_in[7];
  const float* Wv  = (const float*)d_in[8];
  const float* Wo  = (const float*)d_in[9];
  const float* Woo = (const float*)d_in[10];
  float* out = (float*)d_out;

  char* ws = (char*)d_ws;
  size_t off = 0;
  auto take = [&](size_t bytes)->char*{ char* p = ws + off; off = (off + bytes + 255) & ~(size_t)255; return p; };

  int*    src      = (int*)   take((size_t)Bb*Nn*Kk*4);
  float*  nodeA    = (float*) take((size_t)Bb*Nn*Dd*4);
  float*  nodeB    = (float*) take((size_t)Bb*Nn*Dd*4);
  bf16_t* node_bf  = (bf16_t*)take((size_t)Bb*Nn*Dd*2);
  bf16_t* agg_bf   = (bf16_t*)take((size_t)Bb*Nn*Dd*2);
  float*  vproj_f  = (float*) take((size_t)Bb*Nn*256*4);
  bf16_t* hsrc_bf  = (bf16_t*)take((size_t)Bb*Nn*128*2);
  float*  hdst_f   = (float*) take((size_t)Bb*Nn*128*4);
  bf16_t* qw_bf    = (bf16_t*)take(((size_t)Bb*Nn*1024 + 2048)*2);  // +pad for B-frag overread
  bf16_t* Wt       = (bf16_t*)take((size_t)4*NCOLS*Dd*2);
  bf16_t* Wto      = (bf16_t*)take((size_t)3*Dd*Dd*2);
  bf16_t* WrbfT    = (bf16_t*)take((size_t)4*HIDh*NBnb*2);
  float*  t_hd     = (float*) take((size_t)4*Bb*HIDh*4);

  setup_kernel<<<dim3(11088), 256, 0, stream>>>(x, y, t, We, Wk1, bk1, Wk2, Wq, Wv, Wo,
                                                Wt, Wto, WrbfT, t_hd, src, nodeA, node_bf);

  gemm_proj<<<dim3(64,24), 256, 0, stream>>>(node_bf, Wt, vproj_f, hsrc_bf, hdst_f, qw_bf, t_hd, 0);
  attn_kernel<<<dim3(Bb*Nn), 128, 0, stream>>>(x, src, vproj_f, hsrc_bf, hdst_f, qw_bf,
                                               WrbfT, Wv, Woo, agg_bf, out, 0);
  // node f32 double-buffer: lu=0 reads A writes B; lu=1 reads B writes A; lu=2 reads A (bf16 only)
  const float* nin[3]  = {nodeA, nodeB, nodeA};
  float*       nout[3] = {nodeB, nodeA, nodeB};
  for (int l=1; l<4; l++){
    gemm_upd<<<dim3(64,4), 256, 0, stream>>>(agg_bf, Wto, nin[l-1], nout[l-1], node_bf,
                                             l-1, (l < 3) ? 1 : 0);
    gemm_proj<<<dim3(64,24), 256, 0, stream>>>(node_bf, Wt, vproj_f, hsrc_bf, hdst_f, qw_bf, t_hd, l);
    attn_kernel<<<dim3(Bb*Nn), 128, 0, stream>>>(x, src, vproj_f, hsrc_bf, hdst_f, qw_bf,
                                                 WrbfT, Wv, Woo, agg_bf, out, l);
  }
}

// Round 8
// 383.625 us; speedup vs baseline: 1.3271x; 1.0400x over previous
//
#include <hip/hip_runtime.h>
#include <math.h>

#define Bb 8
#define Nn 1024
#define Kk 32
#define Dd 256
#define Hh 8
#define DHh 32
#define TDIMt 16
#define NBnb 32
#define HIDh 128
#define NSns 128
#define SHDs 9
#define EINe 304   // NB + TDIM + 2*NS
#define NCOLS 1536 // vproj 256 | hsrc 128 | hdst 128 | qw 1024

typedef __bf16 bf16_t;
typedef bf16_t bf16x8 __attribute__((ext_vector_type(8)));
typedef bf16_t bf16x4v __attribute__((ext_vector_type(4)));
typedef float floatx4 __attribute__((ext_vector_type(4)));

// global->LDS direct copy, 16B per lane; LDS dest must be linear in lane id.
#define GLOAD_LDS16(gp, lp) __builtin_amdgcn_global_load_lds( \
    (const __attribute__((address_space(1))) void*)(gp),      \
    (__attribute__((address_space(3))) void*)(lp), 16, 0, 0)

__device__ __forceinline__ float gelu_fast(float x){
  float g = 1.5957691216057308f*(x + 0.044715f*x*x*x);
  return x*__builtin_amdgcn_rcpf(1.0f + __expf(-g));
}
__device__ __forceinline__ float tanh_fast(float x){
  return 1.0f - 2.0f*__builtin_amdgcn_rcpf(1.0f + __expf(2.0f*x));
}

// ---------------- setup: knn FIRST, then preps, then embed ----------------
__global__ __launch_bounds__(256) void setup_kernel(
    const float* __restrict__ x, const float* __restrict__ y, const float* __restrict__ t,
    const float* __restrict__ We, const float* __restrict__ Wk1, const float* __restrict__ bk1,
    const float* __restrict__ Wk2, const float* __restrict__ Wq, const float* __restrict__ Wv,
    const float* __restrict__ Wo,
    bf16_t* __restrict__ Wt, bf16_t* __restrict__ Wto, bf16_t* __restrict__ WrbfT,
    float* __restrict__ t_hd, int* __restrict__ src,
    float* __restrict__ node, bf16_t* __restrict__ node_bf){

  __shared__ float s_b[32];
  __shared__ unsigned long long s_knn[4][64];
  const int bid = blockIdx.x, tid = threadIdx.x;

  if (bid < 2048){                       // ---- knn: threshold-select + compact + bitonic sort
    int wave = tid >> 6, lane = tid & 63;
    int bn = bid*4 + wave;
    int b = bn >> 10, n = bn & (Nn-1);
    const float* xb = x + (size_t)b*Nn*3;
    float px = xb[n*3+0], py = xb[n*3+1], pz = xb[n*3+2];
    float d2v[16];
    #pragma unroll
    for (int i=0;i<16;i++){
      int j = i*64 + lane;
      float dx = px - xb[j*3+0];
      float dy = py - xb[j*3+1];
      float dz = pz - xb[j*3+2];
      d2v[i] = dx*dx + dy*dy + dz*dz;
    }

    // find wave-uniform T with |{d2 <= T}| in [32,64]; interp-bisection on count
    unsigned lob = 0u, hib = 0x7149F2CAu;   // bits(1e30)
    float T = 1.0f;
    int lc = 0;
    for (int it=0; it<24; ++it){
      lc = 0;
      #pragma unroll
      for (int i=0;i<16;i++) lc += (d2v[i] <= T) ? 1 : 0;
      int c = lc;
      #pragma unroll
      for (int off=32; off>=1; off>>=1) c += __shfl_xor(c, off);
      if (c >= 32 && c <= 64) break;
      if (c < 32) lob = __float_as_uint(T); else hib = __float_as_uint(T);
      // cnt ~ T^(3/2) for small radii -> T_next = T*(target/c)^(2/3)
      float ratio = 44.0f * __builtin_amdgcn_rcpf((float)(c < 1 ? 1 : c));
      float Tn = T * __powf(ratio, 0.6666667f);
      unsigned tb = __float_as_uint(Tn);
      if (tb <= lob || tb >= hib) tb = lob + ((hib - lob) >> 1);
      T = __uint_as_float(tb);
    }

    // exclusive prefix of per-lane candidate counts
    int pre = lc;
    #pragma unroll
    for (int d=1; d<64; d<<=1){
      int o = __shfl_up(pre, d);
      if (lane >= d) pre += o;
    }
    int wo = pre - lc;   // this lane's base slot

    unsigned long long* sl = s_knn[wave];
    sl[lane] = ~0ull;    // pad with +inf keys (program-order before compact writes)
    #pragma unroll
    for (int i=0;i<16;i++){
      if (d2v[i] <= T && wo < 64){
        sl[wo] = (((unsigned long long)__float_as_uint(d2v[i])) << 10)
                 | (unsigned)(i*64 + lane);
        wo++;
      }
    }
    __syncthreads();

    // 64-element cross-lane bitonic sort on exact (d2,idx) keys, ascending
    unsigned long long key = sl[lane];
    #pragma unroll
    for (int k2=2; k2<=64; k2<<=1){
      #pragma unroll
      for (int j2=k2>>1; j2>=1; j2>>=1){
        unsigned long long pv = __shfl_xor(key, j2);
        bool takeMin = (((lane & j2) == 0) == ((lane & k2) == 0));
        bool pLess = pv < key;
        key = (pLess == takeMin) ? pv : key;
      }
    }
    if (lane < 32) src[(size_t)bn*Kk + lane] = (int)(key & 1023u);
  } else if (bid < 6144){                // ---- wprepM (coalesced)
    int i = bid-2048; int l = i>>10, yy = i&1023;
    int h = yy>>7, c = yy&127;
    if (tid < 32) s_b[tid] = Wk2[(size_t)l*HIDh*Dd + (size_t)c*Dd + h*DHh + tid];
    __syncthreads();
    const int rloc = tid>>3, dg = tid&7;
    const float b0 = s_b[dg*4+0], b1 = s_b[dg*4+1], b2 = s_b[dg*4+2], b3 = s_b[dg*4+3];
    #pragma unroll
    for (int p=0;p<8;p++){
      int ii = p*32 + rloc;
      const float4 v = *(const float4*)(Wq + (size_t)l*Dd*Dd + (size_t)ii*Dd + h*DHh + dg*4);
      float part = v.x*b0 + v.y*b1 + v.z*b2 + v.w*b3;
      part += __shfl_xor(part, 1);
      part += __shfl_xor(part, 2);
      part += __shfl_xor(part, 4);
      if (dg == 0) Wt[((size_t)l*NCOLS + 512 + yy)*Dd + ii] = (bf16_t)part;
    }
  } else if (bid < 8192){                // ---- wprep: Wt[l][c][k], c<512
    int i = bid-6144; int l = i>>9, c = i&511, k = tid;
    const float* wk1l = Wk1 + (size_t)l*EINe*HIDh;
    float v;
    if (c < 256)       v = Wv[(size_t)l*265*Dd + (size_t)k*Dd + c];
    else if (c < 384){ int c2 = c-256; v = (k < 128) ? wk1l[(48+k)*HIDh + c2] : 0.0f; }
    else             { int c2 = c-384; v = (k < 128) ? wk1l[(176+k)*HIDh + c2] : 0.0f; }
    Wt[((size_t)l*NCOLS + c)*Dd + k] = (bf16_t)v;
  } else if (bid < 8960){                // ---- wprepO
    int i = bid-8192; int l = i>>8; int c = i&255; int k = tid;
    Wto[((size_t)l*Dd + c)*Dd + k] = (bf16_t)Wo[(size_t)l*Dd*Dd + (size_t)k*Dd + c];
  } else if (bid < 9024){                // ---- wprepR
    int i = bid-8960; int l = i>>4, cg = i&15;
    int c = cg*8 + (tid>>5), k = tid&31;
    WrbfT[((size_t)l*HIDh + c)*NBnb + k] = (bf16_t)Wk1[(size_t)l*EINe*HIDh + (size_t)k*HIDh + c];
  } else if (bid < 9040){                // ---- tprep
    int i = bid-9024; int pair = i*2 + (tid>>7);
    int l = pair>>3, b = pair&7, c = tid&127;
    const float* wk1l = Wk1 + (size_t)l*EINe*HIDh;
    float a = bk1[l*HIDh + c];
    #pragma unroll
    for (int ii=0;ii<TDIMt;ii++) a += t[b*TDIMt+ii]*wk1l[(32+ii)*HIDh + c];
    t_hd[(l*Bb + b)*HIDh + c] = a;
  } else {                               // ---- embed (4 nodes/block)
    int bn0 = (bid-9040)*4; int c = tid;
    float w0 = We[0*Dd+c], w1 = We[1*Dd+c], w2 = We[2*Dd+c];
    float wt[TDIMt];
    #pragma unroll
    for (int i=0;i<TDIMt;i++) wt[i] = We[(3+i)*Dd+c];
    #pragma unroll
    for (int u=0;u<4;u++){
      int bn = bn0 + u; int b = bn >> 10;
      float a = y[(size_t)bn*3+0]*w0 + y[(size_t)bn*3+1]*w1 + y[(size_t)bn*3+2]*w2;
      #pragma unroll
      for (int i=0;i<TDIMt;i++) a += t[b*TDIMt+i]*wt[i];
      node[(size_t)bn*Dd + c] = a;
      node_bf[(size_t)bn*Dd + c] = (bf16_t)a;
    }
  }
}

// ---------------- proj GEMM (all layers): LDS-staged 128x64 tile, BK=64 dbuf ----------------
__global__ __launch_bounds__(256) void gemm_proj(const bf16_t* __restrict__ A,
    const bf16_t* __restrict__ Wt_all, float* __restrict__ vproj_f,
    bf16_t* __restrict__ hsrc_bf, float* __restrict__ hdst_f,
    bf16_t* __restrict__ qw_bf, const float* __restrict__ t_hd, int layer){

  __shared__ __align__(16) bf16_t s_A[2][8192];   // [buf][128 rows][64 k] xor-swizzled
  __shared__ __align__(16) bf16_t s_B[2][4096];   // [buf][ 64 cols][64 k] xor-swizzled

  const int tid = threadIdx.x;
  const int wave = tid>>6, lane = tid&63;
  const int row16 = lane&15, quad = lane>>4;
  const int bx = blockIdx.x;
  const int brow = ((bx & 7) << 3) + (bx >> 3);    // batch = bx&7
  const int m0 = brow*128;
  const int m_base = m0 + wave*32;
  const int n_base = blockIdx.y*64;
  const bf16_t* Ab = A + (size_t)m0*Dd;
  const bf16_t* Bw = Wt_all + ((size_t)layer*NCOLS + n_base)*Dd;

  const int trow = tid>>3;                          // 0..31
  const int tk   = ((tid&7) ^ (trow&7)) << 3;       // element offset, xor-swizzled
  const int swz  = (row16&7) << 3;                  // read-side xor (elements)

  floatx4 acc[2][4];
  #pragma unroll
  for (int mi=0;mi<2;mi++)
    #pragma unroll
    for (int ni=0;ni<4;ni++){ floatx4 z = {0.f,0.f,0.f,0.f}; acc[mi][ni] = z; }

  {
    const bf16_t* ga = Ab + (size_t)trow*Dd + tk;
    #pragma unroll
    for (int i=0;i<4;i++) GLOAD_LDS16(ga + (size_t)i*32*Dd, &s_A[0][i*2048 + tid*8]);
    const bf16_t* gb = Bw + (size_t)trow*Dd + tk;
    #pragma unroll
    for (int j=0;j<2;j++) GLOAD_LDS16(gb + (size_t)j*32*Dd, &s_B[0][j*2048 + tid*8]);
  }
  __syncthreads();

  #pragma unroll
  for (int kt=0; kt<4; kt++){
    const int cur = kt&1, nxt = cur^1;
    if (kt < 3){
      const bf16_t* ga = Ab + (size_t)trow*Dd + (kt+1)*64 + tk;
      #pragma unroll
      for (int i=0;i<4;i++) GLOAD_LDS16(ga + (size_t)i*32*Dd, &s_A[nxt][i*2048 + tid*8]);
      const bf16_t* gb = Bw + (size_t)trow*Dd + (kt+1)*64 + tk;
      #pragma unroll
      for (int j=0;j<2;j++) GLOAD_LDS16(gb + (size_t)j*32*Dd, &s_B[nxt][j*2048 + tid*8]);
    }
    #pragma unroll
    for (int ksub=0; ksub<2; ksub++){
      const int ko = (ksub*32 + quad*8) ^ swz;
      bf16x8 a0 = *(const bf16x8*)&s_A[cur][(wave*32      + row16)*64 + ko];
      bf16x8 a1 = *(const bf16x8*)&s_A[cur][(wave*32 + 16 + row16)*64 + ko];
      #pragma unroll
      for (int ni=0;ni<4;ni++){
        bf16x8 b = *(const bf16x8*)&s_B[cur][(ni*16 + row16)*64 + ko];
        acc[0][ni] = __builtin_amdgcn_mfma_f32_16x16x32_bf16(a0, b, acc[0][ni], 0,0,0);
        acc[1][ni] = __builtin_amdgcn_mfma_f32_16x16x32_bf16(a1, b, acc[1][ni], 0,0,0);
      }
    }
    __syncthreads();
  }

  const int by = blockIdx.y;
  const int bb = m_base >> 10;
  #pragma unroll
  for (int mi=0;mi<2;mi++)
    #pragma unroll
    for (int ni=0;ni<4;ni++){
      int col = n_base + ni*16 + row16;
      #pragma unroll
      for (int r=0;r<4;r++){
        int row = m_base + mi*16 + quad*4 + r;
        float v = acc[mi][ni][r];
        if (by < 4)       vproj_f[(size_t)row*256 + col]        = v;
        else if (by < 6)  hsrc_bf[(size_t)row*128 + (col-256)]  = (bf16_t)v;
        else if (by < 8)  hdst_f[(size_t)row*128 + (col-384)]   = v + t_hd[(size_t)(layer*Bb + bb)*HIDh + (col-384)];
        else              qw_bf[(size_t)row*1024 + (col-512)]   = (bf16_t)v;
      }
    }
}

// ---------------- upd GEMM: node_out = act(agg @ Wto[lu] + node_in); writes f32 + bf16 ----------------
__global__ __launch_bounds__(256) void gemm_upd(
    const bf16_t* __restrict__ agg_bf, const bf16_t* __restrict__ Wto,
    const float* __restrict__ node_in, float* __restrict__ node_out,
    bf16_t* __restrict__ node_bf, int lu, int write_node){

  __shared__ __align__(16) bf16_t s_A[2][8192];
  __shared__ __align__(16) bf16_t s_B[2][4096];

  const int tid = threadIdx.x;
  const int wave = tid>>6, lane = tid&63;
  const int row16 = lane&15, quad = lane>>4;
  const int bx = blockIdx.x;
  const int brow = ((bx & 7) << 3) + (bx >> 3);
  const int m0 = brow*128;
  const int m_base = m0 + wave*32;
  const int n_base = blockIdx.y*64;
  const bf16_t* Ab = agg_bf + (size_t)m0*Dd;
  const bf16_t* Bw = Wto + (size_t)lu*Dd*Dd + (size_t)n_base*Dd;

  const int trow = tid>>3;
  const int tk   = ((tid&7) ^ (trow&7)) << 3;
  const int swz  = (row16&7) << 3;

  floatx4 acc[2][4];
  #pragma unroll
  for (int mi=0;mi<2;mi++)
    #pragma unroll
    for (int ni=0;ni<4;ni++){ floatx4 z = {0.f,0.f,0.f,0.f}; acc[mi][ni] = z; }

  {
    const bf16_t* ga = Ab + (size_t)trow*Dd + tk;
    #pragma unroll
    for (int i=0;i<4;i++) GLOAD_LDS16(ga + (size_t)i*32*Dd, &s_A[0][i*2048 + tid*8]);
    const bf16_t* gb = Bw + (size_t)trow*Dd + tk;
    #pragma unroll
    for (int j=0;j<2;j++) GLOAD_LDS16(gb + (size_t)j*32*Dd, &s_B[0][j*2048 + tid*8]);
  }
  __syncthreads();

  #pragma unroll
  for (int kt=0; kt<4; kt++){
    const int cur = kt&1, nxt = cur^1;
    if (kt < 3){
      const bf16_t* ga = Ab + (size_t)trow*Dd + (kt+1)*64 + tk;
      #pragma unroll
      for (int i=0;i<4;i++) GLOAD_LDS16(ga + (size_t)i*32*Dd, &s_A[nxt][i*2048 + tid*8]);
      const bf16_t* gb = Bw + (size_t)trow*Dd + (kt+1)*64 + tk;
      #pragma unroll
      for (int j=0;j<2;j++) GLOAD_LDS16(gb + (size_t)j*32*Dd, &s_B[nxt][j*2048 + tid*8]);
    }
    #pragma unroll
    for (int ksub=0; ksub<2; ksub++){
      const int ko = (ksub*32 + quad*8) ^ swz;
      bf16x8 a0 = *(const bf16x8*)&s_A[cur][(wave*32      + row16)*64 + ko];
      bf16x8 a1 = *(const bf16x8*)&s_A[cur][(wave*32 + 16 + row16)*64 + ko];
      #pragma unroll
      for (int ni=0;ni<4;ni++){
        bf16x8 b = *(const bf16x8*)&s_B[cur][(ni*16 + row16)*64 + ko];
        acc[0][ni] = __builtin_amdgcn_mfma_f32_16x16x32_bf16(a0, b, acc[0][ni], 0,0,0);
        acc[1][ni] = __builtin_amdgcn_mfma_f32_16x16x32_bf16(a1, b, acc[1][ni], 0,0,0);
      }
    }
    __syncthreads();
  }

  #pragma unroll
  for (int mi=0;mi<2;mi++)
    #pragma unroll
    for (int ni=0;ni<4;ni++){
      int col = n_base + ni*16 + row16;
      #pragma unroll
      for (int r=0;r<4;r++){
        int row = m_base + mi*16 + quad*4 + r;
        float v = acc[mi][ni][r] + node_in[(size_t)row*Dd + col];
        if (col < 64)       v = gelu_fast(v);
        else if (col < 128) v = tanh_fast(v);
        if (write_node) node_out[(size_t)row*Dd + col] = v;
        node_bf[(size_t)row*Dd + col] = (bf16_t)v;
      }
    }
}

// ---------------- attn: BARRIER-FREE, one wave per node (4 nodes/block) ----------------
__global__ __launch_bounds__(256) void attn_kernel(
    const float* __restrict__ x, const int* __restrict__ src,
    const float* __restrict__ vproj_f, const bf16_t* __restrict__ hsrc_bf,
    const float* __restrict__ hdst_f, const bf16_t* __restrict__ qw_bf,
    const bf16_t* __restrict__ WrbfT,
    const float* __restrict__ Wvg, const float* __restrict__ Woo,
    bf16_t* __restrict__ agg_bf, float* __restrict__ out, int layer){

  __shared__ __align__(16) char smem[46080];     // 4 waves x 11520B private slices
  const int tid  = threadIdx.x;
  const int wave = tid>>6, lane = tid&63;
  char* sw = smem + wave*11520;
  bf16_t* s_h   = (bf16_t*)(sw);                 // [32][136]
  float*  s_al  = (float*)(sw + 8704);           // [32][8] logits->alpha
  float*  s_sh  = (float*)(sw + 9728);           // [32][10]
  float*  s_cut = (float*)(sw + 11008);          // [32]
  float*  s_pool= (float*)(sw + 11136);          // [8][10]

  const int bidx = blockIdx.x;
  const int b    = bidx & 7;                     // batch -> XCD affinity
  const int bn   = (b << 10) | ((bidx >> 3) << 2) | wave;
  const int row16 = lane&15, quad = lane>>4;

  // ---- prefetches (per wave, no cross-wave deps) ----
  bf16x8 qf[4];
  { const bf16_t* qp = qw_bf + (size_t)bn*1024 + row16*HIDh + quad*8;
    #pragma unroll
    for (int ks=0; ks<4; ks++) qf[ks] = *(const bf16x8*)(qp + ks*32); }
  float hdv[8];
  #pragma unroll
  for (int j=0; j<8; j++) hdv[j] = hdst_f[(size_t)bn*128 + j*16 + row16];

  const float ax = x[(size_t)bn*3+0], ay = x[(size_t)bn*3+1], az = x[(size_t)bn*3+2];

  // hsrc gather: lane covers edge e=lane>>1, col-half (lane&1): 8 x bf16x8
  bf16x8 hsv[8];
  {
    const int eg = lane>>1, half = lane&1;
    const int sG = src[(size_t)bn*Kk + eg];
    const bf16_t* hp = hsrc_bf + ((size_t)b*Nn + sG)*128 + half*64;
    #pragma unroll
    for (int j=0;j<8;j++) hsv[j] = *(const bf16x8*)(hp + j*8);
  }

  // rbf A-fragments via Gaussian recurrence (edges row16, row16+16)
  const int sE0 = src[(size_t)bn*Kk + row16];
  const int sE1 = src[(size_t)bn*Kk + row16 + 16];
  bf16x8 a0f, a1f;
  {
    const float* xj0 = x + ((size_t)b*Nn + sE0)*3;
    const float* xj1 = x + ((size_t)b*Nn + sE1)*3;
    float d0x = ax - xj0[0], d0y = ay - xj0[1], d0z = az - xj0[2];
    float d1x = ax - xj1[0], d1y = ay - xj1[1], d1z = az - xj1[2];
    float rr0 = sqrtf(d0x*d0x + d0y*d0y + d0z*d0z);
    float rr1 = sqrtf(d1x*d1x + d1y*d1y + d1z*d1z);
    float xx0 = 10.0f*(1.0f - rr0*0.5f);
    float xx1 = 10.0f*(1.0f - rr1*0.5f);
    float cu0 = (xx0 > 0.0f) ? 1.4f*__expf(-__builtin_amdgcn_rcpf(xx0)) : 0.0f;
    float cu1 = (xx1 > 0.0f) ? 1.4f*__expf(-__builtin_amdgcn_rcpf(xx1)) : 0.0f;
    float sc0 = 4.798224586623f*cu0;
    float sc1 = 4.798224586623f*cu1;
    float rs0 = fminf(rr0*15.5f, 33.0f);
    float rs1 = fminf(rr1*15.5f, 33.0f);
    float cbase = (float)(quad*8);
    float dd0 = rs0 - cbase, dd1 = rs1 - cbase;
    float e0v = __expf(-dd0*dd0)*sc0;
    float e1v = __expf(-dd1*dd1)*sc1;
    float g0 = __expf(2.0f*dd0 - 1.0f);
    float g1 = __expf(2.0f*dd1 - 1.0f);
    a0f[0] = (bf16_t)e0v; a1f[0] = (bf16_t)e1v;
    #pragma unroll
    for (int j=1;j<8;j++){
      e0v *= g0; e1v *= g1;
      a0f[j] = (bf16_t)e0v; a1f[j] = (bf16_t)e1v;
      g0 *= 0.13533528323661270f; g1 *= 0.13533528323661270f;
    }
  }

  // cut (lanes 0-31) + sh (lanes 32-63), wave-private
  {
    const int k = lane & 31;
    const int j = src[(size_t)bn*Kk + k];
    const float* xj = x + ((size_t)b*Nn + j)*3;
    float dx = ax - xj[0], dy = ay - xj[1], dz = az - xj[2];
    float rr = sqrtf(dx*dx + dy*dy + dz*dz);
    if (lane < 32){
      float xx = 10.0f*(1.0f - rr*0.5f);
      s_cut[k] = (xx > 0.0f) ? 1.4f*__expf(-__builtin_amdgcn_rcpf(xx)) : 0.0f;
    } else {
      float inv = __builtin_amdgcn_rcpf(fmaxf(rr, 1e-9f));
      float ux = dx*inv, uy = dy*inv, uz = dz*inv;
      float* sh = s_sh + k*10;
      sh[0] = 1.0f;
      sh[1] = 1.7320508075688772f*ux;
      sh[2] = 1.7320508075688772f*uy;
      sh[3] = 1.7320508075688772f*uz;
      sh[4] = 3.872983346207417f*ux*uy;
      sh[5] = 3.872983346207417f*uy*uz;
      sh[6] = 1.118033988749895f*(3.0f*uz*uz - 1.0f);
      sh[7] = 3.872983346207417f*ux*uz;
      sh[8] = 1.9364916731037085f*(ux*ux - uy*uy);
    }
  }

  // rbf MFMA: wave covers all 128 cols (8 n-frags), edges 0-15 (acc0) & 16-31 (acc1)
  floatx4 acc0[8], acc1[8];
  {
    const bf16_t* bp = WrbfT + ((size_t)layer*HIDh + row16)*NBnb + quad*8;
    #pragma unroll
    for (int j=0;j<8;j++){
      floatx4 z = {0.f,0.f,0.f,0.f};
      bf16x8 bbf = *(const bf16x8*)(bp + (size_t)j*16*NBnb);
      acc0[j] = __builtin_amdgcn_mfma_f32_16x16x32_bf16(a0f, bbf, z, 0,0,0);
      acc1[j] = __builtin_amdgcn_mfma_f32_16x16x32_bf16(a1f, bbf, z, 0,0,0);
    }
  }

  // stage hsrc into s_h (wave-private; lgkm ordering by compiler)
  {
    const int eg = lane>>1, half = lane&1;
    #pragma unroll
    for (int j=0;j<8;j++)
      *(bf16x8*)(s_h + eg*136 + half*64 + j*8) = hsv[j];
  }

  // gelu combine: 64 elems/lane (col j*16+row16, edges quad*4+r and +16)
  #pragma unroll
  for (int j=0;j<8;j++){
    const int c = j*16 + row16;
    const float hd = hdv[j];
    #pragma unroll
    for (int r=0;r<4;r++){
      int e = quad*4 + r;
      float hs = (float)s_h[e*136 + c];
      s_h[e*136 + c] = (bf16_t)gelu_fast(acc0[j][r] + hd + hs);
    }
    #pragma unroll
    for (int r=0;r<4;r++){
      int e = 16 + quad*4 + r;
      float hs = (float)s_h[e*136 + c];
      s_h[e*136 + c] = (bf16_t)gelu_fast(acc1[j][r] + hd + hs);
    }
  }

  // logits: 2 row-groups x 4 k-steps
  floatx4 la[2];
  #pragma unroll
  for (int rg=0; rg<2; rg++){
    floatx4 l4 = {0.f,0.f,0.f,0.f};
    #pragma unroll
    for (int ks=0; ks<4; ks++){
      bf16x8 a = *(const bf16x8*)(s_h + (rg*16 + row16)*136 + ks*32 + quad*8);
      l4 = __builtin_amdgcn_mfma_f32_16x16x32_bf16(a, qf[ks], l4, 0,0,0);
    }
    la[rg] = l4;
  }

  // softmax in-register: lane holds 8 logits for h=row16 (e = rg*16+quad*4+r)
  {
    float lv[8], ct[8];
    #pragma unroll
    for (int rg=0; rg<2; rg++)
      #pragma unroll
      for (int r=0;r<4;r++){
        lv[rg*4+r] = la[rg][r]*0.17677669529663687f;
        ct[rg*4+r] = s_cut[rg*16 + quad*4 + r];
      }
    float m = lv[0];
    #pragma unroll
    for (int i=1;i<8;i++) m = fmaxf(m, lv[i]);
    m = fmaxf(m, __shfl_xor(m, 16));
    m = fmaxf(m, __shfl_xor(m, 32));
    float w[8]; float ss = 0.f;
    #pragma unroll
    for (int i=0;i<8;i++){ w[i] = ct[i]*__expf(lv[i]-m); ss += w[i]; }
    ss += __shfl_xor(ss, 16);
    ss += __shfl_xor(ss, 32);
    float rs = __builtin_amdgcn_rcpf(ss + 1e-9f);
    if (row16 < Hh){
      #pragma unroll
      for (int rg=0; rg<2; rg++)
        #pragma unroll
        for (int r=0;r<4;r++)
          s_al[(rg*16 + quad*4 + r)*8 + row16] = w[rg*4+r]*rs;
    }
  }

  // sh-pool: lanes cover 8h x 8sg; lanes 0-7 also sg=8
  {
    const int h2 = lane>>3, sg = lane&7;
    float a = 0.0f;
    #pragma unroll
    for (int k2=0;k2<Kk;k2++)
      a += s_al[k2*8 + h2] * s_sh[k2*10 + sg];
    s_pool[h2*10 + sg] = a;
    if (lane < 8){
      float a8 = 0.0f;
      #pragma unroll
      for (int k2=0;k2<Kk;k2++)
        a8 += s_al[k2*8 + lane] * s_sh[k2*10 + 8];
      s_pool[lane*10 + 8] = a8;
    }
  }

  // main agg: lane owns 4 cols (lane*4); 32 rows in 4 chunks of 8
  float4 accv = {0.f,0.f,0.f,0.f};
  {
    const int h = lane>>3;
    #pragma unroll
    for (int g=0; g<4; g++){
      const float* rp[8];
      #pragma unroll
      for (int i=0;i<8;i++){
        int row = __builtin_amdgcn_readfirstlane(src[(size_t)bn*Kk + g*8 + i]);
        rp[i] = vproj_f + ((size_t)b*Nn + row)*256;
      }
      #pragma unroll
      for (int i=0;i<8;i++){
        const float4 v = *(const float4*)(rp[i] + (lane<<2));
        float al = s_al[(g*8+i)*8 + h];
        accv.x += al*v.x; accv.y += al*v.y; accv.z += al*v.z; accv.w += al*v.w;
      }
    }
  }

  // final: 4 cols/lane
  {
    const int h = lane>>3;
    const float* wvsh = Wvg + (size_t)layer*265*Dd + 256*Dd;
    #pragma unroll
    for (int sg=0; sg<SHDs; sg++){
      const float4 wv4 = *(const float4*)(wvsh + sg*Dd + (lane<<2));
      const float pl = s_pool[h*10 + sg];
      accv.x += pl*wv4.x; accv.y += pl*wv4.y; accv.z += pl*wv4.z; accv.w += pl*wv4.w;
    }

    if (layer < 3){
      bf16x4v o;
      o[0] = (bf16_t)accv.x; o[1] = (bf16_t)accv.y;
      o[2] = (bf16_t)accv.z; o[3] = (bf16_t)accv.w;
      *(bf16x4v*)(agg_bf + (size_t)bn*Dd + (lane<<2)) = o;
    } else {
      const int c0 = lane<<2;
      float p0 = accv.x*Woo[c0*3+0] + accv.y*Woo[c0*3+3] + accv.z*Woo[c0*3+6] + accv.w*Woo[c0*3+9];
      float p1 = accv.x*Woo[c0*3+1] + accv.y*Woo[c0*3+4] + accv.z*Woo[c0*3+7] + accv.w*Woo[c0*3+10];
      float p2 = accv.x*Woo[c0*3+2] + accv.y*Woo[c0*3+5] + accv.z*Woo[c0*3+8] + accv.w*Woo[c0*3+11];
      #pragma unroll
      for (int off=32; off>=1; off>>=1){
        p0 += __shfl_xor(p0, off);
        p1 += __shfl_xor(p1, off);
        p2 += __shfl_xor(p2, off);
      }
      if (lane == 0){
        out[(size_t)bn*3+0] = p0;
        out[(size_t)bn*3+1] = p1;
        out[(size_t)bn*3+2] = p2;
      }
    }
  }
}

extern "C" void kernel_launch(void* const* d_in, const int* in_sizes, int n_in,
                              void* d_out, int out_size, void* d_ws, size_t ws_size,
                              hipStream_t stream){
  const float* x   = (const float*)d_in[0];
  const float* y   = (const float*)d_in[1];
  const float* t   = (const float*)d_in[2];
  const float* We  = (const float*)d_in[3];
  const float* Wk1 = (const float*)d_in[4];
  const float* bk1 = (const float*)d_in[5];
  const float* Wk2 = (const float*)d_in[6];
  const float* Wq  = (const float*)d_in[7];
  const float* Wv  = (const float*)d_in[8];
  const float* Wo  = (const float*)d_in[9];
  const float* Woo = (const float*)d_in[10];
  float* out = (float*)d_out;

  char* ws = (char*)d_ws;
  size_t off = 0;
  auto take = [&](size_t bytes)->char*{ char* p = ws + off; off = (off + bytes + 255) & ~(size_t)255; return p; };

  int*    src      = (int*)   take((size_t)Bb*Nn*Kk*4);
  float*  nodeA    = (float*) take((size_t)Bb*Nn*Dd*4);
  float*  nodeB    = (float*) take((size_t)Bb*Nn*Dd*4);
  bf16_t* node_bf  = (bf16_t*)take((size_t)Bb*Nn*Dd*2);
  bf16_t* agg_bf   = (bf16_t*)take((size_t)Bb*Nn*Dd*2);
  float*  vproj_f  = (float*) take((size_t)Bb*Nn*256*4);
  bf16_t* hsrc_bf  = (bf16_t*)take((size_t)Bb*Nn*128*2);
  float*  hdst_f   = (float*) take((size_t)Bb*Nn*128*4);
  bf16_t* qw_bf    = (bf16_t*)take(((size_t)Bb*Nn*1024 + 2048)*2);  // +pad for B-frag overread
  bf16_t* Wt       = (bf16_t*)take((size_t)4*NCOLS*Dd*2);
  bf16_t* Wto      = (bf16_t*)take((size_t)3*Dd*Dd*2);
  bf16_t* WrbfT    = (bf16_t*)take((size_t)4*HIDh*NBnb*2);
  float*  t_hd     = (float*) take((size_t)4*Bb*HIDh*4);

  setup_kernel<<<dim3(11088), 256, 0, stream>>>(x, y, t, We, Wk1, bk1, Wk2, Wq, Wv, Wo,
                                                Wt, Wto, WrbfT, t_hd, src, nodeA, node_bf);

  gemm_proj<<<dim3(64,24), 256, 0, stream>>>(node_bf, Wt, vproj_f, hsrc_bf, hdst_f, qw_bf, t_hd, 0);
  attn_kernel<<<dim3(Bb*Nn/4), 256, 0, stream>>>(x, src, vproj_f, hsrc_bf, hdst_f, qw_bf,
                                                 WrbfT, Wv, Woo, agg_bf, out, 0);
  // node f32 double-buffer: lu=0 reads A writes B; lu=1 reads B writes A; lu=2 reads A (bf16 only)
  const float* nin[3]  = {nodeA, nodeB, nodeA};
  float*       nout[3] = {nodeB, nodeA, nodeB};
  for (int l=1; l<4; l++){
    gemm_upd<<<dim3(64,4), 256, 0, stream>>>(agg_bf, Wto, nin[l-1], nout[l-1], node_bf,
                                             l-1, (l < 3) ? 1 : 0);
    gemm_proj<<<dim3(64,24), 256, 0, stream>>>(node_bf, Wt, vproj_f, hsrc_bf, hdst_f, qw_bf, t_hd, l);
    attn_kernel<<<dim3(Bb*Nn/4), 256, 0, stream>>>(x, src, vproj_f, hsrc_bf, hdst_f, qw_bf,
                                                   WrbfT, Wv, Woo, agg_bf, out, l);
  }
}

// Round 9
// 370.252 us; speedup vs baseline: 1.3750x; 1.0361x over previous
//
#include <hip/hip_runtime.h>
#include <math.h>

#define Bb 8
#define Nn 1024
#define Kk 32
#define Dd 256
#define Hh 8
#define DHh 32
#define TDIMt 16
#define NBnb 32
#define HIDh 128
#define NSns 128
#define SHDs 9
#define EINe 304   // NB + TDIM + 2*NS
#define NCOLS 1536 // vproj 256 | hsrc 128 | hdst 128 | qw 1024

typedef __bf16 bf16_t;
typedef bf16_t bf16x8 __attribute__((ext_vector_type(8)));
typedef bf16_t bf16x4v __attribute__((ext_vector_type(4)));
typedef float floatx4 __attribute__((ext_vector_type(4)));

// global->LDS direct copy, 16B per lane; LDS dest must be linear in lane id.
#define GLOAD_LDS16(gp, lp) __builtin_amdgcn_global_load_lds( \
    (const __attribute__((address_space(1))) void*)(gp),      \
    (__attribute__((address_space(3))) void*)(lp), 16, 0, 0)

__device__ __forceinline__ float gelu_fast(float x){
  float g = 1.5957691216057308f*(x + 0.044715f*x*x*x);
  return x*__builtin_amdgcn_rcpf(1.0f + __expf(-g));
}
__device__ __forceinline__ float tanh_fast(float x){
  return 1.0f - 2.0f*__builtin_amdgcn_rcpf(1.0f + __expf(2.0f*x));
}

// ---------------- setup: knn FIRST, then preps, then embed ----------------
__global__ __launch_bounds__(256) void setup_kernel(
    const float* __restrict__ x, const float* __restrict__ y, const float* __restrict__ t,
    const float* __restrict__ We, const float* __restrict__ Wk1, const float* __restrict__ bk1,
    const float* __restrict__ Wk2, const float* __restrict__ Wq, const float* __restrict__ Wv,
    const float* __restrict__ Wo,
    bf16_t* __restrict__ Wt, bf16_t* __restrict__ Wto, bf16_t* __restrict__ WrbfT,
    float* __restrict__ t_hd, int* __restrict__ src,
    float* __restrict__ node, bf16_t* __restrict__ node_bf){

  __shared__ float s_b[32];
  __shared__ unsigned long long s_knn[4][64];
  const int bid = blockIdx.x, tid = threadIdx.x;

  if (bid < 2048){                       // ---- knn: threshold-select + compact + bitonic sort
    int wave = tid >> 6, lane = tid & 63;
    int bn = bid*4 + wave;
    int b = bn >> 10, n = bn & (Nn-1);
    const float* xb = x + (size_t)b*Nn*3;
    float px = xb[n*3+0], py = xb[n*3+1], pz = xb[n*3+2];
    float d2v[16];
    #pragma unroll
    for (int i=0;i<16;i++){
      int j = i*64 + lane;
      float dx = px - xb[j*3+0];
      float dy = py - xb[j*3+1];
      float dz = pz - xb[j*3+2];
      d2v[i] = dx*dx + dy*dy + dz*dz;
    }

    // find wave-uniform T with |{d2 <= T}| in [32,64]; interp-bisection on count
    unsigned lob = 0u, hib = 0x7149F2CAu;   // bits(1e30)
    float T = 1.0f;
    int lc = 0;
    for (int it=0; it<24; ++it){
      lc = 0;
      #pragma unroll
      for (int i=0;i<16;i++) lc += (d2v[i] <= T) ? 1 : 0;
      int c = lc;
      #pragma unroll
      for (int off=32; off>=1; off>>=1) c += __shfl_xor(c, off);
      if (c >= 32 && c <= 64) break;
      if (c < 32) lob = __float_as_uint(T); else hib = __float_as_uint(T);
      // cnt ~ T^(3/2) for small radii -> T_next = T*(target/c)^(2/3)
      float ratio = 44.0f * __builtin_amdgcn_rcpf((float)(c < 1 ? 1 : c));
      float Tn = T * __powf(ratio, 0.6666667f);
      unsigned tb = __float_as_uint(Tn);
      if (tb <= lob || tb >= hib) tb = lob + ((hib - lob) >> 1);
      T = __uint_as_float(tb);
    }

    // exclusive prefix of per-lane candidate counts
    int pre = lc;
    #pragma unroll
    for (int d=1; d<64; d<<=1){
      int o = __shfl_up(pre, d);
      if (lane >= d) pre += o;
    }
    int wo = pre - lc;   // this lane's base slot

    unsigned long long* sl = s_knn[wave];
    sl[lane] = ~0ull;    // pad with +inf keys (program-order before compact writes)
    #pragma unroll
    for (int i=0;i<16;i++){
      if (d2v[i] <= T && wo < 64){
        sl[wo] = (((unsigned long long)__float_as_uint(d2v[i])) << 10)
                 | (unsigned)(i*64 + lane);
        wo++;
      }
    }
    __syncthreads();

    // 64-element cross-lane bitonic sort on exact (d2,idx) keys, ascending
    unsigned long long key = sl[lane];
    #pragma unroll
    for (int k2=2; k2<=64; k2<<=1){
      #pragma unroll
      for (int j2=k2>>1; j2>=1; j2>>=1){
        unsigned long long pv = __shfl_xor(key, j2);
        bool takeMin = (((lane & j2) == 0) == ((lane & k2) == 0));
        bool pLess = pv < key;
        key = (pLess == takeMin) ? pv : key;
      }
    }
    if (lane < 32) src[(size_t)bn*Kk + lane] = (int)(key & 1023u);
  } else if (bid < 6144){                // ---- wprepM (coalesced)
    int i = bid-2048; int l = i>>10, yy = i&1023;
    int h = yy>>7, c = yy&127;
    if (tid < 32) s_b[tid] = Wk2[(size_t)l*HIDh*Dd + (size_t)c*Dd + h*DHh + tid];
    __syncthreads();
    const int rloc = tid>>3, dg = tid&7;
    const float b0 = s_b[dg*4+0], b1 = s_b[dg*4+1], b2 = s_b[dg*4+2], b3 = s_b[dg*4+3];
    #pragma unroll
    for (int p=0;p<8;p++){
      int ii = p*32 + rloc;
      const float4 v = *(const float4*)(Wq + (size_t)l*Dd*Dd + (size_t)ii*Dd + h*DHh + dg*4);
      float part = v.x*b0 + v.y*b1 + v.z*b2 + v.w*b3;
      part += __shfl_xor(part, 1);
      part += __shfl_xor(part, 2);
      part += __shfl_xor(part, 4);
      if (dg == 0) Wt[((size_t)l*NCOLS + 512 + yy)*Dd + ii] = (bf16_t)part;
    }
  } else if (bid < 8192){                // ---- wprep: Wt[l][c][k], c<512
    int i = bid-6144; int l = i>>9, c = i&511, k = tid;
    const float* wk1l = Wk1 + (size_t)l*EINe*HIDh;
    float v;
    if (c < 256)       v = Wv[(size_t)l*265*Dd + (size_t)k*Dd + c];
    else if (c < 384){ int c2 = c-256; v = (k < 128) ? wk1l[(48+k)*HIDh + c2] : 0.0f; }
    else             { int c2 = c-384; v = (k < 128) ? wk1l[(176+k)*HIDh + c2] : 0.0f; }
    Wt[((size_t)l*NCOLS + c)*Dd + k] = (bf16_t)v;
  } else if (bid < 8960){                // ---- wprepO
    int i = bid-8192; int l = i>>8; int c = i&255; int k = tid;
    Wto[((size_t)l*Dd + c)*Dd + k] = (bf16_t)Wo[(size_t)l*Dd*Dd + (size_t)k*Dd + c];
  } else if (bid < 9024){                // ---- wprepR
    int i = bid-8960; int l = i>>4, cg = i&15;
    int c = cg*8 + (tid>>5), k = tid&31;
    WrbfT[((size_t)l*HIDh + c)*NBnb + k] = (bf16_t)Wk1[(size_t)l*EINe*HIDh + (size_t)k*HIDh + c];
  } else if (bid < 9040){                // ---- tprep
    int i = bid-9024; int pair = i*2 + (tid>>7);
    int l = pair>>3, b = pair&7, c = tid&127;
    const float* wk1l = Wk1 + (size_t)l*EINe*HIDh;
    float a = bk1[l*HIDh + c];
    #pragma unroll
    for (int ii=0;ii<TDIMt;ii++) a += t[b*TDIMt+ii]*wk1l[(32+ii)*HIDh + c];
    t_hd[(l*Bb + b)*HIDh + c] = a;
  } else {                               // ---- embed (4 nodes/block)
    int bn0 = (bid-9040)*4; int c = tid;
    float w0 = We[0*Dd+c], w1 = We[1*Dd+c], w2 = We[2*Dd+c];
    float wt[TDIMt];
    #pragma unroll
    for (int i=0;i<TDIMt;i++) wt[i] = We[(3+i)*Dd+c];
    #pragma unroll
    for (int u=0;u<4;u++){
      int bn = bn0 + u; int b = bn >> 10;
      float a = y[(size_t)bn*3+0]*w0 + y[(size_t)bn*3+1]*w1 + y[(size_t)bn*3+2]*w2;
      #pragma unroll
      for (int i=0;i<TDIMt;i++) a += t[b*TDIMt+i]*wt[i];
      node[(size_t)bn*Dd + c] = a;
      node_bf[(size_t)bn*Dd + c] = (bf16_t)a;
    }
  }
}

// ---------------- proj GEMM (all layers): LDS-staged 128x64 tile, BK=64 dbuf ----------------
__global__ __launch_bounds__(256) void gemm_proj(const bf16_t* __restrict__ A,
    const bf16_t* __restrict__ Wt_all, float* __restrict__ vproj_f,
    bf16_t* __restrict__ hsrc_bf, float* __restrict__ hdst_f,
    bf16_t* __restrict__ qw_bf, const float* __restrict__ t_hd, int layer){

  __shared__ __align__(16) bf16_t s_A[2][8192];   // [buf][128 rows][64 k] xor-swizzled
  __shared__ __align__(16) bf16_t s_B[2][4096];   // [buf][ 64 cols][64 k] xor-swizzled

  const int tid = threadIdx.x;
  const int wave = tid>>6, lane = tid&63;
  const int row16 = lane&15, quad = lane>>4;
  const int bx = blockIdx.x;
  const int brow = ((bx & 7) << 3) + (bx >> 3);    // batch = bx&7
  const int m0 = brow*128;
  const int m_base = m0 + wave*32;
  const int n_base = blockIdx.y*64;
  const bf16_t* Ab = A + (size_t)m0*Dd;
  const bf16_t* Bw = Wt_all + ((size_t)layer*NCOLS + n_base)*Dd;

  const int trow = tid>>3;                          // 0..31
  const int tk   = ((tid&7) ^ (trow&7)) << 3;       // element offset, xor-swizzled
  const int swz  = (row16&7) << 3;                  // read-side xor (elements)

  floatx4 acc[2][4];
  #pragma unroll
  for (int mi=0;mi<2;mi++)
    #pragma unroll
    for (int ni=0;ni<4;ni++){ floatx4 z = {0.f,0.f,0.f,0.f}; acc[mi][ni] = z; }

  {
    const bf16_t* ga = Ab + (size_t)trow*Dd + tk;
    #pragma unroll
    for (int i=0;i<4;i++) GLOAD_LDS16(ga + (size_t)i*32*Dd, &s_A[0][i*2048 + tid*8]);
    const bf16_t* gb = Bw + (size_t)trow*Dd + tk;
    #pragma unroll
    for (int j=0;j<2;j++) GLOAD_LDS16(gb + (size_t)j*32*Dd, &s_B[0][j*2048 + tid*8]);
  }
  __syncthreads();

  #pragma unroll
  for (int kt=0; kt<4; kt++){
    const int cur = kt&1, nxt = cur^1;
    if (kt < 3){
      const bf16_t* ga = Ab + (size_t)trow*Dd + (kt+1)*64 + tk;
      #pragma unroll
      for (int i=0;i<4;i++) GLOAD_LDS16(ga + (size_t)i*32*Dd, &s_A[nxt][i*2048 + tid*8]);
      const bf16_t* gb = Bw + (size_t)trow*Dd + (kt+1)*64 + tk;
      #pragma unroll
      for (int j=0;j<2;j++) GLOAD_LDS16(gb + (size_t)j*32*Dd, &s_B[nxt][j*2048 + tid*8]);
    }
    #pragma unroll
    for (int ksub=0; ksub<2; ksub++){
      const int ko = (ksub*32 + quad*8) ^ swz;
      bf16x8 a0 = *(const bf16x8*)&s_A[cur][(wave*32      + row16)*64 + ko];
      bf16x8 a1 = *(const bf16x8*)&s_A[cur][(wave*32 + 16 + row16)*64 + ko];
      #pragma unroll
      for (int ni=0;ni<4;ni++){
        bf16x8 b = *(const bf16x8*)&s_B[cur][(ni*16 + row16)*64 + ko];
        acc[0][ni] = __builtin_amdgcn_mfma_f32_16x16x32_bf16(a0, b, acc[0][ni], 0,0,0);
        acc[1][ni] = __builtin_amdgcn_mfma_f32_16x16x32_bf16(a1, b, acc[1][ni], 0,0,0);
      }
    }
    __syncthreads();
  }

  const int by = blockIdx.y;
  const int bb = m_base >> 10;
  #pragma unroll
  for (int mi=0;mi<2;mi++)
    #pragma unroll
    for (int ni=0;ni<4;ni++){
      int col = n_base + ni*16 + row16;
      #pragma unroll
      for (int r=0;r<4;r++){
        int row = m_base + mi*16 + quad*4 + r;
        float v = acc[mi][ni][r];
        if (by < 4)       vproj_f[(size_t)row*256 + col]        = v;
        else if (by < 6)  hsrc_bf[(size_t)row*128 + (col-256)]  = (bf16_t)v;
        else if (by < 8)  hdst_f[(size_t)row*128 + (col-384)]   = v + t_hd[(size_t)(layer*Bb + bb)*HIDh + (col-384)];
        else              qw_bf[(size_t)row*1024 + (col-512)]   = (bf16_t)v;
      }
    }
}

// ---------------- upd GEMM: node_out = act(agg @ Wto[lu] + node_in); writes f32 + bf16 ----------------
__global__ __launch_bounds__(256) void gemm_upd(
    const bf16_t* __restrict__ agg_bf, const bf16_t* __restrict__ Wto,
    const float* __restrict__ node_in, float* __restrict__ node_out,
    bf16_t* __restrict__ node_bf, int lu, int write_node){

  __shared__ __align__(16) bf16_t s_A[2][8192];
  __shared__ __align__(16) bf16_t s_B[2][4096];

  const int tid = threadIdx.x;
  const int wave = tid>>6, lane = tid&63;
  const int row16 = lane&15, quad = lane>>4;
  const int bx = blockIdx.x;
  const int brow = ((bx & 7) << 3) + (bx >> 3);
  const int m0 = brow*128;
  const int m_base = m0 + wave*32;
  const int n_base = blockIdx.y*64;
  const bf16_t* Ab = agg_bf + (size_t)m0*Dd;
  const bf16_t* Bw = Wto + (size_t)lu*Dd*Dd + (size_t)n_base*Dd;

  const int trow = tid>>3;
  const int tk   = ((tid&7) ^ (trow&7)) << 3;
  const int swz  = (row16&7) << 3;

  floatx4 acc[2][4];
  #pragma unroll
  for (int mi=0;mi<2;mi++)
    #pragma unroll
    for (int ni=0;ni<4;ni++){ floatx4 z = {0.f,0.f,0.f,0.f}; acc[mi][ni] = z; }

  {
    const bf16_t* ga = Ab + (size_t)trow*Dd + tk;
    #pragma unroll
    for (int i=0;i<4;i++) GLOAD_LDS16(ga + (size_t)i*32*Dd, &s_A[0][i*2048 + tid*8]);
    const bf16_t* gb = Bw + (size_t)trow*Dd + tk;
    #pragma unroll
    for (int j=0;j<2;j++) GLOAD_LDS16(gb + (size_t)j*32*Dd, &s_B[0][j*2048 + tid*8]);
  }
  __syncthreads();

  #pragma unroll
  for (int kt=0; kt<4; kt++){
    const int cur = kt&1, nxt = cur^1;
    if (kt < 3){
      const bf16_t* ga = Ab + (size_t)trow*Dd + (kt+1)*64 + tk;
      #pragma unroll
      for (int i=0;i<4;i++) GLOAD_LDS16(ga + (size_t)i*32*Dd, &s_A[nxt][i*2048 + tid*8]);
      const bf16_t* gb = Bw + (size_t)trow*Dd + (kt+1)*64 + tk;
      #pragma unroll
      for (int j=0;j<2;j++) GLOAD_LDS16(gb + (size_t)j*32*Dd, &s_B[nxt][j*2048 + tid*8]);
    }
    #pragma unroll
    for (int ksub=0; ksub<2; ksub++){
      const int ko = (ksub*32 + quad*8) ^ swz;
      bf16x8 a0 = *(const bf16x8*)&s_A[cur][(wave*32      + row16)*64 + ko];
      bf16x8 a1 = *(const bf16x8*)&s_A[cur][(wave*32 + 16 + row16)*64 + ko];
      #pragma unroll
      for (int ni=0;ni<4;ni++){
        bf16x8 b = *(const bf16x8*)&s_B[cur][(ni*16 + row16)*64 + ko];
        acc[0][ni] = __builtin_amdgcn_mfma_f32_16x16x32_bf16(a0, b, acc[0][ni], 0,0,0);
        acc[1][ni] = __builtin_amdgcn_mfma_f32_16x16x32_bf16(a1, b, acc[1][ni], 0,0,0);
      }
    }
    __syncthreads();
  }

  #pragma unroll
  for (int mi=0;mi<2;mi++)
    #pragma unroll
    for (int ni=0;ni<4;ni++){
      int col = n_base + ni*16 + row16;
      #pragma unroll
      for (int r=0;r<4;r++){
        int row = m_base + mi*16 + quad*4 + r;
        float v = acc[mi][ni][r] + node_in[(size_t)row*Dd + col];
        if (col < 64)       v = gelu_fast(v);
        else if (col < 128) v = tanh_fast(v);
        if (write_node) node_out[(size_t)row*Dd + col] = v;
        node_bf[(size_t)row*Dd + col] = (bf16_t)v;
      }
    }
}

// ---------------- attn: barrier-free, one wave per node; 10112B/wave LDS, VGPR<=128 ----------------
__global__ __launch_bounds__(256, 4) void attn_kernel(
    const float* __restrict__ x, const int* __restrict__ src,
    const float* __restrict__ vproj_f, const bf16_t* __restrict__ hsrc_bf,
    const float* __restrict__ hdst_f, const bf16_t* __restrict__ qw_bf,
    const bf16_t* __restrict__ WrbfT,
    const float* __restrict__ Wvg, const float* __restrict__ Woo,
    bf16_t* __restrict__ agg_bf, float* __restrict__ out, int layer){

  __shared__ __align__(16) char smem[40448];     // 4 waves x 10112B private slices
  const int tid  = threadIdx.x;
  const int wave = tid>>6, lane = tid&63;
  char* sw = smem + wave*10112;
  bf16_t* s_h   = (bf16_t*)(sw);                 // [32][136]
  float*  s_sh  = (float*)(sw + 8704);           // [32][10]
  float*  s_cut = (float*)(sw + 9984);           // [32]
  float*  s_al  = (float*)(sw);                  // [32][8]  OVERLAY on s_h (dead after logits)
  float*  s_pool= (float*)(sw + 1024);           // [8][10]  OVERLAY on s_h

  const int bidx = blockIdx.x;
  const int b    = bidx & 7;                     // batch -> XCD affinity
  const int bn   = (b << 10) | ((bidx >> 3) << 2) | wave;
  const int row16 = lane&15, quad = lane>>4;

  // ---- prefetches (per wave, no cross-wave deps) ----
  bf16x8 qf[4];
  { const bf16_t* qp = qw_bf + (size_t)bn*1024 + row16*HIDh + quad*8;
    #pragma unroll
    for (int ks=0; ks<4; ks++) qf[ks] = *(const bf16x8*)(qp + ks*32); }
  float hdv[8];
  #pragma unroll
  for (int j=0; j<8; j++) hdv[j] = hdst_f[(size_t)bn*128 + j*16 + row16];

  const float ax = x[(size_t)bn*3+0], ay = x[(size_t)bn*3+1], az = x[(size_t)bn*3+2];

  // hsrc gather -> straight to LDS (lane: edge lane>>1, col-half lane&1)
  {
    const int eg = lane>>1, half = lane&1;
    const int sG = src[(size_t)bn*Kk + eg];
    const bf16_t* hp = hsrc_bf + ((size_t)b*Nn + sG)*128 + half*64;
    #pragma unroll
    for (int j=0;j<8;j++)
      *(bf16x8*)(s_h + eg*136 + half*64 + j*8) = *(const bf16x8*)(hp + j*8);
  }

  // rbf A-fragments via Gaussian recurrence (edges row16, row16+16)
  const int sE0 = src[(size_t)bn*Kk + row16];
  const int sE1 = src[(size_t)bn*Kk + row16 + 16];
  bf16x8 a0f, a1f;
  {
    const float* xj0 = x + ((size_t)b*Nn + sE0)*3;
    const float* xj1 = x + ((size_t)b*Nn + sE1)*3;
    float d0x = ax - xj0[0], d0y = ay - xj0[1], d0z = az - xj0[2];
    float d1x = ax - xj1[0], d1y = ay - xj1[1], d1z = az - xj1[2];
    float rr0 = sqrtf(d0x*d0x + d0y*d0y + d0z*d0z);
    float rr1 = sqrtf(d1x*d1x + d1y*d1y + d1z*d1z);
    float xx0 = 10.0f*(1.0f - rr0*0.5f);
    float xx1 = 10.0f*(1.0f - rr1*0.5f);
    float cu0 = (xx0 > 0.0f) ? 1.4f*__expf(-__builtin_amdgcn_rcpf(xx0)) : 0.0f;
    float cu1 = (xx1 > 0.0f) ? 1.4f*__expf(-__builtin_amdgcn_rcpf(xx1)) : 0.0f;
    float sc0 = 4.798224586623f*cu0;
    float sc1 = 4.798224586623f*cu1;
    float rs0 = fminf(rr0*15.5f, 33.0f);
    float rs1 = fminf(rr1*15.5f, 33.0f);
    float cbase = (float)(quad*8);
    float dd0 = rs0 - cbase, dd1 = rs1 - cbase;
    float e0v = __expf(-dd0*dd0)*sc0;
    float e1v = __expf(-dd1*dd1)*sc1;
    float g0 = __expf(2.0f*dd0 - 1.0f);
    float g1 = __expf(2.0f*dd1 - 1.0f);
    a0f[0] = (bf16_t)e0v; a1f[0] = (bf16_t)e1v;
    #pragma unroll
    for (int j=1;j<8;j++){
      e0v *= g0; e1v *= g1;
      a0f[j] = (bf16_t)e0v; a1f[j] = (bf16_t)e1v;
      g0 *= 0.13533528323661270f; g1 *= 0.13533528323661270f;
    }
  }

  // cut (lanes 0-31) + sh (lanes 32-63), wave-private
  {
    const int k = lane & 31;
    const int j = src[(size_t)bn*Kk + k];
    const float* xj = x + ((size_t)b*Nn + j)*3;
    float dx = ax - xj[0], dy = ay - xj[1], dz = az - xj[2];
    float rr = sqrtf(dx*dx + dy*dy + dz*dz);
    if (lane < 32){
      float xx = 10.0f*(1.0f - rr*0.5f);
      s_cut[k] = (xx > 0.0f) ? 1.4f*__expf(-__builtin_amdgcn_rcpf(xx)) : 0.0f;
    } else {
      float inv = __builtin_amdgcn_rcpf(fmaxf(rr, 1e-9f));
      float ux = dx*inv, uy = dy*inv, uz = dz*inv;
      float* sh = s_sh + k*10;
      sh[0] = 1.0f;
      sh[1] = 1.7320508075688772f*ux;
      sh[2] = 1.7320508075688772f*uy;
      sh[3] = 1.7320508075688772f*uz;
      sh[4] = 3.872983346207417f*ux*uy;
      sh[5] = 3.872983346207417f*uy*uz;
      sh[6] = 1.118033988749895f*(3.0f*uz*uz - 1.0f);
      sh[7] = 3.872983346207417f*ux*uz;
      sh[8] = 1.9364916731037085f*(ux*ux - uy*uy);
    }
  }

  // rbf MFMA + gelu combine in 2 passes of 4 col-groups (halves live acc regs)
  #pragma unroll
  for (int p=0; p<2; p++){
    floatx4 acc0[4], acc1[4];
    const bf16_t* bp = WrbfT + ((size_t)layer*HIDh + row16)*NBnb + quad*8;
    #pragma unroll
    for (int j2=0;j2<4;j2++){
      floatx4 z = {0.f,0.f,0.f,0.f};
      bf16x8 bbf = *(const bf16x8*)(bp + (size_t)(p*4+j2)*16*NBnb);
      acc0[j2] = __builtin_amdgcn_mfma_f32_16x16x32_bf16(a0f, bbf, z, 0,0,0);
      acc1[j2] = __builtin_amdgcn_mfma_f32_16x16x32_bf16(a1f, bbf, z, 0,0,0);
    }
    #pragma unroll
    for (int j2=0;j2<4;j2++){
      const int c = (p*4+j2)*16 + row16;
      const float hd = hdv[p*4+j2];
      #pragma unroll
      for (int r=0;r<4;r++){
        int e = quad*4 + r;
        float hs = (float)s_h[e*136 + c];
        s_h[e*136 + c] = (bf16_t)gelu_fast(acc0[j2][r] + hd + hs);
      }
      #pragma unroll
      for (int r=0;r<4;r++){
        int e = 16 + quad*4 + r;
        float hs = (float)s_h[e*136 + c];
        s_h[e*136 + c] = (bf16_t)gelu_fast(acc1[j2][r] + hd + hs);
      }
    }
  }

  // logits: 2 row-groups x 4 k-steps
  floatx4 la[2];
  #pragma unroll
  for (int rg=0; rg<2; rg++){
    floatx4 l4 = {0.f,0.f,0.f,0.f};
    #pragma unroll
    for (int ks=0; ks<4; ks++){
      bf16x8 a = *(const bf16x8*)(s_h + (rg*16 + row16)*136 + ks*32 + quad*8);
      l4 = __builtin_amdgcn_mfma_f32_16x16x32_bf16(a, qf[ks], l4, 0,0,0);
    }
    la[rg] = l4;
  }

  // fence: s_al/s_pool OVERLAY s_h — block compiler from hoisting float stores above bf16 reads
  __builtin_amdgcn_sched_barrier(0);

  // softmax in-register: lane holds 8 logits for h=row16 (e = rg*16+quad*4+r)
  {
    float lv[8], ct[8];
    #pragma unroll
    for (int rg=0; rg<2; rg++)
      #pragma unroll
      for (int r=0;r<4;r++){
        lv[rg*4+r] = la[rg][r]*0.17677669529663687f;
        ct[rg*4+r] = s_cut[rg*16 + quad*4 + r];
      }
    float m = lv[0];
    #pragma unroll
    for (int i=1;i<8;i++) m = fmaxf(m, lv[i]);
    m = fmaxf(m, __shfl_xor(m, 16));
    m = fmaxf(m, __shfl_xor(m, 32));
    float w[8]; float ss = 0.f;
    #pragma unroll
    for (int i=0;i<8;i++){ w[i] = ct[i]*__expf(lv[i]-m); ss += w[i]; }
    ss += __shfl_xor(ss, 16);
    ss += __shfl_xor(ss, 32);
    float rs = __builtin_amdgcn_rcpf(ss + 1e-9f);
    if (row16 < Hh){
      #pragma unroll
      for (int rg=0; rg<2; rg++)
        #pragma unroll
        for (int r=0;r<4;r++)
          s_al[(rg*16 + quad*4 + r)*8 + row16] = w[rg*4+r]*rs;
    }
  }

  // sh-pool: lanes cover 8h x 8sg; lanes 0-7 also sg=8
  {
    const int h2 = lane>>3, sg = lane&7;
    float a = 0.0f;
    #pragma unroll
    for (int k2=0;k2<Kk;k2++)
      a += s_al[k2*8 + h2] * s_sh[k2*10 + sg];
    s_pool[h2*10 + sg] = a;
    if (lane < 8){
      float a8 = 0.0f;
      #pragma unroll
      for (int k2=0;k2<Kk;k2++)
        a8 += s_al[k2*8 + lane] * s_sh[k2*10 + 8];
      s_pool[lane*10 + 8] = a8;
    }
  }

  // main agg: lane owns 4 cols (lane*4); 32 rows in 4 chunks of 8
  float4 accv = {0.f,0.f,0.f,0.f};
  {
    const int h = lane>>3;
    #pragma unroll
    for (int g=0; g<4; g++){
      const float* rp[8];
      #pragma unroll
      for (int i=0;i<8;i++){
        int row = __builtin_amdgcn_readfirstlane(src[(size_t)bn*Kk + g*8 + i]);
        rp[i] = vproj_f + ((size_t)b*Nn + row)*256;
      }
      #pragma unroll
      for (int i=0;i<8;i++){
        const float4 v = *(const float4*)(rp[i] + (lane<<2));
        float al = s_al[(g*8+i)*8 + h];
        accv.x += al*v.x; accv.y += al*v.y; accv.z += al*v.z; accv.w += al*v.w;
      }
    }
  }

  // final: 4 cols/lane
  {
    const int h = lane>>3;
    const float* wvsh = Wvg + (size_t)layer*265*Dd + 256*Dd;
    #pragma unroll
    for (int sg=0; sg<SHDs; sg++){
      const float4 wv4 = *(const float4*)(wvsh + sg*Dd + (lane<<2));
      const float pl = s_pool[h*10 + sg];
      accv.x += pl*wv4.x; accv.y += pl*wv4.y; accv.z += pl*wv4.z; accv.w += pl*wv4.w;
    }

    if (layer < 3){
      bf16x4v o;
      o[0] = (bf16_t)accv.x; o[1] = (bf16_t)accv.y;
      o[2] = (bf16_t)accv.z; o[3] = (bf16_t)accv.w;
      *(bf16x4v*)(agg_bf + (size_t)bn*Dd + (lane<<2)) = o;
    } else {
      const int c0 = lane<<2;
      float p0 = accv.x*Woo[c0*3+0] + accv.y*Woo[c0*3+3] + accv.z*Woo[c0*3+6] + accv.w*Woo[c0*3+9];
      float p1 = accv.x*Woo[c0*3+1] + accv.y*Woo[c0*3+4] + accv.z*Woo[c0*3+7] + accv.w*Woo[c0*3+10];
      float p2 = accv.x*Woo[c0*3+2] + accv.y*Woo[c0*3+5] + accv.z*Woo[c0*3+8] + accv.w*Woo[c0*3+11];
      #pragma unroll
      for (int off=32; off>=1; off>>=1){
        p0 += __shfl_xor(p0, off);
        p1 += __shfl_xor(p1, off);
        p2 += __shfl_xor(p2, off);
      }
      if (lane == 0){
        out[(size_t)bn*3+0] = p0;
        out[(size_t)bn*3+1] = p1;
        out[(size_t)bn*3+2] = p2;
      }
    }
  }
}

extern "C" void kernel_launch(void* const* d_in, const int* in_sizes, int n_in,
                              void* d_out, int out_size, void* d_ws, size_t ws_size,
                              hipStream_t stream){
  const float* x   = (const float*)d_in[0];
  const float* y   = (const float*)d_in[1];
  const float* t   = (const float*)d_in[2];
  const float* We  = (const float*)d_in[3];
  const float* Wk1 = (const float*)d_in[4];
  const float* bk1 = (const float*)d_in[5];
  const float* Wk2 = (const float*)d_in[6];
  const float* Wq  = (const float*)d_in[7];
  const float* Wv  = (const float*)d_in[8];
  const float* Wo  = (const float*)d_in[9];
  const float* Woo = (const float*)d_in[10];
  float* out = (float*)d_out;

  char* ws = (char*)d_ws;
  size_t off = 0;
  auto take = [&](size_t bytes)->char*{ char* p = ws + off; off = (off + bytes + 255) & ~(size_t)255; return p; };

  int*    src      = (int*)   take((size_t)Bb*Nn*Kk*4);
  float*  nodeA    = (float*) take((size_t)Bb*Nn*Dd*4);
  float*  nodeB    = (float*) take((size_t)Bb*Nn*Dd*4);
  bf16_t* node_bf  = (bf16_t*)take((size_t)Bb*Nn*Dd*2);
  bf16_t* agg_bf   = (bf16_t*)take((size_t)Bb*Nn*Dd*2);
  float*  vproj_f  = (float*) take((size_t)Bb*Nn*256*4);
  bf16_t* hsrc_bf  = (bf16_t*)take((size_t)Bb*Nn*128*2);
  float*  hdst_f   = (float*) take((size_t)Bb*Nn*128*4);
  bf16_t* qw_bf    = (bf16_t*)take(((size_t)Bb*Nn*1024 + 2048)*2);  // +pad for B-frag overread
  bf16_t* Wt       = (bf16_t*)take((size_t)4*NCOLS*Dd*2);
  bf16_t* Wto      = (bf16_t*)take((size_t)3*Dd*Dd*2);
  bf16_t* WrbfT    = (bf16_t*)take((size_t)4*HIDh*NBnb*2);
  float*  t_hd     = (float*) take((size_t)4*Bb*HIDh*4);

  setup_kernel<<<dim3(11088), 256, 0, stream>>>(x, y, t, We, Wk1, bk1, Wk2, Wq, Wv, Wo,
                                                Wt, Wto, WrbfT, t_hd, src, nodeA, node_bf);

  gemm_proj<<<dim3(64,24), 256, 0, stream>>>(node_bf, Wt, vproj_f, hsrc_bf, hdst_f, qw_bf, t_hd, 0);
  attn_kernel<<<dim3(Bb*Nn/4), 256, 0, stream>>>(x, src, vproj_f, hsrc_bf, hdst_f, qw_bf,
                                                 WrbfT, Wv, Woo, agg_bf, out, 0);
  // node f32 double-buffer: lu=0 reads A writes B; lu=1 reads B writes A; lu=2 reads A (bf16 only)
  const float* nin[3]  = {nodeA, nodeB, nodeA};
  float*       nout[3] = {nodeB, nodeA, nodeB};
  for (int l=1; l<4; l++){
    gemm_upd<<<dim3(64,4), 256, 0, stream>>>(agg_bf, Wto, nin[l-1], nout[l-1], node_bf,
                                             l-1, (l < 3) ? 1 : 0);
    gemm_proj<<<dim3(64,24), 256, 0, stream>>>(node_bf, Wt, vproj_f, hsrc_bf, hdst_f, qw_bf, t_hd, l);
    attn_kernel<<<dim3(Bb*Nn/4), 256, 0, stream>>>(x, src, vproj_f, hsrc_bf, hdst_f, qw_bf,
                                                   WrbfT, Wv, Woo, agg_bf, out, l);
  }
}

// Round 10
// 364.738 us; speedup vs baseline: 1.3958x; 1.0151x over previous
//
#include <hip/hip_runtime.h>
#include <math.h>

#define Bb 8
#define Nn 1024
#define Kk 32
#define Dd 256
#define Hh 8
#define DHh 32
#define TDIMt 16
#define NBnb 32
#define HIDh 128
#define NSns 128
#define SHDs 9
#define EINe 304   // NB + TDIM + 2*NS
#define NCOLS 1536 // vproj 256 | hsrc 128 | hdst 128 | qw 1024

typedef __bf16 bf16_t;
typedef bf16_t bf16x8 __attribute__((ext_vector_type(8)));
typedef bf16_t bf16x4v __attribute__((ext_vector_type(4)));
typedef float floatx4 __attribute__((ext_vector_type(4)));

// global->LDS direct copy, 16B per lane; LDS dest must be linear in lane id.
#define GLOAD_LDS16(gp, lp) __builtin_amdgcn_global_load_lds( \
    (const __attribute__((address_space(1))) void*)(gp),      \
    (__attribute__((address_space(3))) void*)(lp), 16, 0, 0)

__device__ __forceinline__ float gelu_fast(float x){
  float g = 1.5957691216057308f*(x + 0.044715f*x*x*x);
  return x*__builtin_amdgcn_rcpf(1.0f + __expf(-g));
}
__device__ __forceinline__ float tanh_fast(float x){
  return 1.0f - 2.0f*__builtin_amdgcn_rcpf(1.0f + __expf(2.0f*x));
}

// ---------------- setup: knn FIRST, then preps, then embed ----------------
__global__ __launch_bounds__(256) void setup_kernel(
    const float* __restrict__ x, const float* __restrict__ y, const float* __restrict__ t,
    const float* __restrict__ We, const float* __restrict__ Wk1, const float* __restrict__ bk1,
    const float* __restrict__ Wk2, const float* __restrict__ Wq, const float* __restrict__ Wv,
    const float* __restrict__ Wo,
    bf16_t* __restrict__ Wt, bf16_t* __restrict__ Wto, bf16_t* __restrict__ WrbfT,
    float* __restrict__ t_hd, int* __restrict__ src,
    float* __restrict__ node, bf16_t* __restrict__ node_bf){

  __shared__ float s_b[32];
  __shared__ unsigned long long s_knn[4][64];
  const int bid = blockIdx.x, tid = threadIdx.x;

  if (bid < 2048){                       // ---- knn: threshold-select + compact + bitonic sort
    int wave = tid >> 6, lane = tid & 63;
    int bn = bid*4 + wave;
    int b = bn >> 10, n = bn & (Nn-1);
    const float* xb = x + (size_t)b*Nn*3;
    float px = xb[n*3+0], py = xb[n*3+1], pz = xb[n*3+2];
    float d2v[16];
    #pragma unroll
    for (int i=0;i<16;i++){
      int j = i*64 + lane;
      float dx = px - xb[j*3+0];
      float dy = py - xb[j*3+1];
      float dz = pz - xb[j*3+2];
      d2v[i] = dx*dx + dy*dy + dz*dz;
    }

    // find wave-uniform T with |{d2 <= T}| in [32,64]; interp-bisection on count
    unsigned lob = 0u, hib = 0x7149F2CAu;   // bits(1e30)
    float T = 1.0f;
    int lc = 0;
    for (int it=0; it<24; ++it){
      lc = 0;
      #pragma unroll
      for (int i=0;i<16;i++) lc += (d2v[i] <= T) ? 1 : 0;
      int c = lc;
      #pragma unroll
      for (int off=32; off>=1; off>>=1) c += __shfl_xor(c, off);
      if (c >= 32 && c <= 64) break;
      if (c < 32) lob = __float_as_uint(T); else hib = __float_as_uint(T);
      // cnt ~ T^(3/2) for small radii -> T_next = T*(target/c)^(2/3)
      float ratio = 44.0f * __builtin_amdgcn_rcpf((float)(c < 1 ? 1 : c));
      float Tn = T * __powf(ratio, 0.6666667f);
      unsigned tb = __float_as_uint(Tn);
      if (tb <= lob || tb >= hib) tb = lob + ((hib - lob) >> 1);
      T = __uint_as_float(tb);
    }

    // exclusive prefix of per-lane candidate counts
    int pre = lc;
    #pragma unroll
    for (int d=1; d<64; d<<=1){
      int o = __shfl_up(pre, d);
      if (lane >= d) pre += o;
    }
    int wo = pre - lc;   // this lane's base slot

    unsigned long long* sl = s_knn[wave];
    sl[lane] = ~0ull;    // pad with +inf keys (program-order before compact writes)
    #pragma unroll
    for (int i=0;i<16;i++){
      if (d2v[i] <= T && wo < 64){
        sl[wo] = (((unsigned long long)__float_as_uint(d2v[i])) << 10)
                 | (unsigned)(i*64 + lane);
        wo++;
      }
    }
    __syncthreads();

    // 64-element cross-lane bitonic sort on exact (d2,idx) keys, ascending
    unsigned long long key = sl[lane];
    #pragma unroll
    for (int k2=2; k2<=64; k2<<=1){
      #pragma unroll
      for (int j2=k2>>1; j2>=1; j2>>=1){
        unsigned long long pv = __shfl_xor(key, j2);
        bool takeMin = (((lane & j2) == 0) == ((lane & k2) == 0));
        bool pLess = pv < key;
        key = (pLess == takeMin) ? pv : key;
      }
    }
    if (lane < 32) src[(size_t)bn*Kk + lane] = (int)(key & 1023u);
  } else if (bid < 6144){                // ---- wprepM (coalesced)
    int i = bid-2048; int l = i>>10, yy = i&1023;
    int h = yy>>7, c = yy&127;
    if (tid < 32) s_b[tid] = Wk2[(size_t)l*HIDh*Dd + (size_t)c*Dd + h*DHh + tid];
    __syncthreads();
    const int rloc = tid>>3, dg = tid&7;
    const float b0 = s_b[dg*4+0], b1 = s_b[dg*4+1], b2 = s_b[dg*4+2], b3 = s_b[dg*4+3];
    #pragma unroll
    for (int p=0;p<8;p++){
      int ii = p*32 + rloc;
      const float4 v = *(const float4*)(Wq + (size_t)l*Dd*Dd + (size_t)ii*Dd + h*DHh + dg*4);
      float part = v.x*b0 + v.y*b1 + v.z*b2 + v.w*b3;
      part += __shfl_xor(part, 1);
      part += __shfl_xor(part, 2);
      part += __shfl_xor(part, 4);
      if (dg == 0) Wt[((size_t)l*NCOLS + 512 + yy)*Dd + ii] = (bf16_t)part;
    }
  } else if (bid < 8192){                // ---- wprep: Wt[l][c][k], c<512
    int i = bid-6144; int l = i>>9, c = i&511, k = tid;
    const float* wk1l = Wk1 + (size_t)l*EINe*HIDh;
    float v;
    if (c < 256)       v = Wv[(size_t)l*265*Dd + (size_t)k*Dd + c];
    else if (c < 384){ int c2 = c-256; v = (k < 128) ? wk1l[(48+k)*HIDh + c2] : 0.0f; }
    else             { int c2 = c-384; v = (k < 128) ? wk1l[(176+k)*HIDh + c2] : 0.0f; }
    Wt[((size_t)l*NCOLS + c)*Dd + k] = (bf16_t)v;
  } else if (bid < 8960){                // ---- wprepO
    int i = bid-8192; int l = i>>8; int c = i&255; int k = tid;
    Wto[((size_t)l*Dd + c)*Dd + k] = (bf16_t)Wo[(size_t)l*Dd*Dd + (size_t)k*Dd + c];
  } else if (bid < 9024){                // ---- wprepR
    int i = bid-8960; int l = i>>4, cg = i&15;
    int c = cg*8 + (tid>>5), k = tid&31;
    WrbfT[((size_t)l*HIDh + c)*NBnb + k] = (bf16_t)Wk1[(size_t)l*EINe*HIDh + (size_t)k*HIDh + c];
  } else if (bid < 9040){                // ---- tprep
    int i = bid-9024; int pair = i*2 + (tid>>7);
    int l = pair>>3, b = pair&7, c = tid&127;
    const float* wk1l = Wk1 + (size_t)l*EINe*HIDh;
    float a = bk1[l*HIDh + c];
    #pragma unroll
    for (int ii=0;ii<TDIMt;ii++) a += t[b*TDIMt+ii]*wk1l[(32+ii)*HIDh + c];
    t_hd[(l*Bb + b)*HIDh + c] = a;
  } else {                               // ---- embed (4 nodes/block)
    int bn0 = (bid-9040)*4; int c = tid;
    float w0 = We[0*Dd+c], w1 = We[1*Dd+c], w2 = We[2*Dd+c];
    float wt[TDIMt];
    #pragma unroll
    for (int i=0;i<TDIMt;i++) wt[i] = We[(3+i)*Dd+c];
    #pragma unroll
    for (int u=0;u<4;u++){
      int bn = bn0 + u; int b = bn >> 10;
      float a = y[(size_t)bn*3+0]*w0 + y[(size_t)bn*3+1]*w1 + y[(size_t)bn*3+2]*w2;
      #pragma unroll
      for (int i=0;i<TDIMt;i++) a += t[b*TDIMt+i]*wt[i];
      node[(size_t)bn*Dd + c] = a;
      node_bf[(size_t)bn*Dd + c] = (bf16_t)a;
    }
  }
}

// ---------------- proj GEMM (all layers): LDS-staged 128x64 tile, BK=64 dbuf ----------------
__global__ __launch_bounds__(256) void gemm_proj(const bf16_t* __restrict__ A,
    const bf16_t* __restrict__ Wt_all, float* __restrict__ vproj_f,
    bf16_t* __restrict__ hsrc_bf, float* __restrict__ hdst_f,
    bf16_t* __restrict__ qw_bf, const float* __restrict__ t_hd, int layer){

  __shared__ __align__(16) bf16_t s_A[2][8192];   // [buf][128 rows][64 k] xor-swizzled
  __shared__ __align__(16) bf16_t s_B[2][4096];   // [buf][ 64 cols][64 k] xor-swizzled

  const int tid = threadIdx.x;
  const int wave = tid>>6, lane = tid&63;
  const int row16 = lane&15, quad = lane>>4;
  const int bx = blockIdx.x;
  const int brow = ((bx & 7) << 3) + (bx >> 3);    // batch = bx&7
  const int m0 = brow*128;
  const int m_base = m0 + wave*32;
  const int n_base = blockIdx.y*64;
  const bf16_t* Ab = A + (size_t)m0*Dd;
  const bf16_t* Bw = Wt_all + ((size_t)layer*NCOLS + n_base)*Dd;

  const int trow = tid>>3;                          // 0..31
  const int tk   = ((tid&7) ^ (trow&7)) << 3;       // element offset, xor-swizzled
  const int swz  = (row16&7) << 3;                  // read-side xor (elements)

  floatx4 acc[2][4];
  #pragma unroll
  for (int mi=0;mi<2;mi++)
    #pragma unroll
    for (int ni=0;ni<4;ni++){ floatx4 z = {0.f,0.f,0.f,0.f}; acc[mi][ni] = z; }

  {
    const bf16_t* ga = Ab + (size_t)trow*Dd + tk;
    #pragma unroll
    for (int i=0;i<4;i++) GLOAD_LDS16(ga + (size_t)i*32*Dd, &s_A[0][i*2048 + tid*8]);
    const bf16_t* gb = Bw + (size_t)trow*Dd + tk;
    #pragma unroll
    for (int j=0;j<2;j++) GLOAD_LDS16(gb + (size_t)j*32*Dd, &s_B[0][j*2048 + tid*8]);
  }
  __syncthreads();

  #pragma unroll
  for (int kt=0; kt<4; kt++){
    const int cur = kt&1, nxt = cur^1;
    if (kt < 3){
      const bf16_t* ga = Ab + (size_t)trow*Dd + (kt+1)*64 + tk;
      #pragma unroll
      for (int i=0;i<4;i++) GLOAD_LDS16(ga + (size_t)i*32*Dd, &s_A[nxt][i*2048 + tid*8]);
      const bf16_t* gb = Bw + (size_t)trow*Dd + (kt+1)*64 + tk;
      #pragma unroll
      for (int j=0;j<2;j++) GLOAD_LDS16(gb + (size_t)j*32*Dd, &s_B[nxt][j*2048 + tid*8]);
    }
    #pragma unroll
    for (int ksub=0; ksub<2; ksub++){
      const int ko = (ksub*32 + quad*8) ^ swz;
      bf16x8 a0 = *(const bf16x8*)&s_A[cur][(wave*32      + row16)*64 + ko];
      bf16x8 a1 = *(const bf16x8*)&s_A[cur][(wave*32 + 16 + row16)*64 + ko];
      #pragma unroll
      for (int ni=0;ni<4;ni++){
        bf16x8 b = *(const bf16x8*)&s_B[cur][(ni*16 + row16)*64 + ko];
        acc[0][ni] = __builtin_amdgcn_mfma_f32_16x16x32_bf16(a0, b, acc[0][ni], 0,0,0);
        acc[1][ni] = __builtin_amdgcn_mfma_f32_16x16x32_bf16(a1, b, acc[1][ni], 0,0,0);
      }
    }
    __syncthreads();
  }

  const int by = blockIdx.y;
  const int bb = m_base >> 10;
  #pragma unroll
  for (int mi=0;mi<2;mi++)
    #pragma unroll
    for (int ni=0;ni<4;ni++){
      int col = n_base + ni*16 + row16;
      #pragma unroll
      for (int r=0;r<4;r++){
        int row = m_base + mi*16 + quad*4 + r;
        float v = acc[mi][ni][r];
        if (by < 4)       vproj_f[(size_t)row*256 + col]        = v;
        else if (by < 6)  hsrc_bf[(size_t)row*128 + (col-256)]  = (bf16_t)v;
        else if (by < 8)  hdst_f[(size_t)row*128 + (col-384)]   = v + t_hd[(size_t)(layer*Bb + bb)*HIDh + (col-384)];
        else              qw_bf[(size_t)row*1024 + (col-512)]   = (bf16_t)v;
      }
    }
}

// ---------------- upd GEMM: node_out = act(agg @ Wto[lu] + node_in); writes f32 + bf16 ----------------
__global__ __launch_bounds__(256) void gemm_upd(
    const bf16_t* __restrict__ agg_bf, const bf16_t* __restrict__ Wto,
    const float* __restrict__ node_in, float* __restrict__ node_out,
    bf16_t* __restrict__ node_bf, int lu, int write_node){

  __shared__ __align__(16) bf16_t s_A[2][8192];
  __shared__ __align__(16) bf16_t s_B[2][4096];

  const int tid = threadIdx.x;
  const int wave = tid>>6, lane = tid&63;
  const int row16 = lane&15, quad = lane>>4;
  const int bx = blockIdx.x;
  const int brow = ((bx & 7) << 3) + (bx >> 3);
  const int m0 = brow*128;
  const int m_base = m0 + wave*32;
  const int n_base = blockIdx.y*64;
  const bf16_t* Ab = agg_bf + (size_t)m0*Dd;
  const bf16_t* Bw = Wto + (size_t)lu*Dd*Dd + (size_t)n_base*Dd;

  const int trow = tid>>3;
  const int tk   = ((tid&7) ^ (trow&7)) << 3;
  const int swz  = (row16&7) << 3;

  floatx4 acc[2][4];
  #pragma unroll
  for (int mi=0;mi<2;mi++)
    #pragma unroll
    for (int ni=0;ni<4;ni++){ floatx4 z = {0.f,0.f,0.f,0.f}; acc[mi][ni] = z; }

  {
    const bf16_t* ga = Ab + (size_t)trow*Dd + tk;
    #pragma unroll
    for (int i=0;i<4;i++) GLOAD_LDS16(ga + (size_t)i*32*Dd, &s_A[0][i*2048 + tid*8]);
    const bf16_t* gb = Bw + (size_t)trow*Dd + tk;
    #pragma unroll
    for (int j=0;j<2;j++) GLOAD_LDS16(gb + (size_t)j*32*Dd, &s_B[0][j*2048 + tid*8]);
  }
  __syncthreads();

  #pragma unroll
  for (int kt=0; kt<4; kt++){
    const int cur = kt&1, nxt = cur^1;
    if (kt < 3){
      const bf16_t* ga = Ab + (size_t)trow*Dd + (kt+1)*64 + tk;
      #pragma unroll
      for (int i=0;i<4;i++) GLOAD_LDS16(ga + (size_t)i*32*Dd, &s_A[nxt][i*2048 + tid*8]);
      const bf16_t* gb = Bw + (size_t)trow*Dd + (kt+1)*64 + tk;
      #pragma unroll
      for (int j=0;j<2;j++) GLOAD_LDS16(gb + (size_t)j*32*Dd, &s_B[nxt][j*2048 + tid*8]);
    }
    #pragma unroll
    for (int ksub=0; ksub<2; ksub++){
      const int ko = (ksub*32 + quad*8) ^ swz;
      bf16x8 a0 = *(const bf16x8*)&s_A[cur][(wave*32      + row16)*64 + ko];
      bf16x8 a1 = *(const bf16x8*)&s_A[cur][(wave*32 + 16 + row16)*64 + ko];
      #pragma unroll
      for (int ni=0;ni<4;ni++){
        bf16x8 b = *(const bf16x8*)&s_B[cur][(ni*16 + row16)*64 + ko];
        acc[0][ni] = __builtin_amdgcn_mfma_f32_16x16x32_bf16(a0, b, acc[0][ni], 0,0,0);
        acc[1][ni] = __builtin_amdgcn_mfma_f32_16x16x32_bf16(a1, b, acc[1][ni], 0,0,0);
      }
    }
    __syncthreads();
  }

  #pragma unroll
  for (int mi=0;mi<2;mi++)
    #pragma unroll
    for (int ni=0;ni<4;ni++){
      int col = n_base + ni*16 + row16;
      #pragma unroll
      for (int r=0;r<4;r++){
        int row = m_base + mi*16 + quad*4 + r;
        float v = acc[mi][ni][r] + node_in[(size_t)row*Dd + col];
        if (col < 64)       v = gelu_fast(v);
        else if (col < 128) v = tanh_fast(v);
        if (write_node) node_out[(size_t)row*Dd + col] = v;
        node_bf[(size_t)row*Dd + col] = (bf16_t)v;
      }
    }
}

// ---------------- attn: barrier-free, one wave per node; src register-resident ----------------
__global__ __launch_bounds__(256, 4) void attn_kernel(
    const float* __restrict__ x, const int* __restrict__ src,
    const float* __restrict__ vproj_f, const bf16_t* __restrict__ hsrc_bf,
    const float* __restrict__ hdst_f, const bf16_t* __restrict__ qw_bf,
    const bf16_t* __restrict__ WrbfT,
    const float* __restrict__ Wvg, const float* __restrict__ Woo,
    bf16_t* __restrict__ agg_bf, float* __restrict__ out, int layer){

  __shared__ __align__(16) char smem[40448];     // 4 waves x 10112B private slices
  const int tid  = threadIdx.x;
  const int wave = tid>>6, lane = tid&63;
  char* sw = smem + wave*10112;
  bf16_t* s_h   = (bf16_t*)(sw);                 // [32][136]
  float*  s_sh  = (float*)(sw + 8704);           // [32][10]
  float*  s_cut = (float*)(sw + 9984);           // [32]
  float*  s_al  = (float*)(sw);                  // [32][8]  OVERLAY on s_h (dead after logits)
  float*  s_pool= (float*)(sw + 1024);           // [8][10]  OVERLAY on s_h

  const int bidx = blockIdx.x;
  const int b    = bidx & 7;                     // batch -> XCD affinity
  const int bn   = (b << 10) | ((bidx >> 3) << 2) | wave;
  const int row16 = lane&15, quad = lane>>4;

  // ---- single src load; all other uses via cross-lane ops ----
  const int srcv = src[(size_t)bn*Kk + (lane & 31)];

  // ---- prefetches (per wave, no cross-wave deps) ----
  bf16x8 qf[4];
  { const bf16_t* qp = qw_bf + (size_t)bn*1024 + row16*HIDh + quad*8;
    #pragma unroll
    for (int ks=0; ks<4; ks++) qf[ks] = *(const bf16x8*)(qp + ks*32); }
  float hdv[8];
  #pragma unroll
  for (int j=0; j<8; j++) hdv[j] = hdst_f[(size_t)bn*128 + j*16 + row16];

  const float ax = x[(size_t)bn*3+0], ay = x[(size_t)bn*3+1], az = x[(size_t)bn*3+2];

  // hsrc gather -> straight to LDS (lane: edge lane>>1, col-half lane&1)
  {
    const int eg = lane>>1, half = lane&1;
    const int sG = __shfl(srcv, eg);
    const bf16_t* hp = hsrc_bf + ((size_t)b*Nn + sG)*128 + half*64;
    #pragma unroll
    for (int j=0;j<8;j++)
      *(bf16x8*)(s_h + eg*136 + half*64 + j*8) = *(const bf16x8*)(hp + j*8);
  }

  // rbf A-fragments via Gaussian recurrence (edges row16, row16+16)
  const int sE0 = __shfl(srcv, row16);
  const int sE1 = __shfl(srcv, row16 + 16);
  bf16x8 a0f, a1f;
  {
    const float* xj0 = x + ((size_t)b*Nn + sE0)*3;
    const float* xj1 = x + ((size_t)b*Nn + sE1)*3;
    float d0x = ax - xj0[0], d0y = ay - xj0[1], d0z = az - xj0[2];
    float d1x = ax - xj1[0], d1y = ay - xj1[1], d1z = az - xj1[2];
    float rr0 = sqrtf(d0x*d0x + d0y*d0y + d0z*d0z);
    float rr1 = sqrtf(d1x*d1x + d1y*d1y + d1z*d1z);
    float xx0 = 10.0f*(1.0f - rr0*0.5f);
    float xx1 = 10.0f*(1.0f - rr1*0.5f);
    float cu0 = (xx0 > 0.0f) ? 1.4f*__expf(-__builtin_amdgcn_rcpf(xx0)) : 0.0f;
    float cu1 = (xx1 > 0.0f) ? 1.4f*__expf(-__builtin_amdgcn_rcpf(xx1)) : 0.0f;
    float sc0 = 4.798224586623f*cu0;
    float sc1 = 4.798224586623f*cu1;
    float rs0 = fminf(rr0*15.5f, 33.0f);
    float rs1 = fminf(rr1*15.5f, 33.0f);
    float cbase = (float)(quad*8);
    float dd0 = rs0 - cbase, dd1 = rs1 - cbase;
    float e0v = __expf(-dd0*dd0)*sc0;
    float e1v = __expf(-dd1*dd1)*sc1;
    float g0 = __expf(2.0f*dd0 - 1.0f);
    float g1 = __expf(2.0f*dd1 - 1.0f);
    a0f[0] = (bf16_t)e0v; a1f[0] = (bf16_t)e1v;
    #pragma unroll
    for (int j=1;j<8;j++){
      e0v *= g0; e1v *= g1;
      a0f[j] = (bf16_t)e0v; a1f[j] = (bf16_t)e1v;
      g0 *= 0.13533528323661270f; g1 *= 0.13533528323661270f;
    }
  }

  // cut (lanes 0-31) + sh (lanes 32-63), wave-private
  {
    const int k = lane & 31;
    const int j = srcv;
    const float* xj = x + ((size_t)b*Nn + j)*3;
    float dx = ax - xj[0], dy = ay - xj[1], dz = az - xj[2];
    float rr = sqrtf(dx*dx + dy*dy + dz*dz);
    if (lane < 32){
      float xx = 10.0f*(1.0f - rr*0.5f);
      s_cut[k] = (xx > 0.0f) ? 1.4f*__expf(-__builtin_amdgcn_rcpf(xx)) : 0.0f;
    } else {
      float inv = __builtin_amdgcn_rcpf(fmaxf(rr, 1e-9f));
      float ux = dx*inv, uy = dy*inv, uz = dz*inv;
      float* sh = s_sh + k*10;
      sh[0] = 1.0f;
      sh[1] = 1.7320508075688772f*ux;
      sh[2] = 1.7320508075688772f*uy;
      sh[3] = 1.7320508075688772f*uz;
      sh[4] = 3.872983346207417f*ux*uy;
      sh[5] = 3.872983346207417f*uy*uz;
      sh[6] = 1.118033988749895f*(3.0f*uz*uz - 1.0f);
      sh[7] = 3.872983346207417f*ux*uz;
      sh[8] = 1.9364916731037085f*(ux*ux - uy*uy);
    }
  }

  // rbf MFMA + gelu combine in 2 passes of 4 col-groups (halves live acc regs)
  #pragma unroll
  for (int p=0; p<2; p++){
    floatx4 acc0[4], acc1[4];
    const bf16_t* bp = WrbfT + ((size_t)layer*HIDh + row16)*NBnb + quad*8;
    #pragma unroll
    for (int j2=0;j2<4;j2++){
      floatx4 z = {0.f,0.f,0.f,0.f};
      bf16x8 bbf = *(const bf16x8*)(bp + (size_t)(p*4+j2)*16*NBnb);
      acc0[j2] = __builtin_amdgcn_mfma_f32_16x16x32_bf16(a0f, bbf, z, 0,0,0);
      acc1[j2] = __builtin_amdgcn_mfma_f32_16x16x32_bf16(a1f, bbf, z, 0,0,0);
    }
    #pragma unroll
    for (int j2=0;j2<4;j2++){
      const int c = (p*4+j2)*16 + row16;
      const float hd = hdv[p*4+j2];
      #pragma unroll
      for (int r=0;r<4;r++){
        int e = quad*4 + r;
        float hs = (float)s_h[e*136 + c];
        s_h[e*136 + c] = (bf16_t)gelu_fast(acc0[j2][r] + hd + hs);
      }
      #pragma unroll
      for (int r=0;r<4;r++){
        int e = 16 + quad*4 + r;
        float hs = (float)s_h[e*136 + c];
        s_h[e*136 + c] = (bf16_t)gelu_fast(acc1[j2][r] + hd + hs);
      }
    }
  }

  // logits: 2 row-groups x 4 k-steps
  floatx4 la[2];
  #pragma unroll
  for (int rg=0; rg<2; rg++){
    floatx4 l4 = {0.f,0.f,0.f,0.f};
    #pragma unroll
    for (int ks=0; ks<4; ks++){
      bf16x8 a = *(const bf16x8*)(s_h + (rg*16 + row16)*136 + ks*32 + quad*8);
      l4 = __builtin_amdgcn_mfma_f32_16x16x32_bf16(a, qf[ks], l4, 0,0,0);
    }
    la[rg] = l4;
  }

  // fence: s_al/s_pool OVERLAY s_h — block compiler from hoisting float stores above bf16 reads
  __builtin_amdgcn_sched_barrier(0);

  // softmax in-register: lane holds 8 logits for h=row16 (e = rg*16+quad*4+r)
  {
    float lv[8], ct[8];
    #pragma unroll
    for (int rg=0; rg<2; rg++)
      #pragma unroll
      for (int r=0;r<4;r++){
        lv[rg*4+r] = la[rg][r]*0.17677669529663687f;
        ct[rg*4+r] = s_cut[rg*16 + quad*4 + r];
      }
    float m = lv[0];
    #pragma unroll
    for (int i=1;i<8;i++) m = fmaxf(m, lv[i]);
    m = fmaxf(m, __shfl_xor(m, 16));
    m = fmaxf(m, __shfl_xor(m, 32));
    float w[8]; float ss = 0.f;
    #pragma unroll
    for (int i=0;i<8;i++){ w[i] = ct[i]*__expf(lv[i]-m); ss += w[i]; }
    ss += __shfl_xor(ss, 16);
    ss += __shfl_xor(ss, 32);
    float rs = __builtin_amdgcn_rcpf(ss + 1e-9f);
    if (row16 < Hh){
      #pragma unroll
      for (int rg=0; rg<2; rg++)
        #pragma unroll
        for (int r=0;r<4;r++)
          s_al[(rg*16 + quad*4 + r)*8 + row16] = w[rg*4+r]*rs;
    }
  }

  // sh-pool: lanes cover 8h x 8sg; lanes 0-7 also sg=8
  {
    const int h2 = lane>>3, sg = lane&7;
    float a = 0.0f;
    #pragma unroll
    for (int k2=0;k2<Kk;k2++)
      a += s_al[k2*8 + h2] * s_sh[k2*10 + sg];
    s_pool[h2*10 + sg] = a;
    if (lane < 8){
      float a8 = 0.0f;
      #pragma unroll
      for (int k2=0;k2<Kk;k2++)
        a8 += s_al[k2*8 + lane] * s_sh[k2*10 + 8];
      s_pool[lane*10 + 8] = a8;
    }
  }

  // main agg: lane owns 4 cols (lane*4); row bases from readlane (NO memory loads)
  float4 accv = {0.f,0.f,0.f,0.f};
  {
    const int h = lane>>3;
    #pragma unroll
    for (int g=0; g<4; g++){
      const float* rp[8];
      #pragma unroll
      for (int i=0;i<8;i++){
        int row = __builtin_amdgcn_readlane(srcv, g*8 + i);
        rp[i] = vproj_f + ((size_t)b*Nn + row)*256;
      }
      #pragma unroll
      for (int i=0;i<8;i++){
        const float4 v = *(const float4*)(rp[i] + (lane<<2));
        float al = s_al[(g*8+i)*8 + h];
        accv.x += al*v.x; accv.y += al*v.y; accv.z += al*v.z; accv.w += al*v.w;
      }
    }
  }

  // final: 4 cols/lane
  {
    const int h = lane>>3;
    const float* wvsh = Wvg + (size_t)layer*265*Dd + 256*Dd;
    #pragma unroll
    for (int sg=0; sg<SHDs; sg++){
      const float4 wv4 = *(const float4*)(wvsh + sg*Dd + (lane<<2));
      const float pl = s_pool[h*10 + sg];
      accv.x += pl*wv4.x; accv.y += pl*wv4.y; accv.z += pl*wv4.z; accv.w += pl*wv4.w;
    }

    if (layer < 3){
      bf16x4v o;
      o[0] = (bf16_t)accv.x; o[1] = (bf16_t)accv.y;
      o[2] = (bf16_t)accv.z; o[3] = (bf16_t)accv.w;
      *(bf16x4v*)(agg_bf + (size_t)bn*Dd + (lane<<2)) = o;
    } else {
      const int c0 = lane<<2;
      float p0 = accv.x*Woo[c0*3+0] + accv.y*Woo[c0*3+3] + accv.z*Woo[c0*3+6] + accv.w*Woo[c0*3+9];
      float p1 = accv.x*Woo[c0*3+1] + accv.y*Woo[c0*3+4] + accv.z*Woo[c0*3+7] + accv.w*Woo[c0*3+10];
      float p2 = accv.x*Woo[c0*3+2] + accv.y*Woo[c0*3+5] + accv.z*Woo[c0*3+8] + accv.w*Woo[c0*3+11];
      #pragma unroll
      for (int off=32; off>=1; off>>=1){
        p0 += __shfl_xor(p0, off);
        p1 += __shfl_xor(p1, off);
        p2 += __shfl_xor(p2, off);
      }
      if (lane == 0){
        out[(size_t)bn*3+0] = p0;
        out[(size_t)bn*3+1] = p1;
        out[(size_t)bn*3+2] = p2;
      }
    }
  }
}

extern "C" void kernel_launch(void* const* d_in, const int* in_sizes, int n_in,
                              void* d_out, int out_size, void* d_ws, size_t ws_size,
                              hipStream_t stream){
  const float* x   = (const float*)d_in[0];
  const float* y   = (const float*)d_in[1];
  const float* t   = (const float*)d_in[2];
  const float* We  = (const float*)d_in[3];
  const float* Wk1 = (const float*)d_in[4];
  const float* bk1 = (const float*)d_in[5];
  const float* Wk2 = (const float*)d_in[6];
  const float* Wq  = (const float*)d_in[7];
  const float* Wv  = (const float*)d_in[8];
  const float* Wo  = (const float*)d_in[9];
  const float* Woo = (const float*)d_in[10];
  float* out = (float*)d_out;

  char* ws = (char*)d_ws;
  size_t off = 0;
  auto take = [&](size_t bytes)->char*{ char* p = ws + off; off = (off + bytes + 255) & ~(size_t)255; return p; };

  int*    src      = (int*)   take((size_t)Bb*Nn*Kk*4);
  float*  nodeA    = (float*) take((size_t)Bb*Nn*Dd*4);
  float*  nodeB    = (float*) take((size_t)Bb*Nn*Dd*4);
  bf16_t* node_bf  = (bf16_t*)take((size_t)Bb*Nn*Dd*2);
  bf16_t* agg_bf   = (bf16_t*)take((size_t)Bb*Nn*Dd*2);
  float*  vproj_f  = (float*) take((size_t)Bb*Nn*256*4);
  bf16_t* hsrc_bf  = (bf16_t*)take((size_t)Bb*Nn*128*2);
  float*  hdst_f   = (float*) take((size_t)Bb*Nn*128*4);
  bf16_t* qw_bf    = (bf16_t*)take(((size_t)Bb*Nn*1024 + 2048)*2);  // +pad for B-frag overread
  bf16_t* Wt       = (bf16_t*)take((size_t)4*NCOLS*Dd*2);
  bf16_t* Wto      = (bf16_t*)take((size_t)3*Dd*Dd*2);
  bf16_t* WrbfT    = (bf16_t*)take((size_t)4*HIDh*NBnb*2);
  float*  t_hd     = (float*) take((size_t)4*Bb*HIDh*4);

  setup_kernel<<<dim3(11088), 256, 0, stream>>>(x, y, t, We, Wk1, bk1, Wk2, Wq, Wv, Wo,
                                                Wt, Wto, WrbfT, t_hd, src, nodeA, node_bf);

  gemm_proj<<<dim3(64,24), 256, 0, stream>>>(node_bf, Wt, vproj_f, hsrc_bf, hdst_f, qw_bf, t_hd, 0);
  attn_kernel<<<dim3(Bb*Nn/4), 256, 0, stream>>>(x, src, vproj_f, hsrc_bf, hdst_f, qw_bf,
                                                 WrbfT, Wv, Woo, agg_bf, out, 0);
  // node f32 double-buffer: lu=0 reads A writes B; lu=1 reads B writes A; lu=2 reads A (bf16 only)
  const float* nin[3]  = {nodeA, nodeB, nodeA};
  float*       nout[3] = {nodeB, nodeA, nodeB};
  for (int l=1; l<4; l++){
    gemm_upd<<<dim3(64,4), 256, 0, stream>>>(agg_bf, Wto, nin[l-1], nout[l-1], node_bf,
                                             l-1, (l < 3) ? 1 : 0);
    gemm_proj<<<dim3(64,24), 256, 0, stream>>>(node_bf, Wt, vproj_f, hsrc_bf, hdst_f, qw_bf, t_hd, l);
    attn_kernel<<<dim3(Bb*Nn/4), 256, 0, stream>>>(x, src, vproj_f, hsrc_bf, hdst_f, qw_bf,
                                                   WrbfT, Wv, Woo, agg_bf, out, l);
  }
}

// Round 11
// 363.691 us; speedup vs baseline: 1.3999x; 1.0029x over previous
//
#include <hip/hip_runtime.h>
#include <math.h>

#define Bb 8
#define Nn 1024
#define Kk 32
#define Dd 256
#define Hh 8
#define DHh 32
#define TDIMt 16
#define NBnb 32
#define HIDh 128
#define NSns 128
#define SHDs 9
#define EINe 304   // NB + TDIM + 2*NS
#define NCOLS 1536 // vproj 256 | hsrc 128 | hdst 128 | qw 1024

typedef __bf16 bf16_t;
typedef bf16_t bf16x8 __attribute__((ext_vector_type(8)));
typedef bf16_t bf16x4v __attribute__((ext_vector_type(4)));
typedef float floatx4 __attribute__((ext_vector_type(4)));

// global->LDS direct copy, 16B per lane; LDS dest must be linear in lane id.
#define GLOAD_LDS16(gp, lp) __builtin_amdgcn_global_load_lds( \
    (const __attribute__((address_space(1))) void*)(gp),      \
    (__attribute__((address_space(3))) void*)(lp), 16, 0, 0)

__device__ __forceinline__ float gelu_fast(float x){
  float g = 1.5957691216057308f*(x + 0.044715f*x*x*x);
  return x*__builtin_amdgcn_rcpf(1.0f + __expf(-g));
}
__device__ __forceinline__ float tanh_fast(float x){
  return 1.0f - 2.0f*__builtin_amdgcn_rcpf(1.0f + __expf(2.0f*x));
}

// ---------------- setup: knn FIRST, then preps, then embed ----------------
__global__ __launch_bounds__(256) void setup_kernel(
    const float* __restrict__ x, const float* __restrict__ y, const float* __restrict__ t,
    const float* __restrict__ We, const float* __restrict__ Wk1, const float* __restrict__ bk1,
    const float* __restrict__ Wk2, const float* __restrict__ Wq, const float* __restrict__ Wv,
    const float* __restrict__ Wo,
    bf16_t* __restrict__ Wt, bf16_t* __restrict__ Wto, bf16_t* __restrict__ WrbfT,
    float* __restrict__ t_hd, int* __restrict__ src,
    float* __restrict__ node, bf16_t* __restrict__ node_bf){

  __shared__ float s_b[32];
  __shared__ unsigned long long s_knn[4][64];
  const int bid = blockIdx.x, tid = threadIdx.x;

  if (bid < 2048){                       // ---- knn: threshold-select + compact + bitonic sort
    int wave = tid >> 6, lane = tid & 63;
    int bn = bid*4 + wave;
    int b = bn >> 10, n = bn & (Nn-1);
    const float* xb = x + (size_t)b*Nn*3;
    float px = xb[n*3+0], py = xb[n*3+1], pz = xb[n*3+2];
    float d2v[16];
    #pragma unroll
    for (int i=0;i<16;i++){
      int j = i*64 + lane;
      float dx = px - xb[j*3+0];
      float dy = py - xb[j*3+1];
      float dz = pz - xb[j*3+2];
      d2v[i] = dx*dx + dy*dy + dz*dz;
    }

    // find wave-uniform T with |{d2 <= T}| in [32,64]; interp-bisection on count
    unsigned lob = 0u, hib = 0x7149F2CAu;   // bits(1e30)
    float T = 1.0f;
    int lc = 0;
    for (int it=0; it<24; ++it){
      lc = 0;
      #pragma unroll
      for (int i=0;i<16;i++) lc += (d2v[i] <= T) ? 1 : 0;
      int c = lc;
      #pragma unroll
      for (int off=32; off>=1; off>>=1) c += __shfl_xor(c, off);
      if (c >= 32 && c <= 64) break;
      if (c < 32) lob = __float_as_uint(T); else hib = __float_as_uint(T);
      // cnt ~ T^(3/2) for small radii -> T_next = T*(target/c)^(2/3)
      float ratio = 44.0f * __builtin_amdgcn_rcpf((float)(c < 1 ? 1 : c));
      float Tn = T * __powf(ratio, 0.6666667f);
      unsigned tb = __float_as_uint(Tn);
      if (tb <= lob || tb >= hib) tb = lob + ((hib - lob) >> 1);
      T = __uint_as_float(tb);
    }

    // exclusive prefix of per-lane candidate counts
    int pre = lc;
    #pragma unroll
    for (int d=1; d<64; d<<=1){
      int o = __shfl_up(pre, d);
      if (lane >= d) pre += o;
    }
    int wo = pre - lc;   // this lane's base slot

    unsigned long long* sl = s_knn[wave];
    sl[lane] = ~0ull;    // pad with +inf keys (program-order before compact writes)
    #pragma unroll
    for (int i=0;i<16;i++){
      if (d2v[i] <= T && wo < 64){
        sl[wo] = (((unsigned long long)__float_as_uint(d2v[i])) << 10)
                 | (unsigned)(i*64 + lane);
        wo++;
      }
    }
    __syncthreads();

    // 64-element cross-lane bitonic sort on exact (d2,idx) keys, ascending
    unsigned long long key = sl[lane];
    #pragma unroll
    for (int k2=2; k2<=64; k2<<=1){
      #pragma unroll
      for (int j2=k2>>1; j2>=1; j2>>=1){
        unsigned long long pv = __shfl_xor(key, j2);
        bool takeMin = (((lane & j2) == 0) == ((lane & k2) == 0));
        bool pLess = pv < key;
        key = (pLess == takeMin) ? pv : key;
      }
    }
    if (lane < 32) src[(size_t)bn*Kk + lane] = (int)(key & 1023u);
  } else if (bid < 6144){                // ---- wprepM (coalesced)
    int i = bid-2048; int l = i>>10, yy = i&1023;
    int h = yy>>7, c = yy&127;
    if (tid < 32) s_b[tid] = Wk2[(size_t)l*HIDh*Dd + (size_t)c*Dd + h*DHh + tid];
    __syncthreads();
    const int rloc = tid>>3, dg = tid&7;
    const float b0 = s_b[dg*4+0], b1 = s_b[dg*4+1], b2 = s_b[dg*4+2], b3 = s_b[dg*4+3];
    #pragma unroll
    for (int p=0;p<8;p++){
      int ii = p*32 + rloc;
      const float4 v = *(const float4*)(Wq + (size_t)l*Dd*Dd + (size_t)ii*Dd + h*DHh + dg*4);
      float part = v.x*b0 + v.y*b1 + v.z*b2 + v.w*b3;
      part += __shfl_xor(part, 1);
      part += __shfl_xor(part, 2);
      part += __shfl_xor(part, 4);
      if (dg == 0) Wt[((size_t)l*NCOLS + 512 + yy)*Dd + ii] = (bf16_t)part;
    }
  } else if (bid < 8192){                // ---- wprep: Wt[l][c][k], c<512
    int i = bid-6144; int l = i>>9, c = i&511, k = tid;
    const float* wk1l = Wk1 + (size_t)l*EINe*HIDh;
    float v;
    if (c < 256)       v = Wv[(size_t)l*265*Dd + (size_t)k*Dd + c];
    else if (c < 384){ int c2 = c-256; v = (k < 128) ? wk1l[(48+k)*HIDh + c2] : 0.0f; }
    else             { int c2 = c-384; v = (k < 128) ? wk1l[(176+k)*HIDh + c2] : 0.0f; }
    Wt[((size_t)l*NCOLS + c)*Dd + k] = (bf16_t)v;
  } else if (bid < 8960){                // ---- wprepO
    int i = bid-8192; int l = i>>8; int c = i&255; int k = tid;
    Wto[((size_t)l*Dd + c)*Dd + k] = (bf16_t)Wo[(size_t)l*Dd*Dd + (size_t)k*Dd + c];
  } else if (bid < 9024){                // ---- wprepR
    int i = bid-8960; int l = i>>4, cg = i&15;
    int c = cg*8 + (tid>>5), k = tid&31;
    WrbfT[((size_t)l*HIDh + c)*NBnb + k] = (bf16_t)Wk1[(size_t)l*EINe*HIDh + (size_t)k*HIDh + c];
  } else if (bid < 9040){                // ---- tprep
    int i = bid-9024; int pair = i*2 + (tid>>7);
    int l = pair>>3, b = pair&7, c = tid&127;
    const float* wk1l = Wk1 + (size_t)l*EINe*HIDh;
    float a = bk1[l*HIDh + c];
    #pragma unroll
    for (int ii=0;ii<TDIMt;ii++) a += t[b*TDIMt+ii]*wk1l[(32+ii)*HIDh + c];
    t_hd[(l*Bb + b)*HIDh + c] = a;
  } else {                               // ---- embed (4 nodes/block)
    int bn0 = (bid-9040)*4; int c = tid;
    float w0 = We[0*Dd+c], w1 = We[1*Dd+c], w2 = We[2*Dd+c];
    float wt[TDIMt];
    #pragma unroll
    for (int i=0;i<TDIMt;i++) wt[i] = We[(3+i)*Dd+c];
    #pragma unroll
    for (int u=0;u<4;u++){
      int bn = bn0 + u; int b = bn >> 10;
      float a = y[(size_t)bn*3+0]*w0 + y[(size_t)bn*3+1]*w1 + y[(size_t)bn*3+2]*w2;
      #pragma unroll
      for (int i=0;i<TDIMt;i++) a += t[b*TDIMt+i]*wt[i];
      node[(size_t)bn*Dd + c] = a;
      node_bf[(size_t)bn*Dd + c] = (bf16_t)a;
    }
  }
}

// ---------------- proj GEMM (all layers): LDS-staged 128x64 tile, BK=64 dbuf ----------------
__global__ __launch_bounds__(256) void gemm_proj(const bf16_t* __restrict__ A,
    const bf16_t* __restrict__ Wt_all, bf16_t* __restrict__ vproj_bf,
    bf16_t* __restrict__ hsrc_bf, float* __restrict__ hdst_f,
    bf16_t* __restrict__ qw_bf, const float* __restrict__ t_hd, int layer){

  __shared__ __align__(16) bf16_t s_A[2][8192];   // [buf][128 rows][64 k] xor-swizzled
  __shared__ __align__(16) bf16_t s_B[2][4096];   // [buf][ 64 cols][64 k] xor-swizzled

  const int tid = threadIdx.x;
  const int wave = tid>>6, lane = tid&63;
  const int row16 = lane&15, quad = lane>>4;
  const int bx = blockIdx.x;
  const int brow = ((bx & 7) << 3) + (bx >> 3);    // batch = bx&7
  const int m0 = brow*128;
  const int m_base = m0 + wave*32;
  const int n_base = blockIdx.y*64;
  const bf16_t* Ab = A + (size_t)m0*Dd;
  const bf16_t* Bw = Wt_all + ((size_t)layer*NCOLS + n_base)*Dd;

  const int trow = tid>>3;                          // 0..31
  const int tk   = ((tid&7) ^ (trow&7)) << 3;       // element offset, xor-swizzled
  const int swz  = (row16&7) << 3;                  // read-side xor (elements)

  floatx4 acc[2][4];
  #pragma unroll
  for (int mi=0;mi<2;mi++)
    #pragma unroll
    for (int ni=0;ni<4;ni++){ floatx4 z = {0.f,0.f,0.f,0.f}; acc[mi][ni] = z; }

  {
    const bf16_t* ga = Ab + (size_t)trow*Dd + tk;
    #pragma unroll
    for (int i=0;i<4;i++) GLOAD_LDS16(ga + (size_t)i*32*Dd, &s_A[0][i*2048 + tid*8]);
    const bf16_t* gb = Bw + (size_t)trow*Dd + tk;
    #pragma unroll
    for (int j=0;j<2;j++) GLOAD_LDS16(gb + (size_t)j*32*Dd, &s_B[0][j*2048 + tid*8]);
  }
  __syncthreads();

  #pragma unroll
  for (int kt=0; kt<4; kt++){
    const int cur = kt&1, nxt = cur^1;
    if (kt < 3){
      const bf16_t* ga = Ab + (size_t)trow*Dd + (kt+1)*64 + tk;
      #pragma unroll
      for (int i=0;i<4;i++) GLOAD_LDS16(ga + (size_t)i*32*Dd, &s_A[nxt][i*2048 + tid*8]);
      const bf16_t* gb = Bw + (size_t)trow*Dd + (kt+1)*64 + tk;
      #pragma unroll
      for (int j=0;j<2;j++) GLOAD_LDS16(gb + (size_t)j*32*Dd, &s_B[nxt][j*2048 + tid*8]);
    }
    #pragma unroll
    for (int ksub=0; ksub<2; ksub++){
      const int ko = (ksub*32 + quad*8) ^ swz;
      bf16x8 a0 = *(const bf16x8*)&s_A[cur][(wave*32      + row16)*64 + ko];
      bf16x8 a1 = *(const bf16x8*)&s_A[cur][(wave*32 + 16 + row16)*64 + ko];
      #pragma unroll
      for (int ni=0;ni<4;ni++){
        bf16x8 b = *(const bf16x8*)&s_B[cur][(ni*16 + row16)*64 + ko];
        acc[0][ni] = __builtin_amdgcn_mfma_f32_16x16x32_bf16(a0, b, acc[0][ni], 0,0,0);
        acc[1][ni] = __builtin_amdgcn_mfma_f32_16x16x32_bf16(a1, b, acc[1][ni], 0,0,0);
      }
    }
    __syncthreads();
  }

  const int by = blockIdx.y;
  const int bb = m_base >> 10;
  #pragma unroll
  for (int mi=0;mi<2;mi++)
    #pragma unroll
    for (int ni=0;ni<4;ni++){
      int col = n_base + ni*16 + row16;
      #pragma unroll
      for (int r=0;r<4;r++){
        int row = m_base + mi*16 + quad*4 + r;
        float v = acc[mi][ni][r];
        if (by < 4)       vproj_bf[(size_t)row*256 + col]       = (bf16_t)v;
        else if (by < 6)  hsrc_bf[(size_t)row*128 + (col-256)]  = (bf16_t)v;
        else if (by < 8)  hdst_f[(size_t)row*128 + (col-384)]   = v + t_hd[(size_t)(layer*Bb + bb)*HIDh + (col-384)];
        else              qw_bf[(size_t)row*1024 + (col-512)]   = (bf16_t)v;
      }
    }
}

// ---------------- upd GEMM: node_out = act(agg @ Wto[lu] + node_in); writes f32 + bf16 ----------------
__global__ __launch_bounds__(256) void gemm_upd(
    const bf16_t* __restrict__ agg_bf, const bf16_t* __restrict__ Wto,
    const float* __restrict__ node_in, float* __restrict__ node_out,
    bf16_t* __restrict__ node_bf, int lu, int write_node){

  __shared__ __align__(16) bf16_t s_A[2][8192];
  __shared__ __align__(16) bf16_t s_B[2][4096];

  const int tid = threadIdx.x;
  const int wave = tid>>6, lane = tid&63;
  const int row16 = lane&15, quad = lane>>4;
  const int bx = blockIdx.x;
  const int brow = ((bx & 7) << 3) + (bx >> 3);
  const int m0 = brow*128;
  const int m_base = m0 + wave*32;
  const int n_base = blockIdx.y*64;
  const bf16_t* Ab = agg_bf + (size_t)m0*Dd;
  const bf16_t* Bw = Wto + (size_t)lu*Dd*Dd + (size_t)n_base*Dd;

  const int trow = tid>>3;
  const int tk   = ((tid&7) ^ (trow&7)) << 3;
  const int swz  = (row16&7) << 3;

  floatx4 acc[2][4];
  #pragma unroll
  for (int mi=0;mi<2;mi++)
    #pragma unroll
    for (int ni=0;ni<4;ni++){ floatx4 z = {0.f,0.f,0.f,0.f}; acc[mi][ni] = z; }

  {
    const bf16_t* ga = Ab + (size_t)trow*Dd + tk;
    #pragma unroll
    for (int i=0;i<4;i++) GLOAD_LDS16(ga + (size_t)i*32*Dd, &s_A[0][i*2048 + tid*8]);
    const bf16_t* gb = Bw + (size_t)trow*Dd + tk;
    #pragma unroll
    for (int j=0;j<2;j++) GLOAD_LDS16(gb + (size_t)j*32*Dd, &s_B[0][j*2048 + tid*8]);
  }
  __syncthreads();

  #pragma unroll
  for (int kt=0; kt<4; kt++){
    const int cur = kt&1, nxt = cur^1;
    if (kt < 3){
      const bf16_t* ga = Ab + (size_t)trow*Dd + (kt+1)*64 + tk;
      #pragma unroll
      for (int i=0;i<4;i++) GLOAD_LDS16(ga + (size_t)i*32*Dd, &s_A[nxt][i*2048 + tid*8]);
      const bf16_t* gb = Bw + (size_t)trow*Dd + (kt+1)*64 + tk;
      #pragma unroll
      for (int j=0;j<2;j++) GLOAD_LDS16(gb + (size_t)j*32*Dd, &s_B[nxt][j*2048 + tid*8]);
    }
    #pragma unroll
    for (int ksub=0; ksub<2; ksub++){
      const int ko = (ksub*32 + quad*8) ^ swz;
      bf16x8 a0 = *(const bf16x8*)&s_A[cur][(wave*32      + row16)*64 + ko];
      bf16x8 a1 = *(const bf16x8*)&s_A[cur][(wave*32 + 16 + row16)*64 + ko];
      #pragma unroll
      for (int ni=0;ni<4;ni++){
        bf16x8 b = *(const bf16x8*)&s_B[cur][(ni*16 + row16)*64 + ko];
        acc[0][ni] = __builtin_amdgcn_mfma_f32_16x16x32_bf16(a0, b, acc[0][ni], 0,0,0);
        acc[1][ni] = __builtin_amdgcn_mfma_f32_16x16x32_bf16(a1, b, acc[1][ni], 0,0,0);
      }
    }
    __syncthreads();
  }

  #pragma unroll
  for (int mi=0;mi<2;mi++)
    #pragma unroll
    for (int ni=0;ni<4;ni++){
      int col = n_base + ni*16 + row16;
      #pragma unroll
      for (int r=0;r<4;r++){
        int row = m_base + mi*16 + quad*4 + r;
        float v = acc[mi][ni][r] + node_in[(size_t)row*Dd + col];
        if (col < 64)       v = gelu_fast(v);
        else if (col < 128) v = tanh_fast(v);
        if (write_node) node_out[(size_t)row*Dd + col] = v;
        node_bf[(size_t)row*Dd + col] = (bf16_t)v;
      }
    }
}

// ---------------- attn: barrier-free, one wave per node; src register-resident; bf16 V ----------------
__global__ __launch_bounds__(256, 4) void attn_kernel(
    const float* __restrict__ x, const int* __restrict__ src,
    const bf16_t* __restrict__ vproj_bf, const bf16_t* __restrict__ hsrc_bf,
    const float* __restrict__ hdst_f, const bf16_t* __restrict__ qw_bf,
    const bf16_t* __restrict__ WrbfT,
    const float* __restrict__ Wvg, const float* __restrict__ Woo,
    bf16_t* __restrict__ agg_bf, float* __restrict__ out, int layer){

  __shared__ __align__(16) char smem[40448];     // 4 waves x 10112B private slices
  const int tid  = threadIdx.x;
  const int wave = tid>>6, lane = tid&63;
  char* sw = smem + wave*10112;
  bf16_t* s_h   = (bf16_t*)(sw);                 // [32][136]
  float*  s_sh  = (float*)(sw + 8704);           // [32][10]
  float*  s_cut = (float*)(sw + 9984);           // [32]
  float*  s_al  = (float*)(sw);                  // [32][8]  OVERLAY on s_h (dead after logits)
  float*  s_pool= (float*)(sw + 1024);           // [8][10]  OVERLAY on s_h

  const int bidx = blockIdx.x;
  const int b    = bidx & 7;                     // batch -> XCD affinity
  const int bn   = (b << 10) | ((bidx >> 3) << 2) | wave;
  const int row16 = lane&15, quad = lane>>4;

  // ---- single src load; all other uses via cross-lane ops ----
  const int srcv = src[(size_t)bn*Kk + (lane & 31)];

  // ---- prefetches (per wave, no cross-wave deps) ----
  bf16x8 qf[4];
  { const bf16_t* qp = qw_bf + (size_t)bn*1024 + row16*HIDh + quad*8;
    #pragma unroll
    for (int ks=0; ks<4; ks++) qf[ks] = *(const bf16x8*)(qp + ks*32); }
  float hdv[8];
  #pragma unroll
  for (int j=0; j<8; j++) hdv[j] = hdst_f[(size_t)bn*128 + j*16 + row16];

  const float ax = x[(size_t)bn*3+0], ay = x[(size_t)bn*3+1], az = x[(size_t)bn*3+2];

  // hsrc gather -> straight to LDS (lane: edge lane>>1, col-half lane&1)
  {
    const int eg = lane>>1, half = lane&1;
    const int sG = __shfl(srcv, eg);
    const bf16_t* hp = hsrc_bf + ((size_t)b*Nn + sG)*128 + half*64;
    #pragma unroll
    for (int j=0;j<8;j++)
      *(bf16x8*)(s_h + eg*136 + half*64 + j*8) = *(const bf16x8*)(hp + j*8);
  }

  // rbf A-fragments via Gaussian recurrence (edges row16, row16+16)
  const int sE0 = __shfl(srcv, row16);
  const int sE1 = __shfl(srcv, row16 + 16);
  bf16x8 a0f, a1f;
  {
    const float* xj0 = x + ((size_t)b*Nn + sE0)*3;
    const float* xj1 = x + ((size_t)b*Nn + sE1)*3;
    float d0x = ax - xj0[0], d0y = ay - xj0[1], d0z = az - xj0[2];
    float d1x = ax - xj1[0], d1y = ay - xj1[1], d1z = az - xj1[2];
    float rr0 = sqrtf(d0x*d0x + d0y*d0y + d0z*d0z);
    float rr1 = sqrtf(d1x*d1x + d1y*d1y + d1z*d1z);
    float xx0 = 10.0f*(1.0f - rr0*0.5f);
    float xx1 = 10.0f*(1.0f - rr1*0.5f);
    float cu0 = (xx0 > 0.0f) ? 1.4f*__expf(-__builtin_amdgcn_rcpf(xx0)) : 0.0f;
    float cu1 = (xx1 > 0.0f) ? 1.4f*__expf(-__builtin_amdgcn_rcpf(xx1)) : 0.0f;
    float sc0 = 4.798224586623f*cu0;
    float sc1 = 4.798224586623f*cu1;
    float rs0 = fminf(rr0*15.5f, 33.0f);
    float rs1 = fminf(rr1*15.5f, 33.0f);
    float cbase = (float)(quad*8);
    float dd0 = rs0 - cbase, dd1 = rs1 - cbase;
    float e0v = __expf(-dd0*dd0)*sc0;
    float e1v = __expf(-dd1*dd1)*sc1;
    float g0 = __expf(2.0f*dd0 - 1.0f);
    float g1 = __expf(2.0f*dd1 - 1.0f);
    a0f[0] = (bf16_t)e0v; a1f[0] = (bf16_t)e1v;
    #pragma unroll
    for (int j=1;j<8;j++){
      e0v *= g0; e1v *= g1;
      a0f[j] = (bf16_t)e0v; a1f[j] = (bf16_t)e1v;
      g0 *= 0.13533528323661270f; g1 *= 0.13533528323661270f;
    }
  }

  // cut (lanes 0-31) + sh (lanes 32-63), wave-private
  {
    const int k = lane & 31;
    const int j = srcv;
    const float* xj = x + ((size_t)b*Nn + j)*3;
    float dx = ax - xj[0], dy = ay - xj[1], dz = az - xj[2];
    float rr = sqrtf(dx*dx + dy*dy + dz*dz);
    if (lane < 32){
      float xx = 10.0f*(1.0f - rr*0.5f);
      s_cut[k] = (xx > 0.0f) ? 1.4f*__expf(-__builtin_amdgcn_rcpf(xx)) : 0.0f;
    } else {
      float inv = __builtin_amdgcn_rcpf(fmaxf(rr, 1e-9f));
      float ux = dx*inv, uy = dy*inv, uz = dz*inv;
      float* sh = s_sh + k*10;
      sh[0] = 1.0f;
      sh[1] = 1.7320508075688772f*ux;
      sh[2] = 1.7320508075688772f*uy;
      sh[3] = 1.7320508075688772f*uz;
      sh[4] = 3.872983346207417f*ux*uy;
      sh[5] = 3.872983346207417f*uy*uz;
      sh[6] = 1.118033988749895f*(3.0f*uz*uz - 1.0f);
      sh[7] = 3.872983346207417f*ux*uz;
      sh[8] = 1.9364916731037085f*(ux*ux - uy*uy);
    }
  }

  // rbf MFMA + gelu combine in 2 passes of 4 col-groups (halves live acc regs)
  #pragma unroll
  for (int p=0; p<2; p++){
    floatx4 acc0[4], acc1[4];
    const bf16_t* bp = WrbfT + ((size_t)layer*HIDh + row16)*NBnb + quad*8;
    #pragma unroll
    for (int j2=0;j2<4;j2++){
      floatx4 z = {0.f,0.f,0.f,0.f};
      bf16x8 bbf = *(const bf16x8*)(bp + (size_t)(p*4+j2)*16*NBnb);
      acc0[j2] = __builtin_amdgcn_mfma_f32_16x16x32_bf16(a0f, bbf, z, 0,0,0);
      acc1[j2] = __builtin_amdgcn_mfma_f32_16x16x32_bf16(a1f, bbf, z, 0,0,0);
    }
    #pragma unroll
    for (int j2=0;j2<4;j2++){
      const int c = (p*4+j2)*16 + row16;
      const float hd = hdv[p*4+j2];
      #pragma unroll
      for (int r=0;r<4;r++){
        int e = quad*4 + r;
        float hs = (float)s_h[e*136 + c];
        s_h[e*136 + c] = (bf16_t)gelu_fast(acc0[j2][r] + hd + hs);
      }
      #pragma unroll
      for (int r=0;r<4;r++){
        int e = 16 + quad*4 + r;
        float hs = (float)s_h[e*136 + c];
        s_h[e*136 + c] = (bf16_t)gelu_fast(acc1[j2][r] + hd + hs);
      }
    }
  }

  // logits: 2 row-groups x 4 k-steps
  floatx4 la[2];
  #pragma unroll
  for (int rg=0; rg<2; rg++){
    floatx4 l4 = {0.f,0.f,0.f,0.f};
    #pragma unroll
    for (int ks=0; ks<4; ks++){
      bf16x8 a = *(const bf16x8*)(s_h + (rg*16 + row16)*136 + ks*32 + quad*8);
      l4 = __builtin_amdgcn_mfma_f32_16x16x32_bf16(a, qf[ks], l4, 0,0,0);
    }
    la[rg] = l4;
  }

  // fence: s_al/s_pool OVERLAY s_h — block compiler from hoisting float stores above bf16 reads
  __builtin_amdgcn_sched_barrier(0);

  // softmax in-register: lane holds 8 logits for h=row16 (e = rg*16+quad*4+r)
  {
    float lv[8], ct[8];
    #pragma unroll
    for (int rg=0; rg<2; rg++)
      #pragma unroll
      for (int r=0;r<4;r++){
        lv[rg*4+r] = la[rg][r]*0.17677669529663687f;
        ct[rg*4+r] = s_cut[rg*16 + quad*4 + r];
      }
    float m = lv[0];
    #pragma unroll
    for (int i=1;i<8;i++) m = fmaxf(m, lv[i]);
    m = fmaxf(m, __shfl_xor(m, 16));
    m = fmaxf(m, __shfl_xor(m, 32));
    float w[8]; float ss = 0.f;
    #pragma unroll
    for (int i=0;i<8;i++){ w[i] = ct[i]*__expf(lv[i]-m); ss += w[i]; }
    ss += __shfl_xor(ss, 16);
    ss += __shfl_xor(ss, 32);
    float rs = __builtin_amdgcn_rcpf(ss + 1e-9f);
    if (row16 < Hh){
      #pragma unroll
      for (int rg=0; rg<2; rg++)
        #pragma unroll
        for (int r=0;r<4;r++)
          s_al[(rg*16 + quad*4 + r)*8 + row16] = w[rg*4+r]*rs;
    }
  }

  // sh-pool: lanes cover 8h x 8sg; lanes 0-7 also sg=8
  {
    const int h2 = lane>>3, sg = lane&7;
    float a = 0.0f;
    #pragma unroll
    for (int k2=0;k2<Kk;k2++)
      a += s_al[k2*8 + h2] * s_sh[k2*10 + sg];
    s_pool[h2*10 + sg] = a;
    if (lane < 8){
      float a8 = 0.0f;
      #pragma unroll
      for (int k2=0;k2<Kk;k2++)
        a8 += s_al[k2*8 + lane] * s_sh[k2*10 + 8];
      s_pool[lane*10 + 8] = a8;
    }
  }

  // main agg: lane owns 4 cols (lane*4); row bases from readlane; bf16 V loads (8B/row)
  float4 accv = {0.f,0.f,0.f,0.f};
  {
    const int h = lane>>3;
    #pragma unroll
    for (int g=0; g<4; g++){
      const bf16_t* rp[8];
      #pragma unroll
      for (int i=0;i<8;i++){
        int row = __builtin_amdgcn_readlane(srcv, g*8 + i);
        rp[i] = vproj_bf + ((size_t)b*Nn + row)*256;
      }
      #pragma unroll
      for (int i=0;i<8;i++){
        const bf16x4v v4 = *(const bf16x4v*)(rp[i] + (lane<<2));
        float al = s_al[(g*8+i)*8 + h];
        accv.x += al*(float)v4[0]; accv.y += al*(float)v4[1];
        accv.z += al*(float)v4[2]; accv.w += al*(float)v4[3];
      }
    }
  }

  // final: 4 cols/lane
  {
    const int h = lane>>3;
    const float* wvsh = Wvg + (size_t)layer*265*Dd + 256*Dd;
    #pragma unroll
    for (int sg=0; sg<SHDs; sg++){
      const float4 wv4 = *(const float4*)(wvsh + sg*Dd + (lane<<2));
      const float pl = s_pool[h*10 + sg];
      accv.x += pl*wv4.x; accv.y += pl*wv4.y; accv.z += pl*wv4.z; accv.w += pl*wv4.w;
    }

    if (layer < 3){
      bf16x4v o;
      o[0] = (bf16_t)accv.x; o[1] = (bf16_t)accv.y;
      o[2] = (bf16_t)accv.z; o[3] = (bf16_t)accv.w;
      *(bf16x4v*)(agg_bf + (size_t)bn*Dd + (lane<<2)) = o;
    } else {
      const int c0 = lane<<2;
      float p0 = accv.x*Woo[c0*3+0] + accv.y*Woo[c0*3+3] + accv.z*Woo[c0*3+6] + accv.w*Woo[c0*3+9];
      float p1 = accv.x*Woo[c0*3+1] + accv.y*Woo[c0*3+4] + accv.z*Woo[c0*3+7] + accv.w*Woo[c0*3+10];
      float p2 = accv.x*Woo[c0*3+2] + accv.y*Woo[c0*3+5] + accv.z*Woo[c0*3+8] + accv.w*Woo[c0*3+11];
      #pragma unroll
      for (int off=32; off>=1; off>>=1){
        p0 += __shfl_xor(p0, off);
        p1 += __shfl_xor(p1, off);
        p2 += __shfl_xor(p2, off);
      }
      if (lane == 0){
        out[(size_t)bn*3+0] = p0;
        out[(size_t)bn*3+1] = p1;
        out[(size_t)bn*3+2] = p2;
      }
    }
  }
}

extern "C" void kernel_launch(void* const* d_in, const int* in_sizes, int n_in,
                              void* d_out, int out_size, void* d_ws, size_t ws_size,
                              hipStream_t stream){
  const float* x   = (const float*)d_in[0];
  const float* y   = (const float*)d_in[1];
  const float* t   = (const float*)d_in[2];
  const float* We  = (const float*)d_in[3];
  const float* Wk1 = (const float*)d_in[4];
  const float* bk1 = (const float*)d_in[5];
  const float* Wk2 = (const float*)d_in[6];
  const float* Wq  = (const float*)d_in[7];
  const float* Wv  = (const float*)d_in[8];
  const float* Wo  = (const float*)d_in[9];
  const float* Woo = (const float*)d_in[10];
  float* out = (float*)d_out;

  char* ws = (char*)d_ws;
  size_t off = 0;
  auto take = [&](size_t bytes)->char*{ char* p = ws + off; off = (off + bytes + 255) & ~(size_t)255; return p; };

  int*    src      = (int*)   take((size_t)Bb*Nn*Kk*4);
  float*  nodeA    = (float*) take((size_t)Bb*Nn*Dd*4);
  float*  nodeB    = (float*) take((size_t)Bb*Nn*Dd*4);
  bf16_t* node_bf  = (bf16_t*)take((size_t)Bb*Nn*Dd*2);
  bf16_t* agg_bf   = (bf16_t*)take((size_t)Bb*Nn*Dd*2);
  bf16_t* vproj_bf = (bf16_t*)take((size_t)Bb*Nn*256*2);
  bf16_t* hsrc_bf  = (bf16_t*)take((size_t)Bb*Nn*128*2);
  float*  hdst_f   = (float*) take((size_t)Bb*Nn*128*4);
  bf16_t* qw_bf    = (bf16_t*)take(((size_t)Bb*Nn*1024 + 2048)*2);  // +pad for B-frag overread
  bf16_t* Wt       = (bf16_t*)take((size_t)4*NCOLS*Dd*2);
  bf16_t* Wto      = (bf16_t*)take((size_t)3*Dd*Dd*2);
  bf16_t* WrbfT    = (bf16_t*)take((size_t)4*HIDh*NBnb*2);
  float*  t_hd     = (float*) take((size_t)4*Bb*HIDh*4);

  setup_kernel<<<dim3(11088), 256, 0, stream>>>(x, y, t, We, Wk1, bk1, Wk2, Wq, Wv, Wo,
                                                Wt, Wto, WrbfT, t_hd, src, nodeA, node_bf);

  gemm_proj<<<dim3(64,24), 256, 0, stream>>>(node_bf, Wt, vproj_bf, hsrc_bf, hdst_f, qw_bf, t_hd, 0);
  attn_kernel<<<dim3(Bb*Nn/4), 256, 0, stream>>>(x, src, vproj_bf, hsrc_bf, hdst_f, qw_bf,
                                                 WrbfT, Wv, Woo, agg_bf, out, 0);
  // node f32 double-buffer: lu=0 reads A writes B; lu=1 reads B writes A; lu=2 reads A (bf16 only)
  const float* nin[3]  = {nodeA, nodeB, nodeA};
  float*       nout[3] = {nodeB, nodeA, nodeB};
  for (int l=1; l<4; l++){
    gemm_upd<<<dim3(64,4), 256, 0, stream>>>(agg_bf, Wto, nin[l-1], nout[l-1], node_bf,
                                             l-1, (l < 3) ? 1 : 0);
    gemm_proj<<<dim3(64,24), 256, 0, stream>>>(node_bf, Wt, vproj_bf, hsrc_bf, hdst_f, qw_bf, t_hd, l);
    attn_kernel<<<dim3(Bb*Nn/4), 256, 0, stream>>>(x, src, vproj_bf, hsrc_bf, hdst_f, qw_bf,
                                                   WrbfT, Wv, Woo, agg_bf, out, l);
  }
}